// Round 6
// baseline (274.610 us; speedup 1.0000x reference)
//
#include <hip/hip_runtime.h>
#include <hip/hip_bf16.h>
#include <math.h>

typedef __bf16 bf16_t;
typedef __bf16 bf16x8 __attribute__((ext_vector_type(8)));
typedef __bf16 bf16x4 __attribute__((ext_vector_type(4)));
typedef float  f32x4  __attribute__((ext_vector_type(4)));

#define L_DIM 2048
#define D_DIM 1024
#define H_DIM 16
#define M_DIM 4096
#define KTOP 409
#define SLOTS 448    // 7 * 64, padded (sel = -1 beyond KTOP)
#define KSPLIT 8
#define KCHUNK 256   // L_DIM / KSPLIT
#define HSZ (L_DIM * 64)   // elements per (b,h) head block = 131072

// split f32 into bf16 hi + bf16 lo (a ~= hi + lo)
__device__ __forceinline__ void split2(float a, bf16_t& h, bf16_t& l) {
  h = (bf16_t)a;
  l = (bf16_t)(a - (float)h);
}

// async global -> LDS, 16B per lane; lds ptr must be wave-uniform (m104/m108)
__device__ __forceinline__ void gld16(const bf16_t* g, bf16_t* l) {
  __builtin_amdgcn_global_load_lds(
      (const __attribute__((address_space(1))) void*)g,
      (__attribute__((address_space(3))) void*)l, 16, 0, 0);
}

// stage a 128x32 bf16 tile (row stride D_DIM) into unpadded LDS.
// wave w covers segments {2w, 2w+1}; seg s = rows 16s..16s+15.
#define STAGE_TILE128(src, dst)                                               \
  {                                                                           \
    const int seg0 = wave * 2;                                                \
    const int r0 = seg0 * 16 + (lane >> 2);                                   \
    const int c0 = (lane & 3) * 8;                                            \
    gld16((src) + (size_t)r0 * D_DIM + c0, (dst) + seg0 * 512);               \
    gld16((src) + (size_t)(r0 + 16) * D_DIM + c0, (dst) + (seg0 + 1) * 512);  \
  }

// stage a 64x32 bf16 tile: one 16-row segment per wave.
#define STAGE_TILE64(src, dst)                                                \
  {                                                                           \
    const int r0 = wave * 16 + (lane >> 2);                                   \
    const int c0 = (lane & 3) * 8;                                            \
    gld16((src) + (size_t)r0 * D_DIM + c0, (dst) + wave * 512);               \
  }

// ---------------------------------------------------------------------------
// prep: pre-split x and Wq into bf16 hi/lo; pre-round Wk/Wv/Wo to bf16.
// Grid-stride (2048 blocks x 4 items) instead of 8192 one-shot blocks.
// ---------------------------------------------------------------------------
__global__ __launch_bounds__(256) void prep_kernel(
    const float* __restrict__ x,  const float* __restrict__ Wq,
    const float* __restrict__ Wk, const float* __restrict__ Wv,
    const float* __restrict__ Wo,
    bf16_t* __restrict__ xhi, bf16_t* __restrict__ xlo,
    bf16_t* __restrict__ Wqhi, bf16_t* __restrict__ Wqlo,
    bf16_t* __restrict__ Wkb,  bf16_t* __restrict__ Wvb,
    bf16_t* __restrict__ Wob)
{
  const int XV = (M_DIM * D_DIM) / 4;
  const int WV = (D_DIM * D_DIM) / 4;
  const int TOT = XV + 4 * WV;
  for (int i = blockIdx.x * 256 + threadIdx.x; i < TOT; i += gridDim.x * 256) {
    if (i < XV) {
      f32x4 v = ((const f32x4*)x)[i];
      bf16x4 h, l;
      #pragma unroll
      for (int j = 0; j < 4; ++j) { bf16_t hh, ll; split2(v[j], hh, ll); h[j] = hh; l[j] = ll; }
      ((bf16x4*)xhi)[i] = h;
      ((bf16x4*)xlo)[i] = l;
    } else if (i < XV + WV) {
      int j0 = i - XV;
      f32x4 v = ((const f32x4*)Wq)[j0];
      bf16x4 h, l;
      #pragma unroll
      for (int j = 0; j < 4; ++j) { bf16_t hh, ll; split2(v[j], hh, ll); h[j] = hh; l[j] = ll; }
      ((bf16x4*)Wqhi)[j0] = h;
      ((bf16x4*)Wqlo)[j0] = l;
    } else if (i < XV + 2 * WV) {
      int j0 = i - XV - WV;
      f32x4 v = ((const f32x4*)Wk)[j0];
      bf16x4 h;
      #pragma unroll
      for (int j = 0; j < 4; ++j) h[j] = (bf16_t)v[j];
      ((bf16x4*)Wkb)[j0] = h;
    } else if (i < XV + 3 * WV) {
      int j0 = i - XV - 2 * WV;
      f32x4 v = ((const f32x4*)Wv)[j0];
      bf16x4 h;
      #pragma unroll
      for (int j = 0; j < 4; ++j) h[j] = (bf16_t)v[j];
      ((bf16x4*)Wvb)[j0] = h;
    } else {
      int j0 = i - XV - 3 * WV;
      f32x4 v = ((const f32x4*)Wo)[j0];
      bf16x4 h;
      #pragma unroll
      for (int j = 0; j < 4; ++j) h[j] = (bf16_t)v[j];
      ((bf16x4*)Wob)[j0] = h;
    }
  }
}

// ---------------------------------------------------------------------------
// Fused QKV projections — round-6: statically work-balanced grid.
// 1024 blocks, quarter-decoded (g = bx>>8): g=0,1 -> Q halves (64x128 tiles,
// 512 blocks x 1.5 units), g=2 -> K, g=3 -> V (128x128, 256 blocks x 1 unit).
// Breadth-first dispatch gives each CU {z0,z0,z1,z2} = uniform 5 units, and
// 40KB LDS allows 4 blocks/CU (16 waves) -> no lone-z0 exposed-latency tail.
// Same per-output FP order as r3/r5 (phase A: xh*Wqh + xh*Wql; B: xl*Wqh).
// K written per-head [b][h][L][64]; V key-tiled [(b,h)][kb][d][32].
// ---------------------------------------------------------------------------
__global__ __launch_bounds__(256, 4) void gemm_qkv(
    const bf16_t* __restrict__ xhi, const bf16_t* __restrict__ xlo,
    const bf16_t* __restrict__ Wqhi, const bf16_t* __restrict__ Wqlo,
    const bf16_t* __restrict__ Wkb, const bf16_t* __restrict__ Wvb,
    const float* __restrict__ bq, const float* __restrict__ bk, const float* __restrict__ bv,
    bf16_t* __restrict__ Qhi, bf16_t* __restrict__ Khi, bf16_t* __restrict__ VThi,
    float* __restrict__ norms)
{
  const int bx = blockIdx.x;
  const int g  = bx >> 8;         // 0,1: Q ; 2: K ; 3: V
  const int id = bx & 255;

  // 40KB: dbuf x 10240 elems. z0 buffer: A(2048) | B1@2048(4096) | B2@6144(4096)
  //                           z1/z2 buffer: A(4096) | B@4096(4096)
  __shared__ __align__(16) bf16_t sm[2][10240];

  const int tid  = threadIdx.x;
  const int lane = tid & 63;
  const int wave = tid >> 6;
  const int wr = wave >> 1, wc = wave & 1;
  const int lm = lane & 15, quad = lane >> 4;

  const f32x4 vzero = {0.f, 0.f, 0.f, 0.f};

  if (g < 2) {
    const int idz  = (g << 8) + id;       // 0..511
    const int n0   = (idz & 7) * 128;
    const int row0 = (idz >> 3) * 64;

    f32x4 acc[2][4];
    #pragma unroll
    for (int mi = 0; mi < 2; ++mi)
      #pragma unroll
      for (int ni = 0; ni < 4; ++ni) acc[mi][ni] = vzero;

#define QSTAGE_A(k0, bsel) do {                                              \
      STAGE_TILE64(xhi   + (size_t)row0 * D_DIM + (k0), sm[bsel]);           \
      STAGE_TILE128(Wqhi + (size_t)n0   * D_DIM + (k0), sm[bsel] + 2048);    \
      STAGE_TILE128(Wqlo + (size_t)n0   * D_DIM + (k0), sm[bsel] + 6144);    \
    } while (0)
#define QSTAGE_B(k0, bsel) do {                                              \
      STAGE_TILE64(xlo   + (size_t)row0 * D_DIM + (k0), sm[bsel]);           \
      STAGE_TILE128(Wqhi + (size_t)n0   * D_DIM + (k0), sm[bsel] + 2048);    \
    } while (0)

    QSTAGE_A(0, 0);
    __syncthreads();
    int cur = 0;
    // phase A: acc += xh*Wqh + xh*Wql
    for (int k0 = 0; k0 < D_DIM; k0 += 32) {
      if (k0 + 32 < D_DIM) QSTAGE_A(k0 + 32, cur ^ 1);
      else                 QSTAGE_B(0, cur ^ 1);      // bridge into phase B
      bf16x8 af[2], bh0[4], bl0[4];
      #pragma unroll
      for (int mi = 0; mi < 2; ++mi)
        af[mi] = *reinterpret_cast<const bf16x8*>(&sm[cur][(wr * 32 + mi * 16 + lm) * 32 + quad * 8]);
      #pragma unroll
      for (int ni = 0; ni < 4; ++ni) {
        bh0[ni] = *reinterpret_cast<const bf16x8*>(&sm[cur][2048 + (wc * 64 + ni * 16 + lm) * 32 + quad * 8]);
        bl0[ni] = *reinterpret_cast<const bf16x8*>(&sm[cur][6144 + (wc * 64 + ni * 16 + lm) * 32 + quad * 8]);
      }
      #pragma unroll
      for (int mi = 0; mi < 2; ++mi)
        #pragma unroll
        for (int ni = 0; ni < 4; ++ni) {
          acc[mi][ni] = __builtin_amdgcn_mfma_f32_16x16x32_bf16(af[mi], bh0[ni], acc[mi][ni], 0, 0, 0);
          acc[mi][ni] = __builtin_amdgcn_mfma_f32_16x16x32_bf16(af[mi], bl0[ni], acc[mi][ni], 0, 0, 0);
        }
      __syncthreads();
      cur ^= 1;
    }
    // phase B: acc += xl*Wqh
    for (int k0 = 0; k0 < D_DIM; k0 += 32) {
      if (k0 + 32 < D_DIM) QSTAGE_B(k0 + 32, cur ^ 1);
      bf16x8 af[2], bh0[4];
      #pragma unroll
      for (int mi = 0; mi < 2; ++mi)
        af[mi] = *reinterpret_cast<const bf16x8*>(&sm[cur][(wr * 32 + mi * 16 + lm) * 32 + quad * 8]);
      #pragma unroll
      for (int ni = 0; ni < 4; ++ni)
        bh0[ni] = *reinterpret_cast<const bf16x8*>(&sm[cur][2048 + (wc * 64 + ni * 16 + lm) * 32 + quad * 8]);
      #pragma unroll
      for (int mi = 0; mi < 2; ++mi)
        #pragma unroll
        for (int ni = 0; ni < 4; ++ni)
          acc[mi][ni] = __builtin_amdgcn_mfma_f32_16x16x32_bf16(af[mi], bh0[ni], acc[mi][ni], 0, 0, 0);
      __syncthreads();
      cur ^= 1;
    }

    float bvv[4];
    #pragma unroll
    for (int ni = 0; ni < 4; ++ni) bvv[ni] = bq[n0 + wc * 64 + ni * 16 + lm];
    #pragma unroll
    for (int mi = 0; mi < 2; ++mi)
      #pragma unroll
      for (int ni = 0; ni < 4; ++ni)
        #pragma unroll
        for (int r = 0; r < 4; ++r) acc[mi][ni][r] += bvv[ni];

    const int h = (n0 + wc * 64) >> 6;
    #pragma unroll
    for (int mi = 0; mi < 2; ++mi)
      #pragma unroll
      for (int r = 0; r < 4; ++r) {
        float s = 0.f;
        #pragma unroll
        for (int ni = 0; ni < 4; ++ni) { float v = acc[mi][ni][r]; s += v * v; }
        s += __shfl_xor(s, 1); s += __shfl_xor(s, 2);
        s += __shfl_xor(s, 4); s += __shfl_xor(s, 8);
        if (lm == 0) {
          int row = row0 + wr * 32 + mi * 16 + quad * 4 + r;
          int bb = row >> 11, ll = row & (L_DIM - 1);
          norms[(bb * H_DIM + h) * L_DIM + ll] = s;
        }
      }

    #pragma unroll
    for (int mi = 0; mi < 2; ++mi)
      #pragma unroll
      for (int r = 0; r < 4; ++r) {
        int row = row0 + wr * 32 + mi * 16 + quad * 4 + r;
        #pragma unroll
        for (int ni = 0; ni < 4; ++ni)
          Qhi[(size_t)row * D_DIM + n0 + wc * 64 + ni * 16 + lm] = (bf16_t)acc[mi][ni][r];
      }
  } else {
    const int n0   = (id & 7) * 128;
    const int row0 = (id >> 3) * 128;
    const bf16_t* W = (g == 2) ? Wkb : Wvb;

    f32x4 acc[4][4];
    #pragma unroll
    for (int mi = 0; mi < 4; ++mi)
      #pragma unroll
      for (int ni = 0; ni < 4; ++ni) acc[mi][ni] = vzero;

#define LSTAGE(k0, bsel) do {                                                \
      STAGE_TILE128(xhi + (size_t)row0 * D_DIM + (k0), sm[bsel]);            \
      STAGE_TILE128(W   + (size_t)n0   * D_DIM + (k0), sm[bsel] + 4096);     \
    } while (0)

    LSTAGE(0, 0);
    __syncthreads();
    int cur = 0;
    for (int k0 = 0; k0 < D_DIM; k0 += 32) {
      if (k0 + 32 < D_DIM) LSTAGE(k0 + 32, cur ^ 1);
      bf16x8 af[4], bfr[4];
      #pragma unroll
      for (int mi = 0; mi < 4; ++mi)
        af[mi] = *reinterpret_cast<const bf16x8*>(&sm[cur][(wr * 64 + mi * 16 + lm) * 32 + quad * 8]);
      #pragma unroll
      for (int ni = 0; ni < 4; ++ni)
        bfr[ni] = *reinterpret_cast<const bf16x8*>(&sm[cur][4096 + (wc * 64 + ni * 16 + lm) * 32 + quad * 8]);
      #pragma unroll
      for (int mi = 0; mi < 4; ++mi)
        #pragma unroll
        for (int ni = 0; ni < 4; ++ni)
          acc[mi][ni] = __builtin_amdgcn_mfma_f32_16x16x32_bf16(af[mi], bfr[ni], acc[mi][ni], 0, 0, 0);
      __syncthreads();
      cur ^= 1;
    }

    const float* bias = (g == 2) ? bk : bv;
    float bvv[4];
    #pragma unroll
    for (int ni = 0; ni < 4; ++ni) bvv[ni] = bias[n0 + wc * 64 + ni * 16 + lm];
    #pragma unroll
    for (int mi = 0; mi < 4; ++mi)
      #pragma unroll
      for (int ni = 0; ni < 4; ++ni)
        #pragma unroll
        for (int r = 0; r < 4; ++r) acc[mi][ni][r] += bvv[ni];

    const int hh = (n0 + wc * 64) >> 6;   // head 0..15
    if (g == 2) {
      // Khead[b][h][l][64]
      #pragma unroll
      for (int mi = 0; mi < 4; ++mi)
        #pragma unroll
        for (int r = 0; r < 4; ++r) {
          int row = row0 + wr * 64 + mi * 16 + quad * 4 + r;
          int bb = row >> 11, ll = row & (L_DIM - 1);
          size_t base = (size_t)(bb * H_DIM + hh) * HSZ + (size_t)ll * 64;
          #pragma unroll
          for (int ni = 0; ni < 4; ++ni)
            Khi[base + ni * 16 + lm] = (bf16_t)acc[mi][ni][r];
        }
    } else {
      // V key-tiled: [(b,h)][kb=l/32][d][32]
      #pragma unroll
      for (int mi = 0; mi < 4; ++mi) {
        int rbase = row0 + wr * 64 + mi * 16 + quad * 4;
        int bb = rbase >> 11, l0 = rbase & (L_DIM - 1);
        int kbv = l0 >> 5, kin = l0 & 31;
        size_t hb = (size_t)(bb * H_DIM + hh) * HSZ;
        #pragma unroll
        for (int ni = 0; ni < 4; ++ni) {
          int d = ni * 16 + lm;
          bf16x4 wv;
          #pragma unroll
          for (int r = 0; r < 4; ++r) wv[r] = (bf16_t)acc[mi][ni][r];
          *reinterpret_cast<bf16x4*>(&VThi[hb + (size_t)(kbv * 64 + d) * 32 + kin]) = wv;
        }
      }
    }
  }
}

// ---------------------------------------------------------------------------
// Output projection: 64x128 tiles, grid (8,64) = 2 blocks/CU, prefetch dbuf.
// ---------------------------------------------------------------------------
__global__ __launch_bounds__(256) void gemm_out(
    const bf16_t* __restrict__ Ahi, const bf16_t* __restrict__ Wob,
    const float* __restrict__ bias, float* __restrict__ C)
{
  const int n0   = blockIdx.x * 128;
  const int row0 = blockIdx.y * 64;

  __shared__ __align__(16) bf16_t sm[2][6144];   // 24 KB: dbuf x (A64 + B128)

  const int tid  = threadIdx.x;
  const int lane = tid & 63;
  const int wave = tid >> 6;
  const int wr = wave >> 1, wc = wave & 1;
  const int lm = lane & 15, quad = lane >> 4;

  const f32x4 vzero = {0.f, 0.f, 0.f, 0.f};
  f32x4 acc[2][4];
  #pragma unroll
  for (int mi = 0; mi < 2; ++mi)
    #pragma unroll
    for (int ni = 0; ni < 4; ++ni) acc[mi][ni] = vzero;

#define STAGE_O(k0, b) do {                                                  \
    STAGE_TILE64(Ahi + (size_t)row0 * D_DIM + (k0), sm[b]);                  \
    STAGE_TILE128(Wob + (size_t)n0 * D_DIM + (k0), sm[b] + 2048);            \
  } while (0)

  STAGE_O(0, 0);
  __syncthreads();
  int cur = 0;
  for (int k0 = 0; k0 < D_DIM; k0 += 32) {
    if (k0 + 32 < D_DIM) STAGE_O(k0 + 32, cur ^ 1);
    bf16x8 af[2], bfr[4];
    #pragma unroll
    for (int mi = 0; mi < 2; ++mi)
      af[mi] = *reinterpret_cast<const bf16x8*>(&sm[cur][(wr * 32 + mi * 16 + lm) * 32 + quad * 8]);
    #pragma unroll
    for (int ni = 0; ni < 4; ++ni)
      bfr[ni] = *reinterpret_cast<const bf16x8*>(&sm[cur][2048 + (wc * 64 + ni * 16 + lm) * 32 + quad * 8]);
    #pragma unroll
    for (int mi = 0; mi < 2; ++mi)
      #pragma unroll
      for (int ni = 0; ni < 4; ++ni)
        acc[mi][ni] = __builtin_amdgcn_mfma_f32_16x16x32_bf16(af[mi], bfr[ni], acc[mi][ni], 0, 0, 0);
    __syncthreads();
    cur ^= 1;
  }

  float bvv[4];
  #pragma unroll
  for (int ni = 0; ni < 4; ++ni) bvv[ni] = bias[n0 + wc * 64 + ni * 16 + lm];
  #pragma unroll
  for (int mi = 0; mi < 2; ++mi)
    #pragma unroll
    for (int r = 0; r < 4; ++r) {
      int row = row0 + wr * 32 + mi * 16 + quad * 4 + r;
      #pragma unroll
      for (int ni = 0; ni < 4; ++ni)
        C[(size_t)row * D_DIM + n0 + wc * 64 + ni * 16 + lm] = acc[mi][ni][r] + bvv[ni];
    }
}

// ---------------------------------------------------------------------------
// Exact top-409 per (b,h) via 4-pass 8-bit radix select on f32 bits
// (norms >= 0 so uint ordering == float ordering), then ballot-prefix
// write-out. Set matches lax.top_k exactly: all keys > T, plus the
// (KTOP - count_gt) smallest-index keys == T.
// ---------------------------------------------------------------------------
__global__ __launch_bounds__(1024) void topk_kernel(
    const float* __restrict__ norms, int* __restrict__ sel)
{
  const int bh = blockIdx.x;
  const int t  = threadIdx.x;
  const int w  = t >> 6;            // wave 0..15
  const int lane = t & 63;

  __shared__ int bins[256];
  __shared__ unsigned int sh_pfx;
  __shared__ int cnt0[16], cnt1[16], ecnt0[16], ecnt1[16];

  // two keys per thread, index order: k0 -> index t, k1 -> index t+1024
  const unsigned int k0 = __float_as_uint(norms[bh * L_DIM + t]);
  const unsigned int k1 = __float_as_uint(norms[bh * L_DIM + t + 1024]);

  // ---- find T = KTOP-th largest key (exact, 4 passes of 8 bits) ----
  unsigned int pfx = 0;   // high bits fixed so far (in low positions)
  int r = KTOP;           // rank remaining among qualifying keys
  #pragma unroll
  for (int p = 0; p < 4; ++p) {
    const int sh = 24 - 8 * p;
    if (t < 256) bins[t] = 0;
    __syncthreads();
    const bool q0 = (p == 0) || ((k0 >> (sh + 8)) == pfx);
    const bool q1 = (p == 0) || ((k1 >> (sh + 8)) == pfx);
    if (q0) atomicAdd(&bins[(k0 >> sh) & 255], 1);
    if (q1) atomicAdd(&bins[(k1 >> sh) & 255], 1);
    __syncthreads();
    if (t == 0) {
      int cum = 0, B = 0;
      for (int v = 255; v >= 0; --v) {
        int c = bins[v];
        if (cum + c >= r) { B = v; r -= cum; break; }
        cum += c;
      }
      sh_pfx = (pfx << 8) | (unsigned int)B;
      bins[0] = r;          // reuse as broadcast slot (post-barrier read)
    }
    __syncthreads();
    pfx = sh_pfx;
    r = bins[0];
    __syncthreads();
  }
  const unsigned int T = pfx;

  // ---- selection write-out ----
  const bool gt0 = (k0 > T), gt1 = (k1 > T);
  const bool eq0 = (k0 == T), eq1 = (k1 == T);
  const unsigned long long mlt = (lane == 63) ? 0x7fffffffffffffffull
                                              : ((1ull << lane) - 1ull);
  const unsigned long long bg0 = __ballot(gt0);
  const unsigned long long bg1 = __ballot(gt1);
  const unsigned long long be0 = __ballot(eq0);
  const unsigned long long be1 = __ballot(eq1);
  if (lane == 0) {
    cnt0[w]  = __popcll(bg0);
    cnt1[w]  = __popcll(bg1);
    ecnt0[w] = __popcll(be0);
    ecnt1[w] = __popcll(be1);
  }
  __syncthreads();
  int og0 = 0, og1 = 0, oe0 = 0, oe1 = 0;
  int tg0 = 0, tg1 = 0, te0 = 0;
  #pragma unroll
  for (int i = 0; i < 16; ++i) {
    if (i < w) { og0 += cnt0[i]; og1 += cnt1[i]; oe0 += ecnt0[i]; oe1 += ecnt1[i]; }
    tg0 += cnt0[i]; tg1 += cnt1[i]; te0 += ecnt0[i];
  }
  const int G = tg0 + tg1;          // total keys > T (G < KTOP)
  const int take = KTOP - G;        // ties to take, earliest index first
  const int base = bh * SLOTS;

  if (gt0) sel[base + og0 + __popcll(bg0 & mlt)] = t;
  if (gt1) sel[base + tg0 + og1 + __popcll(bg1 & mlt)] = t + 1024;
  if (eq0) {
    int rk = oe0 + __popcll(be0 & mlt);
    if (rk < take) sel[base + G + rk] = t;
  }
  if (eq1) {
    int rk = te0 + oe1 + __popcll(be1 & mlt);
    if (rk < take) sel[base + G + rk] = t + 1024;
  }
  if (t < SLOTS - KTOP) sel[base + KTOP + t] = -1;
}

// ---------------------------------------------------------------------------
// K-split flash attention. K per-head [b][h][L][64]; V key-tiled
// [(b,h)][kb][d][32]. XCD-affinity block swizzle; 2x-unrolled inner loop
// with double-buffered P.
// ---------------------------------------------------------------------------
__global__ __launch_bounds__(256) void attn_kernel(
    const bf16_t* __restrict__ Qhi,
    const bf16_t* __restrict__ Khi,
    const bf16_t* __restrict__ VThi,
    const int* __restrict__ sel,
    float* __restrict__ Ol, bf16_t* __restrict__ Oo)
{
  const int bx = blockIdx.x;
  const int xl = bx & 7;          // XCD id under default round-robin
  const int rest = bx >> 3;       // 0..223
  const int qc = rest % 7;
  const int gh = rest / 7;        // 0..31
  const int g  = gh * 8 + xl;     // K/V-chunk group 0..255
  const int bh = g & 31;
  const int ks = g >> 5;
  const int b = bh >> 4, h = bh & 15;
  const int wave = threadIdx.x >> 6;
  const int lane = threadIdx.x & 63;
  const int lm = lane & 15, quad = lane >> 4;

  __shared__ __align__(16) bf16_t sPh[2][4][16][40];

  const int qbase = qc * 64 + wave * 16;
  const int qi = sel[bh * SLOTS + qbase + lm];
  const size_t qo = ((size_t)(b * L_DIM + (qi >= 0 ? qi : 0))) * D_DIM + h * 64;
  const bf16x8 qa0 = *reinterpret_cast<const bf16x8*>(&Qhi[qo + quad * 8]);
  const bf16x8 qa1 = *reinterpret_cast<const bf16x8*>(&Qhi[qo + 32 + quad * 8]);

  const f32x4 vzero = {0.f, 0.f, 0.f, 0.f};
  float l_l[4] = {0.f, 0.f, 0.f, 0.f};
  f32x4 o[4];
  #pragma unroll
  for (int ni = 0; ni < 4; ++ni) o[ni] = vzero;

  const float scale = 0.125f;
  const size_t khead = (size_t)(b * H_DIM + h) * HSZ;
  const int key0 = ks * KCHUNK;

  // inner name 'kof' differs from the caller's loop var (r2 self-shadow UB)
#define ATTN_STEP(KT, PB)                                                     \
  {                                                                           \
    const int kof = (KT);                                                     \
    size_t kr0 = khead + (size_t)(key0 + kof + lm) * 64;                      \
    size_t kr1 = khead + (size_t)(key0 + kof + 16 + lm) * 64;                 \
    bf16x8 kb0 = *reinterpret_cast<const bf16x8*>(&Khi[kr0 + quad * 8]);      \
    bf16x8 kb1 = *reinterpret_cast<const bf16x8*>(&Khi[kr0 + 32 + quad * 8]); \
    bf16x8 kb2 = *reinterpret_cast<const bf16x8*>(&Khi[kr1 + quad * 8]);      \
    bf16x8 kb3 = *reinterpret_cast<const bf16x8*>(&Khi[kr1 + 32 + quad * 8]); \
    const int kbv = (key0 + kof) >> 5;                                        \
    bf16x8 vbh[4];                                                            \
    _Pragma("unroll")                                                         \
    for (int ni = 0; ni < 4; ++ni) {                                          \
      size_t vo = khead + (size_t)(kbv * 64 + ni * 16 + lm) * 32 + quad * 8;  \
      vbh[ni] = *reinterpret_cast<const bf16x8*>(&VThi[vo]);                  \
    }                                                                         \
    f32x4 s0 = vzero, s1 = vzero;                                             \
    s0 = __builtin_amdgcn_mfma_f32_16x16x32_bf16(qa0, kb0, s0, 0, 0, 0);      \
    s0 = __builtin_amdgcn_mfma_f32_16x16x32_bf16(qa1, kb1, s0, 0, 0, 0);      \
    s1 = __builtin_amdgcn_mfma_f32_16x16x32_bf16(qa0, kb2, s1, 0, 0, 0);      \
    s1 = __builtin_amdgcn_mfma_f32_16x16x32_bf16(qa1, kb3, s1, 0, 0, 0);      \
    _Pragma("unroll")                                                         \
    for (int r = 0; r < 4; ++r) {                                             \
      float p0 = __expf(s0[r] * scale);                                       \
      float p1 = __expf(s1[r] * scale);                                       \
      l_l[r] += p0 + p1;                                                      \
      sPh[PB][wave][quad * 4 + r][lm]      = (bf16_t)p0;                      \
      sPh[PB][wave][quad * 4 + r][16 + lm] = (bf16_t)p1;                      \
    }                                                                         \
    bf16x8 pah = *reinterpret_cast<const bf16x8*>(&sPh[PB][wave][lm][quad * 8]); \
    _Pragma("unroll")                                                         \
    for (int ni = 0; ni < 4; ++ni)                                            \
      o[ni] = __builtin_amdgcn_mfma_f32_16x16x32_bf16(pah, vbh[ni], o[ni], 0, 0, 0); \
  }

  for (int kt = 0; kt < KCHUNK; kt += 64) {
    ATTN_STEP(kt, 0);
    ATTN_STEP(kt + 32, 1);
  }

  #pragma unroll
  for (int r = 0; r < 4; ++r) {
    l_l[r] += __shfl_xor(l_l[r], 1);
    l_l[r] += __shfl_xor(l_l[r], 2);
    l_l[r] += __shfl_xor(l_l[r], 4);
    l_l[r] += __shfl_xor(l_l[r], 8);
  }

  #pragma unroll
  for (int r = 0; r < 4; ++r) {
    int slot = qbase + quad * 4 + r;
    int s2 = sel[bh * SLOTS + slot];
    if (s2 >= 0) {
      size_t gs = (size_t)(bh * SLOTS + slot) * KSPLIT + ks;
      if (lm == 0) Ol[gs] = l_l[r];
      #pragma unroll
      for (int ni = 0; ni < 4; ++ni)
        Oo[gs * 64 + ni * 16 + lm] = (bf16_t)o[ni][r];
    }
  }
}

// ---------------------------------------------------------------------------
// Combine ksplit partials -> AO (selected rows; meanfill covered the rest).
// ---------------------------------------------------------------------------
__global__ __launch_bounds__(256) void combine_kernel(
    const float* __restrict__ Ol, const bf16_t* __restrict__ Oo,
    const int* __restrict__ sel, bf16_t* __restrict__ AOhi)
{
  const int bh = blockIdx.x;
  const int b = bh >> 4, h = bh & 15;
  const int chunk = blockIdx.y;
  const int tid = threadIdx.x;
  const int dim = tid & 63;
  const int sl  = tid >> 6;
  #pragma unroll
  for (int p = 0; p < 4; ++p) {
    int slot = chunk * 16 + p * 4 + sl;
    int qi = sel[bh * SLOTS + slot];
    if (qi < 0) continue;
    size_t gs = (size_t)(bh * SLOTS + slot) * KSPLIT;
    float L = 0.f, ov = 0.f;
    #pragma unroll
    for (int s = 0; s < KSPLIT; ++s) {
      L  += Ol[gs + s];
      ov += (float)Oo[(gs + s) * 64 + dim];
    }
    AOhi[((size_t)(b * L_DIM + qi)) * D_DIM + h * 64 + dim] = (bf16_t)(ov / L);
  }
}

// ---------------------------------------------------------------------------
// mean(V) to EVERY AO row; combine overwrites selected rows.
// V is key-tiled: [(b,h)][kb][d][32].
// ---------------------------------------------------------------------------
__global__ __launch_bounds__(256) void meanfill_kernel(
    const bf16_t* __restrict__ VThi, bf16_t* __restrict__ AOhi)
{
  const int bh = blockIdx.x;
  const int b = bh >> 4, h = bh & 15;
  const int t = threadIdx.x;
  __shared__ __align__(16) bf16_t smh[64];
  {
    const int hd = t >> 2, part = t & 3;
    size_t hbase = (size_t)(b * H_DIM + h) * HSZ;
    float s = 0.f;
    for (int kb = part * 16; kb < part * 16 + 16; ++kb) {
      size_t a = hbase + (size_t)(kb * 64 + hd) * 32;
      bf16x8 v0 = *reinterpret_cast<const bf16x8*>(&VThi[a]);
      bf16x8 v1 = *reinterpret_cast<const bf16x8*>(&VThi[a + 8]);
      bf16x8 v2 = *reinterpret_cast<const bf16x8*>(&VThi[a + 16]);
      bf16x8 v3 = *reinterpret_cast<const bf16x8*>(&VThi[a + 24]);
      #pragma unroll
      for (int j = 0; j < 8; ++j)
        s += (float)v0[j] + (float)v1[j] + (float)v2[j] + (float)v3[j];
    }
    s += __shfl_xor(s, 1);
    s += __shfl_xor(s, 2);
    if (part == 0) smh[hd] = (bf16_t)(s * (1.0f / (float)L_DIM));
  }
  __syncthreads();
  const int lbase = blockIdx.y * 256;
  for (int i = t; i < 256 * 64; i += 256) {
    int l = lbase + (i >> 6), hd = i & 63;
    AOhi[((size_t)(b * L_DIM + l)) * D_DIM + h * 64 + hd] = smh[hd];
  }
}

// ---------------------------------------------------------------------------
extern "C" void kernel_launch(void* const* d_in, const int* in_sizes, int n_in,
                              void* d_out, int out_size, void* d_ws, size_t ws_size,
                              hipStream_t stream) {
  const float* x  = (const float*)d_in[0];
  const float* Wq = (const float*)d_in[1];
  const float* bq = (const float*)d_in[2];
  const float* Wk = (const float*)d_in[3];
  const float* bk = (const float*)d_in[4];
  const float* Wv = (const float*)d_in[5];
  const float* bv = (const float*)d_in[6];
  const float* Wo = (const float*)d_in[7];
  const float* bo = (const float*)d_in[8];
  float* out = (float*)d_out;

  // ws layout (~43 MB):
  //  [0,8)    Qhi  (aliased as AOhi after attn)
  //  [8,16)   VThi (key-tiled per-head layout)
  //  [16,24)  xhi  -+ dead after gemm_qkv; [16,32) reused for Oo (bf16, 14.7MB)
  //  [24,32)  xlo  -+
  //  [32,34)  Wqhi  [34,36) Wqlo  [36,38) Wkb  [38,40) Wvb  [40,42) Wob
  //  [42,..)  norms (256 KB), sel (57 KB), Ol (458 KB)
  // Khi (per-head layout) lives in d_out (8 of 16 MB) — dead until gemm_out.
  const size_t MB = 1u << 20;
  char* ws = (char*)d_ws;
  bf16_t* Qhi  = (bf16_t*)(ws);
  bf16_t* VThi = (bf16_t*)(ws + 8 * MB);
  bf16_t* xhi  = (bf16_t*)(ws + 16 * MB);
  bf16_t* xlo  = (bf16_t*)(ws + 24 * MB);
  bf16_t* Oo   = (bf16_t*)(ws + 16 * MB);         // aliases xhi/xlo
  bf16_t* Wqhi = (bf16_t*)(ws + 32 * MB);
  bf16_t* Wqlo = (bf16_t*)(ws + 34 * MB);
  bf16_t* Wkb  = (bf16_t*)(ws + 36 * MB);
  bf16_t* Wvb  = (bf16_t*)(ws + 38 * MB);
  bf16_t* Wob  = (bf16_t*)(ws + 40 * MB);
  float*  norms = (float*)(ws + 42 * MB);
  int*    sel   = (int*)(ws + 42 * MB + (256u << 10));
  float*  Ol    = (float*)(ws + 42 * MB + (320u << 10));
  bf16_t* AOhi = Qhi;
  bf16_t* Khi = (bf16_t*)d_out;

  dim3 blk(256);
  prep_kernel<<<dim3(2048), blk, 0, stream>>>(x, Wq, Wk, Wv, Wo,
                                              xhi, xlo, Wqhi, Wqlo, Wkb, Wvb, Wob);
  gemm_qkv<<<dim3(1024), blk, 0, stream>>>(xhi, xlo, Wqhi, Wqlo, Wkb, Wvb,
                                           bq, bk, bv, Qhi, Khi, VThi, norms);
  topk_kernel<<<dim3(32), dim3(1024), 0, stream>>>(norms, sel);
  attn_kernel<<<dim3(32 * 7 * KSPLIT), blk, 0, stream>>>(Qhi, Khi, VThi, sel, Ol, Oo);
  meanfill_kernel<<<dim3(32, 8), blk, 0, stream>>>(VThi, AOhi);
  combine_kernel<<<dim3(32, 28), blk, 0, stream>>>(Ol, Oo, sel, AOhi);
  gemm_out<<<dim3(8, 64), blk, 0, stream>>>(AOhi, Wob, bo, out);
}

// Round 8
// 256.271 us; speedup vs baseline: 1.0716x; 1.0716x over previous
//
#include <hip/hip_runtime.h>
#include <hip/hip_bf16.h>
#include <math.h>

typedef __bf16 bf16_t;
typedef __bf16 bf16x8 __attribute__((ext_vector_type(8)));
typedef __bf16 bf16x4 __attribute__((ext_vector_type(4)));
typedef float  f32x4  __attribute__((ext_vector_type(4)));

#define L_DIM 2048
#define D_DIM 1024
#define H_DIM 16
#define M_DIM 4096
#define KTOP 409
#define SLOTS 512      // sel padding (128-slot q-chunks; sel = -1 beyond KTOP)
#define SLOTS_IO 448   // Oo/Ol stride (real slots < 448) — keeps 16MB window
#define KSPLIT 8
#define KCHUNK 256     // L_DIM / KSPLIT
#define HSZ (L_DIM * 64)   // elements per (b,h) head block = 131072

// split f32 into bf16 hi + bf16 lo (a ~= hi + lo)
__device__ __forceinline__ void split2(float a, bf16_t& h, bf16_t& l) {
  h = (bf16_t)a;
  l = (bf16_t)(a - (float)h);
}

// async global -> LDS, 16B per lane; lds ptr must be wave-uniform (m104/m108)
__device__ __forceinline__ void gld16(const bf16_t* g, bf16_t* l) {
  __builtin_amdgcn_global_load_lds(
      (const __attribute__((address_space(1))) void*)g,
      (__attribute__((address_space(3))) void*)l, 16, 0, 0);
}

// Bank-conflict fix (rule #21: both-sides-or-neither with global_load_lds):
// LDS dest stays linear; the SOURCE column slot is XOR-swizzled by row&3, and
// every fragment read XORs its slot the same way (quad ^ (lm&3)).
// Drops the 8-way ds_read_b128 conflict to 4-way (m136: 2.94x -> 1.58x).

// stage a 128x32 bf16 tile (row stride D_DIM) into unpadded LDS (swizzled).
#define STAGE_TILE128(src, dst)                                               \
  {                                                                           \
    const int seg0 = wave * 2;                                                \
    const int r0 = seg0 * 16 + (lane >> 2);                                   \
    const int c0 = (((lane & 3) ^ ((lane >> 2) & 3))) * 8;                    \
    gld16((src) + (size_t)r0 * D_DIM + c0, (dst) + seg0 * 512);               \
    gld16((src) + (size_t)(r0 + 16) * D_DIM + c0, (dst) + (seg0 + 1) * 512);  \
  }

// stage a 64x32 bf16 tile: one 16-row segment per wave (swizzled).
#define STAGE_TILE64(src, dst)                                                \
  {                                                                           \
    const int r0 = wave * 16 + (lane >> 2);                                   \
    const int c0 = (((lane & 3) ^ ((lane >> 2) & 3))) * 8;                    \
    gld16((src) + (size_t)r0 * D_DIM + c0, (dst) + wave * 512);               \
  }

// swizzled fragment read: row ROW (ROW&3 == lm&3 at all call sites)
#define FRAG(buf, ROW) \
  (*reinterpret_cast<const bf16x8*>(&(buf)[(ROW) * 32 + (quad ^ (lm & 3)) * 8]))

// ---------------------------------------------------------------------------
// prep: pre-split x and Wq into bf16 hi/lo; pre-round Wk/Wv/Wo to bf16.
// ---------------------------------------------------------------------------
__global__ __launch_bounds__(256) void prep_kernel(
    const float* __restrict__ x,  const float* __restrict__ Wq,
    const float* __restrict__ Wk, const float* __restrict__ Wv,
    const float* __restrict__ Wo,
    bf16_t* __restrict__ xhi, bf16_t* __restrict__ xlo,
    bf16_t* __restrict__ Wqhi, bf16_t* __restrict__ Wqlo,
    bf16_t* __restrict__ Wkb,  bf16_t* __restrict__ Wvb,
    bf16_t* __restrict__ Wob)
{
  const int XV = (M_DIM * D_DIM) / 4;
  const int WV = (D_DIM * D_DIM) / 4;
  const int TOT = XV + 4 * WV;
  for (int i = blockIdx.x * 256 + threadIdx.x; i < TOT; i += gridDim.x * 256) {
    if (i < XV) {
      f32x4 v = ((const f32x4*)x)[i];
      bf16x4 h, l;
      #pragma unroll
      for (int j = 0; j < 4; ++j) { bf16_t hh, ll; split2(v[j], hh, ll); h[j] = hh; l[j] = ll; }
      ((bf16x4*)xhi)[i] = h;
      ((bf16x4*)xlo)[i] = l;
    } else if (i < XV + WV) {
      int j0 = i - XV;
      f32x4 v = ((const f32x4*)Wq)[j0];
      bf16x4 h, l;
      #pragma unroll
      for (int j = 0; j < 4; ++j) { bf16_t hh, ll; split2(v[j], hh, ll); h[j] = hh; l[j] = ll; }
      ((bf16x4*)Wqhi)[j0] = h;
      ((bf16x4*)Wqlo)[j0] = l;
    } else if (i < XV + 2 * WV) {
      int j0 = i - XV - WV;
      f32x4 v = ((const f32x4*)Wk)[j0];
      bf16x4 h;
      #pragma unroll
      for (int j = 0; j < 4; ++j) h[j] = (bf16_t)v[j];
      ((bf16x4*)Wkb)[j0] = h;
    } else if (i < XV + 3 * WV) {
      int j0 = i - XV - 2 * WV;
      f32x4 v = ((const f32x4*)Wv)[j0];
      bf16x4 h;
      #pragma unroll
      for (int j = 0; j < 4; ++j) h[j] = (bf16_t)v[j];
      ((bf16x4*)Wvb)[j0] = h;
    } else {
      int j0 = i - XV - 3 * WV;
      f32x4 v = ((const f32x4*)Wo)[j0];
      bf16x4 h;
      #pragma unroll
      for (int j = 0; j < 4; ++j) h[j] = (bf16_t)v[j];
      ((bf16x4*)Wob)[j0] = h;
    }
  }
}

// ---------------------------------------------------------------------------
// Fused QKV projections — r5 structure (measured best, 3 blocks/CU) + LDS
// read-swizzle. z0 split into A/B phases at 48 KB LDS, prefetch dbuf.
// K written per-head [b][h][L][64]; V key-tiled [(b,h)][kb][d][32].
// ---------------------------------------------------------------------------
__global__ __launch_bounds__(256, 3) void gemm_qkv(
    const bf16_t* __restrict__ xhi, const bf16_t* __restrict__ xlo,
    const bf16_t* __restrict__ Wqhi, const bf16_t* __restrict__ Wqlo,
    const bf16_t* __restrict__ Wkb, const bf16_t* __restrict__ Wvb,
    const float* __restrict__ bq, const float* __restrict__ bk, const float* __restrict__ bv,
    bf16_t* __restrict__ Qhi, bf16_t* __restrict__ Khi, bf16_t* __restrict__ VThi,
    float* __restrict__ norms)
{
  const int bx = blockIdx.x;
  const int z  = bx % 3;          // interleaved so each CU gets a z-mix
  const int id = bx / 3;          // 0..255
  const int n0   = (id & 7) * 128;
  const int row0 = (id >> 3) * 128;

  __shared__ __align__(16) bf16_t sm[2][3][4096];   // 48 KB: dbuf x 3 tiles

  const int tid  = threadIdx.x;
  const int lane = tid & 63;
  const int wave = tid >> 6;
  const int wr = wave >> 1, wc = wave & 1;
  const int lm = lane & 15, quad = lane >> 4;

  const f32x4 vzero = {0.f, 0.f, 0.f, 0.f};
  f32x4 acc[4][4];
  #pragma unroll
  for (int mi = 0; mi < 4; ++mi)
    #pragma unroll
    for (int ni = 0; ni < 4; ++ni) acc[mi][ni] = vzero;

  if (z == 0) {
#define STAGE_A(k0, b) do {                                                  \
      STAGE_TILE128(xhi  + (size_t)row0 * D_DIM + (k0), sm[b][0]);           \
      STAGE_TILE128(Wqhi + (size_t)n0   * D_DIM + (k0), sm[b][1]);           \
      STAGE_TILE128(Wqlo + (size_t)n0   * D_DIM + (k0), sm[b][2]);           \
    } while (0)
#define STAGE_B(k0, b) do {                                                  \
      STAGE_TILE128(xlo  + (size_t)row0 * D_DIM + (k0), sm[b][0]);           \
      STAGE_TILE128(Wqhi + (size_t)n0   * D_DIM + (k0), sm[b][1]);           \
    } while (0)

    STAGE_A(0, 0);
    __syncthreads();
    int cur = 0;
    // phase A: acc += xh*Wqh + xh*Wql
    for (int k0 = 0; k0 < D_DIM; k0 += 32) {
      if (k0 + 32 < D_DIM) STAGE_A(k0 + 32, cur ^ 1);
      else                 STAGE_B(0, cur ^ 1);       // bridge into phase B
      bf16x8 af[4], bh0[4], bl0[4];
      #pragma unroll
      for (int mi = 0; mi < 4; ++mi)
        af[mi] = FRAG(sm[cur][0], wr * 64 + mi * 16 + lm);
      #pragma unroll
      for (int ni = 0; ni < 4; ++ni) {
        bh0[ni] = FRAG(sm[cur][1], wc * 64 + ni * 16 + lm);
        bl0[ni] = FRAG(sm[cur][2], wc * 64 + ni * 16 + lm);
      }
      #pragma unroll
      for (int mi = 0; mi < 4; ++mi)
        #pragma unroll
        for (int ni = 0; ni < 4; ++ni) {
          acc[mi][ni] = __builtin_amdgcn_mfma_f32_16x16x32_bf16(af[mi], bh0[ni], acc[mi][ni], 0, 0, 0);
          acc[mi][ni] = __builtin_amdgcn_mfma_f32_16x16x32_bf16(af[mi], bl0[ni], acc[mi][ni], 0, 0, 0);
        }
      __syncthreads();
      cur ^= 1;
    }
    // phase B: acc += xl*Wqh
    for (int k0 = 0; k0 < D_DIM; k0 += 32) {
      if (k0 + 32 < D_DIM) STAGE_B(k0 + 32, cur ^ 1);
      bf16x8 af[4], bh0[4];
      #pragma unroll
      for (int mi = 0; mi < 4; ++mi)
        af[mi] = FRAG(sm[cur][0], wr * 64 + mi * 16 + lm);
      #pragma unroll
      for (int ni = 0; ni < 4; ++ni)
        bh0[ni] = FRAG(sm[cur][1], wc * 64 + ni * 16 + lm);
      #pragma unroll
      for (int mi = 0; mi < 4; ++mi)
        #pragma unroll
        for (int ni = 0; ni < 4; ++ni)
          acc[mi][ni] = __builtin_amdgcn_mfma_f32_16x16x32_bf16(af[mi], bh0[ni], acc[mi][ni], 0, 0, 0);
      __syncthreads();
      cur ^= 1;
    }

    float bvv[4];
    #pragma unroll
    for (int ni = 0; ni < 4; ++ni) bvv[ni] = bq[n0 + wc * 64 + ni * 16 + lm];
    #pragma unroll
    for (int mi = 0; mi < 4; ++mi)
      #pragma unroll
      for (int ni = 0; ni < 4; ++ni)
        #pragma unroll
        for (int r = 0; r < 4; ++r) acc[mi][ni][r] += bvv[ni];

    const int h = (n0 + wc * 64) >> 6;
    #pragma unroll
    for (int mi = 0; mi < 4; ++mi)
      #pragma unroll
      for (int r = 0; r < 4; ++r) {
        float s = 0.f;
        #pragma unroll
        for (int ni = 0; ni < 4; ++ni) { float v = acc[mi][ni][r]; s += v * v; }
        s += __shfl_xor(s, 1); s += __shfl_xor(s, 2);
        s += __shfl_xor(s, 4); s += __shfl_xor(s, 8);
        if (lm == 0) {
          int row = row0 + wr * 64 + mi * 16 + quad * 4 + r;
          int bb = row >> 11, ll = row & (L_DIM - 1);
          norms[(bb * H_DIM + h) * L_DIM + ll] = s;
        }
      }

    #pragma unroll
    for (int mi = 0; mi < 4; ++mi)
      #pragma unroll
      for (int r = 0; r < 4; ++r) {
        int row = row0 + wr * 64 + mi * 16 + quad * 4 + r;
        #pragma unroll
        for (int ni = 0; ni < 4; ++ni)
          Qhi[(size_t)row * D_DIM + n0 + wc * 64 + ni * 16 + lm] = (bf16_t)acc[mi][ni][r];
      }
  } else {
    const bf16_t* W = (z == 1) ? Wkb : Wvb;
#define STAGE_L(k0, b) do {                                                  \
      STAGE_TILE128(xhi + (size_t)row0 * D_DIM + (k0), sm[b][0]);            \
      STAGE_TILE128(W   + (size_t)n0   * D_DIM + (k0), sm[b][1]);            \
    } while (0)

    STAGE_L(0, 0);
    __syncthreads();
    int cur = 0;
    for (int k0 = 0; k0 < D_DIM; k0 += 32) {
      if (k0 + 32 < D_DIM) STAGE_L(k0 + 32, cur ^ 1);
      bf16x8 af[4], bfr[4];
      #pragma unroll
      for (int mi = 0; mi < 4; ++mi)
        af[mi] = FRAG(sm[cur][0], wr * 64 + mi * 16 + lm);
      #pragma unroll
      for (int ni = 0; ni < 4; ++ni)
        bfr[ni] = FRAG(sm[cur][1], wc * 64 + ni * 16 + lm);
      #pragma unroll
      for (int mi = 0; mi < 4; ++mi)
        #pragma unroll
        for (int ni = 0; ni < 4; ++ni)
          acc[mi][ni] = __builtin_amdgcn_mfma_f32_16x16x32_bf16(af[mi], bfr[ni], acc[mi][ni], 0, 0, 0);
      __syncthreads();
      cur ^= 1;
    }

    const float* bias = (z == 1) ? bk : bv;
    float bvv[4];
    #pragma unroll
    for (int ni = 0; ni < 4; ++ni) bvv[ni] = bias[n0 + wc * 64 + ni * 16 + lm];
    #pragma unroll
    for (int mi = 0; mi < 4; ++mi)
      #pragma unroll
      for (int ni = 0; ni < 4; ++ni)
        #pragma unroll
        for (int r = 0; r < 4; ++r) acc[mi][ni][r] += bvv[ni];

    const int hh = (n0 + wc * 64) >> 6;   // head 0..15
    if (z == 1) {
      // Khead[b][h][l][64]
      #pragma unroll
      for (int mi = 0; mi < 4; ++mi)
        #pragma unroll
        for (int r = 0; r < 4; ++r) {
          int row = row0 + wr * 64 + mi * 16 + quad * 4 + r;
          int bb = row >> 11, ll = row & (L_DIM - 1);
          size_t base = (size_t)(bb * H_DIM + hh) * HSZ + (size_t)ll * 64;
          #pragma unroll
          for (int ni = 0; ni < 4; ++ni)
            Khi[base + ni * 16 + lm] = (bf16_t)acc[mi][ni][r];
        }
    } else {
      // V key-tiled: [(b,h)][kb=l/32][d][32]
      #pragma unroll
      for (int mi = 0; mi < 4; ++mi) {
        int rbase = row0 + wr * 64 + mi * 16 + quad * 4;
        int bb = rbase >> 11, l0 = rbase & (L_DIM - 1);
        int kbv = l0 >> 5, kin = l0 & 31;
        size_t hb = (size_t)(bb * H_DIM + hh) * HSZ;
        #pragma unroll
        for (int ni = 0; ni < 4; ++ni) {
          int d = ni * 16 + lm;
          bf16x4 wv;
          #pragma unroll
          for (int r = 0; r < 4; ++r) wv[r] = (bf16_t)acc[mi][ni][r];
          *reinterpret_cast<bf16x4*>(&VThi[hb + (size_t)(kbv * 64 + d) * 32 + kin]) = wv;
        }
      }
    }
  }
}

// ---------------------------------------------------------------------------
// Output projection: 64x128 tiles, grid (8,64) = 2 blocks/CU, prefetch dbuf.
// ---------------------------------------------------------------------------
__global__ __launch_bounds__(256) void gemm_out(
    const bf16_t* __restrict__ Ahi, const bf16_t* __restrict__ Wob,
    const float* __restrict__ bias, float* __restrict__ C)
{
  const int n0   = blockIdx.x * 128;
  const int row0 = blockIdx.y * 64;

  __shared__ __align__(16) bf16_t sm[2][6144];   // 24 KB: dbuf x (A64 + B128)

  const int tid  = threadIdx.x;
  const int lane = tid & 63;
  const int wave = tid >> 6;
  const int wr = wave >> 1, wc = wave & 1;
  const int lm = lane & 15, quad = lane >> 4;

  const f32x4 vzero = {0.f, 0.f, 0.f, 0.f};
  f32x4 acc[2][4];
  #pragma unroll
  for (int mi = 0; mi < 2; ++mi)
    #pragma unroll
    for (int ni = 0; ni < 4; ++ni) acc[mi][ni] = vzero;

#define STAGE_O(k0, b) do {                                                  \
    STAGE_TILE64(Ahi + (size_t)row0 * D_DIM + (k0), sm[b]);                  \
    STAGE_TILE128(Wob + (size_t)n0 * D_DIM + (k0), sm[b] + 2048);            \
  } while (0)

  STAGE_O(0, 0);
  __syncthreads();
  int cur = 0;
  for (int k0 = 0; k0 < D_DIM; k0 += 32) {
    if (k0 + 32 < D_DIM) STAGE_O(k0 + 32, cur ^ 1);
    bf16x8 af[2], bfr[4];
    #pragma unroll
    for (int mi = 0; mi < 2; ++mi)
      af[mi] = FRAG(sm[cur], wr * 32 + mi * 16 + lm);
    #pragma unroll
    for (int ni = 0; ni < 4; ++ni)
      bfr[ni] = FRAG(sm[cur] + 2048, wc * 64 + ni * 16 + lm);
    #pragma unroll
    for (int mi = 0; mi < 2; ++mi)
      #pragma unroll
      for (int ni = 0; ni < 4; ++ni)
        acc[mi][ni] = __builtin_amdgcn_mfma_f32_16x16x32_bf16(af[mi], bfr[ni], acc[mi][ni], 0, 0, 0);
    __syncthreads();
    cur ^= 1;
  }

  float bvv[4];
  #pragma unroll
  for (int ni = 0; ni < 4; ++ni) bvv[ni] = bias[n0 + wc * 64 + ni * 16 + lm];
  #pragma unroll
  for (int mi = 0; mi < 2; ++mi)
    #pragma unroll
    for (int r = 0; r < 4; ++r) {
      int row = row0 + wr * 32 + mi * 16 + quad * 4 + r;
      #pragma unroll
      for (int ni = 0; ni < 4; ++ni)
        C[(size_t)row * D_DIM + n0 + wc * 64 + ni * 16 + lm] = acc[mi][ni][r] + bvv[ni];
    }
}

// ---------------------------------------------------------------------------
// Exact top-409 per (b,h) via 4-pass 8-bit radix select on f32 bits
// (norms >= 0 so uint ordering == float ordering), then ballot-prefix
// write-out. Set matches lax.top_k exactly: all keys > T, plus the
// (KTOP - count_gt) smallest-index keys == T.
// ---------------------------------------------------------------------------
__global__ __launch_bounds__(1024) void topk_kernel(
    const float* __restrict__ norms, int* __restrict__ sel)
{
  const int bh = blockIdx.x;
  const int t  = threadIdx.x;
  const int w  = t >> 6;            // wave 0..15
  const int lane = t & 63;

  __shared__ int bins[256];
  __shared__ unsigned int sh_pfx;
  __shared__ int cnt0[16], cnt1[16], ecnt0[16], ecnt1[16];

  // two keys per thread, index order: k0 -> index t, k1 -> index t+1024
  const unsigned int k0 = __float_as_uint(norms[bh * L_DIM + t]);
  const unsigned int k1 = __float_as_uint(norms[bh * L_DIM + t + 1024]);

  // ---- find T = KTOP-th largest key (exact, 4 passes of 8 bits) ----
  unsigned int pfx = 0;   // high bits fixed so far (in low positions)
  int r = KTOP;           // rank remaining among qualifying keys
  #pragma unroll
  for (int p = 0; p < 4; ++p) {
    const int sh = 24 - 8 * p;
    if (t < 256) bins[t] = 0;
    __syncthreads();
    const bool q0 = (p == 0) || ((k0 >> (sh + 8)) == pfx);
    const bool q1 = (p == 0) || ((k1 >> (sh + 8)) == pfx);
    if (q0) atomicAdd(&bins[(k0 >> sh) & 255], 1);
    if (q1) atomicAdd(&bins[(k1 >> sh) & 255], 1);
    __syncthreads();
    if (t == 0) {
      int cum = 0, B = 0;
      for (int v = 255; v >= 0; --v) {
        int c = bins[v];
        if (cum + c >= r) { B = v; r -= cum; break; }
        cum += c;
      }
      sh_pfx = (pfx << 8) | (unsigned int)B;
      bins[0] = r;          // reuse as broadcast slot (post-barrier read)
    }
    __syncthreads();
    pfx = sh_pfx;
    r = bins[0];
    __syncthreads();
  }
  const unsigned int T = pfx;

  // ---- selection write-out ----
  const bool gt0 = (k0 > T), gt1 = (k1 > T);
  const bool eq0 = (k0 == T), eq1 = (k1 == T);
  const unsigned long long mlt = (lane == 63) ? 0x7fffffffffffffffull
                                              : ((1ull << lane) - 1ull);
  const unsigned long long bg0 = __ballot(gt0);
  const unsigned long long bg1 = __ballot(gt1);
  const unsigned long long be0 = __ballot(eq0);
  const unsigned long long be1 = __ballot(eq1);
  if (lane == 0) {
    cnt0[w]  = __popcll(bg0);
    cnt1[w]  = __popcll(bg1);
    ecnt0[w] = __popcll(be0);
    ecnt1[w] = __popcll(be1);
  }
  __syncthreads();
  int og0 = 0, og1 = 0, oe0 = 0, oe1 = 0;
  int tg0 = 0, tg1 = 0, te0 = 0;
  #pragma unroll
  for (int i = 0; i < 16; ++i) {
    if (i < w) { og0 += cnt0[i]; og1 += cnt1[i]; oe0 += ecnt0[i]; oe1 += ecnt1[i]; }
    tg0 += cnt0[i]; tg1 += cnt1[i]; te0 += ecnt0[i];
  }
  const int G = tg0 + tg1;          // total keys > T (G < KTOP)
  const int take = KTOP - G;        // ties to take, earliest index first
  const int base = bh * SLOTS;

  if (gt0) sel[base + og0 + __popcll(bg0 & mlt)] = t;
  if (gt1) sel[base + tg0 + og1 + __popcll(bg1 & mlt)] = t + 1024;
  if (eq0) {
    int rk = oe0 + __popcll(be0 & mlt);
    if (rk < take) sel[base + G + rk] = t;
  }
  if (eq1) {
    int rk = te0 + oe1 + __popcll(be1 & mlt);
    if (rk < take) sel[base + G + rk] = t + 1024;
  }
  if (t < SLOTS - KTOP) sel[base + KTOP + t] = -1;
}

// ---------------------------------------------------------------------------
// K-split flash attention — TWO 16-slot q-tiles per wave (32 slots).
// K/V loads are shared across both tiles -> MFMA:load ratio doubles (16:8,
// was 8:8) to attack the issue/latency bound. K per-head [b][h][L][64];
// V key-tiled [(b,h)][kb][d][32]. XCD-affinity block swizzle (4 qc-siblings
// per chunk on one XCD). Grid 1024 = 4 blocks/CU.
// ---------------------------------------------------------------------------
__global__ __launch_bounds__(256) void attn_kernel(
    const bf16_t* __restrict__ Qhi,
    const bf16_t* __restrict__ Khi,
    const bf16_t* __restrict__ VThi,
    const int* __restrict__ sel,
    float* __restrict__ Ol, bf16_t* __restrict__ Oo)
{
  const int bx = blockIdx.x;
  const int xl = bx & 7;          // XCD id under default round-robin
  const int rest = bx >> 3;       // 0..127
  const int qc = rest & 3;
  const int gh = rest >> 2;       // 0..31
  const int g  = gh * 8 + xl;     // K/V-chunk group 0..255
  const int bh = g & 31;
  const int ks = g >> 5;
  const int b = bh >> 4, h = bh & 15;
  const int wave = threadIdx.x >> 6;
  const int lane = threadIdx.x & 63;
  const int lm = lane & 15, quad = lane >> 4;

  __shared__ __align__(16) bf16_t sPh[2][2][4][16][40];  // [PB][qt][wave][r][c]

  const int qbase = qc * 128 + wave * 32;   // tile qt covers +qt*16
  bf16x8 qa[2][2];
  #pragma unroll
  for (int qt = 0; qt < 2; ++qt) {
    int qi = sel[bh * SLOTS + qbase + qt * 16 + lm];
    size_t qo = ((size_t)(b * L_DIM + (qi >= 0 ? qi : 0))) * D_DIM + h * 64;
    qa[qt][0] = *reinterpret_cast<const bf16x8*>(&Qhi[qo + quad * 8]);
    qa[qt][1] = *reinterpret_cast<const bf16x8*>(&Qhi[qo + 32 + quad * 8]);
  }

  const f32x4 vzero = {0.f, 0.f, 0.f, 0.f};
  float l_l[2][4];
  f32x4 o[2][4];
  #pragma unroll
  for (int qt = 0; qt < 2; ++qt)
    #pragma unroll
    for (int ni = 0; ni < 4; ++ni) { o[qt][ni] = vzero; l_l[qt][ni] = 0.f; }

  const float scale = 0.125f;
  const size_t khead = (size_t)(b * H_DIM + h) * HSZ;
  const int key0 = ks * KCHUNK;

  #pragma unroll 2
  for (int kt = 0; kt < KCHUNK; kt += 32) {
    const int PB = (kt >> 5) & 1;
    size_t kr0 = khead + (size_t)(key0 + kt + lm) * 64;
    size_t kr1 = khead + (size_t)(key0 + kt + 16 + lm) * 64;
    bf16x8 kb0 = *reinterpret_cast<const bf16x8*>(&Khi[kr0 + quad * 8]);
    bf16x8 kb1 = *reinterpret_cast<const bf16x8*>(&Khi[kr0 + 32 + quad * 8]);
    bf16x8 kb2 = *reinterpret_cast<const bf16x8*>(&Khi[kr1 + quad * 8]);
    bf16x8 kb3 = *reinterpret_cast<const bf16x8*>(&Khi[kr1 + 32 + quad * 8]);
    const int kbv = (key0 + kt) >> 5;
    bf16x8 vbh[4];
    #pragma unroll
    for (int ni = 0; ni < 4; ++ni) {
      size_t vo = khead + (size_t)(kbv * 64 + ni * 16 + lm) * 32 + quad * 8;
      vbh[ni] = *reinterpret_cast<const bf16x8*>(&VThi[vo]);
    }
    #pragma unroll
    for (int qt = 0; qt < 2; ++qt) {
      f32x4 s0 = vzero, s1 = vzero;
      s0 = __builtin_amdgcn_mfma_f32_16x16x32_bf16(qa[qt][0], kb0, s0, 0, 0, 0);
      s0 = __builtin_amdgcn_mfma_f32_16x16x32_bf16(qa[qt][1], kb1, s0, 0, 0, 0);
      s1 = __builtin_amdgcn_mfma_f32_16x16x32_bf16(qa[qt][0], kb2, s1, 0, 0, 0);
      s1 = __builtin_amdgcn_mfma_f32_16x16x32_bf16(qa[qt][1], kb3, s1, 0, 0, 0);
      #pragma unroll
      for (int r = 0; r < 4; ++r) {
        float p0 = __expf(s0[r] * scale);
        float p1 = __expf(s1[r] * scale);
        l_l[qt][r] += p0 + p1;
        sPh[PB][qt][wave][quad * 4 + r][lm]      = (bf16_t)p0;
        sPh[PB][qt][wave][quad * 4 + r][16 + lm] = (bf16_t)p1;
      }
      bf16x8 pah = *reinterpret_cast<const bf16x8*>(&sPh[PB][qt][wave][lm][quad * 8]);
      #pragma unroll
      for (int ni = 0; ni < 4; ++ni)
        o[qt][ni] = __builtin_amdgcn_mfma_f32_16x16x32_bf16(pah, vbh[ni], o[qt][ni], 0, 0, 0);
    }
  }

  #pragma unroll
  for (int qt = 0; qt < 2; ++qt)
    #pragma unroll
    for (int r = 0; r < 4; ++r) {
      l_l[qt][r] += __shfl_xor(l_l[qt][r], 1);
      l_l[qt][r] += __shfl_xor(l_l[qt][r], 2);
      l_l[qt][r] += __shfl_xor(l_l[qt][r], 4);
      l_l[qt][r] += __shfl_xor(l_l[qt][r], 8);
    }

  #pragma unroll
  for (int qt = 0; qt < 2; ++qt)
    #pragma unroll
    for (int r = 0; r < 4; ++r) {
      int slot = qbase + qt * 16 + quad * 4 + r;
      int s2 = sel[bh * SLOTS + slot];
      if (s2 >= 0) {
        size_t gs = (size_t)(bh * SLOTS_IO + slot) * KSPLIT + ks;
        if (lm == 0) Ol[gs] = l_l[qt][r];
        #pragma unroll
        for (int ni = 0; ni < 4; ++ni)
          Oo[gs * 64 + ni * 16 + lm] = (bf16_t)o[qt][ni][r];
      }
    }
}

// ---------------------------------------------------------------------------
// Combine ksplit partials -> AO (selected rows; meanfill covered the rest).
// ---------------------------------------------------------------------------
__global__ __launch_bounds__(256) void combine_kernel(
    const float* __restrict__ Ol, const bf16_t* __restrict__ Oo,
    const int* __restrict__ sel, bf16_t* __restrict__ AOhi)
{
  const int bh = blockIdx.x;
  const int b = bh >> 4, h = bh & 15;
  const int chunk = blockIdx.y;
  const int tid = threadIdx.x;
  const int dim = tid & 63;
  const int sl  = tid >> 6;
  #pragma unroll
  for (int p = 0; p < 4; ++p) {
    int slot = chunk * 16 + p * 4 + sl;
    int qi = sel[bh * SLOTS + slot];
    if (qi < 0) continue;
    size_t gs = (size_t)(bh * SLOTS_IO + slot) * KSPLIT;
    float L = 0.f, ov = 0.f;
    #pragma unroll
    for (int s = 0; s < KSPLIT; ++s) {
      L  += Ol[gs + s];
      ov += (float)Oo[(gs + s) * 64 + dim];
    }
    AOhi[((size_t)(b * L_DIM + qi)) * D_DIM + h * 64 + dim] = (bf16_t)(ov / L);
  }
}

// ---------------------------------------------------------------------------
// mean(V) to EVERY AO row; combine overwrites selected rows.
// V is key-tiled: [(b,h)][kb][d][32].
// ---------------------------------------------------------------------------
__global__ __launch_bounds__(256) void meanfill_kernel(
    const bf16_t* __restrict__ VThi, bf16_t* __restrict__ AOhi)
{
  const int bh = blockIdx.x;
  const int b = bh >> 4, h = bh & 15;
  const int t = threadIdx.x;
  __shared__ __align__(16) bf16_t smh[64];
  {
    const int hd = t >> 2, part = t & 3;
    size_t hbase = (size_t)(b * H_DIM + h) * HSZ;
    float s = 0.f;
    for (int kb = part * 16; kb < part * 16 + 16; ++kb) {
      size_t a = hbase + (size_t)(kb * 64 + hd) * 32;
      bf16x8 v0 = *reinterpret_cast<const bf16x8*>(&VThi[a]);
      bf16x8 v1 = *reinterpret_cast<const bf16x8*>(&VThi[a + 8]);
      bf16x8 v2 = *reinterpret_cast<const bf16x8*>(&VThi[a + 16]);
      bf16x8 v3 = *reinterpret_cast<const bf16x8*>(&VThi[a + 24]);
      #pragma unroll
      for (int j = 0; j < 8; ++j)
        s += (float)v0[j] + (float)v1[j] + (float)v2[j] + (float)v3[j];
    }
    s += __shfl_xor(s, 1);
    s += __shfl_xor(s, 2);
    if (part == 0) smh[hd] = (bf16_t)(s * (1.0f / (float)L_DIM));
  }
  __syncthreads();
  const int lbase = blockIdx.y * 256;
  for (int i = t; i < 256 * 64; i += 256) {
    int l = lbase + (i >> 6), hd = i & 63;
    AOhi[((size_t)(b * L_DIM + l)) * D_DIM + h * 64 + hd] = smh[hd];
  }
}

// ---------------------------------------------------------------------------
extern "C" void kernel_launch(void* const* d_in, const int* in_sizes, int n_in,
                              void* d_out, int out_size, void* d_ws, size_t ws_size,
                              hipStream_t stream) {
  const float* x  = (const float*)d_in[0];
  const float* Wq = (const float*)d_in[1];
  const float* bq = (const float*)d_in[2];
  const float* Wk = (const float*)d_in[3];
  const float* bk = (const float*)d_in[4];
  const float* Wv = (const float*)d_in[5];
  const float* bv = (const float*)d_in[6];
  const float* Wo = (const float*)d_in[7];
  const float* bo = (const float*)d_in[8];
  float* out = (float*)d_out;

  // ws layout (~43 MB):
  //  [0,8)    Qhi  (aliased as AOhi after attn)
  //  [8,16)   VThi (key-tiled per-head layout)
  //  [16,24)  xhi  -+ dead after gemm_qkv; [16,32) reused for Oo (bf16, 14.7MB
  //  [24,32)  xlo  -+  at SLOTS_IO=448 stride)
  //  [32,34)  Wqhi  [34,36) Wqlo  [36,38) Wkb  [38,40) Wvb  [40,42) Wob
  //  [42,..)  norms (256 KB), sel (64 KB), Ol (458 KB)
  // Khi (per-head layout) lives in d_out (8 of 16 MB) — dead until gemm_out.
  const size_t MB = 1u << 20;
  char* ws = (char*)d_ws;
  bf16_t* Qhi  = (bf16_t*)(ws);
  bf16_t* VThi = (bf16_t*)(ws + 8 * MB);
  bf16_t* xhi  = (bf16_t*)(ws + 16 * MB);
  bf16_t* xlo  = (bf16_t*)(ws + 24 * MB);
  bf16_t* Oo   = (bf16_t*)(ws + 16 * MB);         // aliases xhi/xlo
  bf16_t* Wqhi = (bf16_t*)(ws + 32 * MB);
  bf16_t* Wqlo = (bf16_t*)(ws + 34 * MB);
  bf16_t* Wkb  = (bf16_t*)(ws + 36 * MB);
  bf16_t* Wvb  = (bf16_t*)(ws + 38 * MB);
  bf16_t* Wob  = (bf16_t*)(ws + 40 * MB);
  float*  norms = (float*)(ws + 42 * MB);
  int*    sel   = (int*)(ws + 42 * MB + (256u << 10));
  float*  Ol    = (float*)(ws + 42 * MB + (320u << 10));
  bf16_t* AOhi = Qhi;
  bf16_t* Khi = (bf16_t*)d_out;

  dim3 blk(256);
  prep_kernel<<<dim3(2048), blk, 0, stream>>>(x, Wq, Wk, Wv, Wo,
                                              xhi, xlo, Wqhi, Wqlo, Wkb, Wvb, Wob);
  gemm_qkv<<<dim3(768), blk, 0, stream>>>(xhi, xlo, Wqhi, Wqlo, Wkb, Wvb,
                                          bq, bk, bv, Qhi, Khi, VThi, norms);
  topk_kernel<<<dim3(32), dim3(1024), 0, stream>>>(norms, sel);
  attn_kernel<<<dim3(32 * 4 * KSPLIT), blk, 0, stream>>>(Qhi, Khi, VThi, sel, Ol, Oo);
  meanfill_kernel<<<dim3(32, 8), blk, 0, stream>>>(VThi, AOhi);
  combine_kernel<<<dim3(32, 32), blk, 0, stream>>>(Ol, Oo, sel, AOhi);
  gemm_out<<<dim3(8, 64), blk, 0, stream>>>(AOhi, Wob, bo, out);
}

// Round 9
// 255.713 us; speedup vs baseline: 1.0739x; 1.0022x over previous
//
#include <hip/hip_runtime.h>
#include <hip/hip_bf16.h>
#include <math.h>

typedef __bf16 bf16_t;
typedef __bf16 bf16x8 __attribute__((ext_vector_type(8)));
typedef __bf16 bf16x4 __attribute__((ext_vector_type(4)));
typedef float  f32x4  __attribute__((ext_vector_type(4)));

#define L_DIM 2048
#define D_DIM 1024
#define H_DIM 16
#define M_DIM 4096
#define KTOP 409
#define SLOTS 512      // sel padding (256-slot q-chunks; sel = -1 beyond KTOP)
#define SLOTS_IO 448   // Oo/Ol stride (real slots < 448) — keeps 16MB window
#define KSPLIT 8
#define KCHUNK 256     // L_DIM / KSPLIT
#define HSZ (L_DIM * 64)   // elements per (b,h) head block = 131072

// split f32 into bf16 hi + bf16 lo (a ~= hi + lo)
__device__ __forceinline__ void split2(float a, bf16_t& h, bf16_t& l) {
  h = (bf16_t)a;
  l = (bf16_t)(a - (float)h);
}

// async global -> LDS, 16B per lane; lds ptr must be wave-uniform (m104/m108)
__device__ __forceinline__ void gld16(const bf16_t* g, bf16_t* l) {
  __builtin_amdgcn_global_load_lds(
      (const __attribute__((address_space(1))) void*)g,
      (__attribute__((address_space(3))) void*)l, 16, 0, 0);
}

// LDS source-side XOR swizzle (rule #21; kept from r8 — perf-neutral, verified)
#define STAGE_TILE128(src, dst)                                               \
  {                                                                           \
    const int seg0 = wave * 2;                                                \
    const int r0 = seg0 * 16 + (lane >> 2);                                   \
    const int c0 = (((lane & 3) ^ ((lane >> 2) & 3))) * 8;                    \
    gld16((src) + (size_t)r0 * D_DIM + c0, (dst) + seg0 * 512);               \
    gld16((src) + (size_t)(r0 + 16) * D_DIM + c0, (dst) + (seg0 + 1) * 512);  \
  }

#define STAGE_TILE64(src, dst)                                                \
  {                                                                           \
    const int r0 = wave * 16 + (lane >> 2);                                   \
    const int c0 = (((lane & 3) ^ ((lane >> 2) & 3))) * 8;                    \
    gld16((src) + (size_t)r0 * D_DIM + c0, (dst) + wave * 512);               \
  }

#define FRAG(buf, ROW) \
  (*reinterpret_cast<const bf16x8*>(&(buf)[(ROW) * 32 + (quad ^ (lm & 3)) * 8]))

// ---------------------------------------------------------------------------
// prep: pre-split x and Wq into bf16 hi/lo; pre-round Wk/Wv/Wo to bf16.
// Also zeroes the Vmean accumulator (2048 f32 = 512 f32x4 items).
// ---------------------------------------------------------------------------
__global__ __launch_bounds__(256) void prep_kernel(
    const float* __restrict__ x,  const float* __restrict__ Wq,
    const float* __restrict__ Wk, const float* __restrict__ Wv,
    const float* __restrict__ Wo,
    bf16_t* __restrict__ xhi, bf16_t* __restrict__ xlo,
    bf16_t* __restrict__ Wqhi, bf16_t* __restrict__ Wqlo,
    bf16_t* __restrict__ Wkb,  bf16_t* __restrict__ Wvb,
    bf16_t* __restrict__ Wob,  float* __restrict__ Vmeanf)
{
  const int XV = (M_DIM * D_DIM) / 4;
  const int WV = (D_DIM * D_DIM) / 4;
  const int TOT = XV + 4 * WV + 512;
  for (int i = blockIdx.x * 256 + threadIdx.x; i < TOT; i += gridDim.x * 256) {
    if (i < XV) {
      f32x4 v = ((const f32x4*)x)[i];
      bf16x4 h, l;
      #pragma unroll
      for (int j = 0; j < 4; ++j) { bf16_t hh, ll; split2(v[j], hh, ll); h[j] = hh; l[j] = ll; }
      ((bf16x4*)xhi)[i] = h;
      ((bf16x4*)xlo)[i] = l;
    } else if (i < XV + WV) {
      int j0 = i - XV;
      f32x4 v = ((const f32x4*)Wq)[j0];
      bf16x4 h, l;
      #pragma unroll
      for (int j = 0; j < 4; ++j) { bf16_t hh, ll; split2(v[j], hh, ll); h[j] = hh; l[j] = ll; }
      ((bf16x4*)Wqhi)[j0] = h;
      ((bf16x4*)Wqlo)[j0] = l;
    } else if (i < XV + 2 * WV) {
      int j0 = i - XV - WV;
      f32x4 v = ((const f32x4*)Wk)[j0];
      bf16x4 h;
      #pragma unroll
      for (int j = 0; j < 4; ++j) h[j] = (bf16_t)v[j];
      ((bf16x4*)Wkb)[j0] = h;
    } else if (i < XV + 3 * WV) {
      int j0 = i - XV - 2 * WV;
      f32x4 v = ((const f32x4*)Wv)[j0];
      bf16x4 h;
      #pragma unroll
      for (int j = 0; j < 4; ++j) h[j] = (bf16_t)v[j];
      ((bf16x4*)Wvb)[j0] = h;
    } else if (i < XV + 4 * WV) {
      int j0 = i - XV - 3 * WV;
      f32x4 v = ((const f32x4*)Wo)[j0];
      bf16x4 h;
      #pragma unroll
      for (int j = 0; j < 4; ++j) h[j] = (bf16_t)v[j];
      ((bf16x4*)Wob)[j0] = h;
    } else {
      int j0 = i - XV - 4 * WV;           // 0..511
      f32x4 zz = {0.f, 0.f, 0.f, 0.f};
      ((f32x4*)Vmeanf)[j0] = zz;
    }
  }
}

// ---------------------------------------------------------------------------
// Fused QKV projections — r5 structure (measured best, 3 blocks/CU).
// z0 split into A/B phases at 48 KB LDS, prefetch dbuf.
// K written per-head [b][h][L][64]; V key-tiled [(b,h)][kb][d][32].
// z2 epilogue also accumulates column-sums of V into Vmeanf (f32 atomics,
// quad-reduced first) — replaces meanfill's 64MB redundant V re-reads.
// ---------------------------------------------------------------------------
__global__ __launch_bounds__(256, 3) void gemm_qkv(
    const bf16_t* __restrict__ xhi, const bf16_t* __restrict__ xlo,
    const bf16_t* __restrict__ Wqhi, const bf16_t* __restrict__ Wqlo,
    const bf16_t* __restrict__ Wkb, const bf16_t* __restrict__ Wvb,
    const float* __restrict__ bq, const float* __restrict__ bk, const float* __restrict__ bv,
    bf16_t* __restrict__ Qhi, bf16_t* __restrict__ Khi, bf16_t* __restrict__ VThi,
    float* __restrict__ norms, float* __restrict__ Vmeanf)
{
  const int bx = blockIdx.x;
  const int z  = bx % 3;          // interleaved so each CU gets a z-mix
  const int id = bx / 3;          // 0..255
  const int n0   = (id & 7) * 128;
  const int row0 = (id >> 3) * 128;

  __shared__ __align__(16) bf16_t sm[2][3][4096];   // 48 KB: dbuf x 3 tiles

  const int tid  = threadIdx.x;
  const int lane = tid & 63;
  const int wave = tid >> 6;
  const int wr = wave >> 1, wc = wave & 1;
  const int lm = lane & 15, quad = lane >> 4;

  const f32x4 vzero = {0.f, 0.f, 0.f, 0.f};
  f32x4 acc[4][4];
  #pragma unroll
  for (int mi = 0; mi < 4; ++mi)
    #pragma unroll
    for (int ni = 0; ni < 4; ++ni) acc[mi][ni] = vzero;

  if (z == 0) {
#define STAGE_A(k0, b) do {                                                  \
      STAGE_TILE128(xhi  + (size_t)row0 * D_DIM + (k0), sm[b][0]);           \
      STAGE_TILE128(Wqhi + (size_t)n0   * D_DIM + (k0), sm[b][1]);           \
      STAGE_TILE128(Wqlo + (size_t)n0   * D_DIM + (k0), sm[b][2]);           \
    } while (0)
#define STAGE_B(k0, b) do {                                                  \
      STAGE_TILE128(xlo  + (size_t)row0 * D_DIM + (k0), sm[b][0]);           \
      STAGE_TILE128(Wqhi + (size_t)n0   * D_DIM + (k0), sm[b][1]);           \
    } while (0)

    STAGE_A(0, 0);
    __syncthreads();
    int cur = 0;
    // phase A: acc += xh*Wqh + xh*Wql
    for (int k0 = 0; k0 < D_DIM; k0 += 32) {
      if (k0 + 32 < D_DIM) STAGE_A(k0 + 32, cur ^ 1);
      else                 STAGE_B(0, cur ^ 1);       // bridge into phase B
      bf16x8 af[4], bh0[4], bl0[4];
      #pragma unroll
      for (int mi = 0; mi < 4; ++mi)
        af[mi] = FRAG(sm[cur][0], wr * 64 + mi * 16 + lm);
      #pragma unroll
      for (int ni = 0; ni < 4; ++ni) {
        bh0[ni] = FRAG(sm[cur][1], wc * 64 + ni * 16 + lm);
        bl0[ni] = FRAG(sm[cur][2], wc * 64 + ni * 16 + lm);
      }
      #pragma unroll
      for (int mi = 0; mi < 4; ++mi)
        #pragma unroll
        for (int ni = 0; ni < 4; ++ni) {
          acc[mi][ni] = __builtin_amdgcn_mfma_f32_16x16x32_bf16(af[mi], bh0[ni], acc[mi][ni], 0, 0, 0);
          acc[mi][ni] = __builtin_amdgcn_mfma_f32_16x16x32_bf16(af[mi], bl0[ni], acc[mi][ni], 0, 0, 0);
        }
      __syncthreads();
      cur ^= 1;
    }
    // phase B: acc += xl*Wqh
    for (int k0 = 0; k0 < D_DIM; k0 += 32) {
      if (k0 + 32 < D_DIM) STAGE_B(k0 + 32, cur ^ 1);
      bf16x8 af[4], bh0[4];
      #pragma unroll
      for (int mi = 0; mi < 4; ++mi)
        af[mi] = FRAG(sm[cur][0], wr * 64 + mi * 16 + lm);
      #pragma unroll
      for (int ni = 0; ni < 4; ++ni)
        bh0[ni] = FRAG(sm[cur][1], wc * 64 + ni * 16 + lm);
      #pragma unroll
      for (int mi = 0; mi < 4; ++mi)
        #pragma unroll
        for (int ni = 0; ni < 4; ++ni)
          acc[mi][ni] = __builtin_amdgcn_mfma_f32_16x16x32_bf16(af[mi], bh0[ni], acc[mi][ni], 0, 0, 0);
      __syncthreads();
      cur ^= 1;
    }

    float bvv[4];
    #pragma unroll
    for (int ni = 0; ni < 4; ++ni) bvv[ni] = bq[n0 + wc * 64 + ni * 16 + lm];
    #pragma unroll
    for (int mi = 0; mi < 4; ++mi)
      #pragma unroll
      for (int ni = 0; ni < 4; ++ni)
        #pragma unroll
        for (int r = 0; r < 4; ++r) acc[mi][ni][r] += bvv[ni];

    const int h = (n0 + wc * 64) >> 6;
    #pragma unroll
    for (int mi = 0; mi < 4; ++mi)
      #pragma unroll
      for (int r = 0; r < 4; ++r) {
        float s = 0.f;
        #pragma unroll
        for (int ni = 0; ni < 4; ++ni) { float v = acc[mi][ni][r]; s += v * v; }
        s += __shfl_xor(s, 1); s += __shfl_xor(s, 2);
        s += __shfl_xor(s, 4); s += __shfl_xor(s, 8);
        if (lm == 0) {
          int row = row0 + wr * 64 + mi * 16 + quad * 4 + r;
          int bb = row >> 11, ll = row & (L_DIM - 1);
          norms[(bb * H_DIM + h) * L_DIM + ll] = s;
        }
      }

    #pragma unroll
    for (int mi = 0; mi < 4; ++mi)
      #pragma unroll
      for (int r = 0; r < 4; ++r) {
        int row = row0 + wr * 64 + mi * 16 + quad * 4 + r;
        #pragma unroll
        for (int ni = 0; ni < 4; ++ni)
          Qhi[(size_t)row * D_DIM + n0 + wc * 64 + ni * 16 + lm] = (bf16_t)acc[mi][ni][r];
      }
  } else {
    const bf16_t* W = (z == 1) ? Wkb : Wvb;
#define STAGE_L(k0, b) do {                                                  \
      STAGE_TILE128(xhi + (size_t)row0 * D_DIM + (k0), sm[b][0]);            \
      STAGE_TILE128(W   + (size_t)n0   * D_DIM + (k0), sm[b][1]);            \
    } while (0)

    STAGE_L(0, 0);
    __syncthreads();
    int cur = 0;
    for (int k0 = 0; k0 < D_DIM; k0 += 32) {
      if (k0 + 32 < D_DIM) STAGE_L(k0 + 32, cur ^ 1);
      bf16x8 af[4], bfr[4];
      #pragma unroll
      for (int mi = 0; mi < 4; ++mi)
        af[mi] = FRAG(sm[cur][0], wr * 64 + mi * 16 + lm);
      #pragma unroll
      for (int ni = 0; ni < 4; ++ni)
        bfr[ni] = FRAG(sm[cur][1], wc * 64 + ni * 16 + lm);
      #pragma unroll
      for (int mi = 0; mi < 4; ++mi)
        #pragma unroll
        for (int ni = 0; ni < 4; ++ni)
          acc[mi][ni] = __builtin_amdgcn_mfma_f32_16x16x32_bf16(af[mi], bfr[ni], acc[mi][ni], 0, 0, 0);
      __syncthreads();
      cur ^= 1;
    }

    const float* bias = (z == 1) ? bk : bv;
    float bvv[4];
    #pragma unroll
    for (int ni = 0; ni < 4; ++ni) bvv[ni] = bias[n0 + wc * 64 + ni * 16 + lm];
    #pragma unroll
    for (int mi = 0; mi < 4; ++mi)
      #pragma unroll
      for (int ni = 0; ni < 4; ++ni)
        #pragma unroll
        for (int r = 0; r < 4; ++r) acc[mi][ni][r] += bvv[ni];

    const int hh = (n0 + wc * 64) >> 6;   // head 0..15
    if (z == 1) {
      // Khead[b][h][l][64]
      #pragma unroll
      for (int mi = 0; mi < 4; ++mi)
        #pragma unroll
        for (int r = 0; r < 4; ++r) {
          int row = row0 + wr * 64 + mi * 16 + quad * 4 + r;
          int bb = row >> 11, ll = row & (L_DIM - 1);
          size_t base = (size_t)(bb * H_DIM + hh) * HSZ + (size_t)ll * 64;
          #pragma unroll
          for (int ni = 0; ni < 4; ++ni)
            Khi[base + ni * 16 + lm] = (bf16_t)acc[mi][ni][r];
        }
    } else {
      // V key-tiled: [(b,h)][kb=l/32][d][32]
      #pragma unroll
      for (int mi = 0; mi < 4; ++mi) {
        int rbase = row0 + wr * 64 + mi * 16 + quad * 4;
        int bb = rbase >> 11, l0 = rbase & (L_DIM - 1);
        int kbv = l0 >> 5, kin = l0 & 31;
        size_t hb = (size_t)(bb * H_DIM + hh) * HSZ;
        #pragma unroll
        for (int ni = 0; ni < 4; ++ni) {
          int d = ni * 16 + lm;
          bf16x4 wv;
          #pragma unroll
          for (int r = 0; r < 4; ++r) wv[r] = (bf16_t)acc[mi][ni][r];
          *reinterpret_cast<bf16x4*>(&VThi[hb + (size_t)(kbv * 64 + d) * 32 + kin]) = wv;
        }
      }
      // Vmean partial: sum this block's 128 rows per (head, dim), f32.
      // Rows covered by this thread: wr*64 + mi*16 + quad*4 + r (16 rows);
      // quad-reduce (shfl 16/32) then one atomic per (wave, ni) lane set.
      const int bb = row0 >> 11;
      float ps[4];
      #pragma unroll
      for (int ni = 0; ni < 4; ++ni) {
        float s = 0.f;
        #pragma unroll
        for (int mi = 0; mi < 4; ++mi)
          #pragma unroll
          for (int r = 0; r < 4; ++r) s += acc[mi][ni][r];
        ps[ni] = s;
      }
      #pragma unroll
      for (int ni = 0; ni < 4; ++ni) {
        ps[ni] += __shfl_xor(ps[ni], 16);
        ps[ni] += __shfl_xor(ps[ni], 32);
      }
      if (quad == 0) {
        #pragma unroll
        for (int ni = 0; ni < 4; ++ni)
          atomicAdd(&Vmeanf[(bb * H_DIM + hh) * 64 + ni * 16 + lm], ps[ni]);
      }
    }
  }
}

// ---------------------------------------------------------------------------
// Output projection: 64x128 tiles, grid (8,64) = 2 blocks/CU, prefetch dbuf.
// ---------------------------------------------------------------------------
__global__ __launch_bounds__(256) void gemm_out(
    const bf16_t* __restrict__ Ahi, const bf16_t* __restrict__ Wob,
    const float* __restrict__ bias, float* __restrict__ C)
{
  const int n0   = blockIdx.x * 128;
  const int row0 = blockIdx.y * 64;

  __shared__ __align__(16) bf16_t sm[2][6144];   // 24 KB: dbuf x (A64 + B128)

  const int tid  = threadIdx.x;
  const int lane = tid & 63;
  const int wave = tid >> 6;
  const int wr = wave >> 1, wc = wave & 1;
  const int lm = lane & 15, quad = lane >> 4;

  const f32x4 vzero = {0.f, 0.f, 0.f, 0.f};
  f32x4 acc[2][4];
  #pragma unroll
  for (int mi = 0; mi < 2; ++mi)
    #pragma unroll
    for (int ni = 0; ni < 4; ++ni) acc[mi][ni] = vzero;

#define STAGE_O(k0, b) do {                                                  \
    STAGE_TILE64(Ahi + (size_t)row0 * D_DIM + (k0), sm[b]);                  \
    STAGE_TILE128(Wob + (size_t)n0 * D_DIM + (k0), sm[b] + 2048);            \
  } while (0)

  STAGE_O(0, 0);
  __syncthreads();
  int cur = 0;
  for (int k0 = 0; k0 < D_DIM; k0 += 32) {
    if (k0 + 32 < D_DIM) STAGE_O(k0 + 32, cur ^ 1);
    bf16x8 af[2], bfr[4];
    #pragma unroll
    for (int mi = 0; mi < 2; ++mi)
      af[mi] = FRAG(sm[cur], wr * 32 + mi * 16 + lm);
    #pragma unroll
    for (int ni = 0; ni < 4; ++ni)
      bfr[ni] = FRAG(sm[cur] + 2048, wc * 64 + ni * 16 + lm);
    #pragma unroll
    for (int mi = 0; mi < 2; ++mi)
      #pragma unroll
      for (int ni = 0; ni < 4; ++ni)
        acc[mi][ni] = __builtin_amdgcn_mfma_f32_16x16x32_bf16(af[mi], bfr[ni], acc[mi][ni], 0, 0, 0);
    __syncthreads();
    cur ^= 1;
  }

  float bvv[4];
  #pragma unroll
  for (int ni = 0; ni < 4; ++ni) bvv[ni] = bias[n0 + wc * 64 + ni * 16 + lm];
  #pragma unroll
  for (int mi = 0; mi < 2; ++mi)
    #pragma unroll
    for (int r = 0; r < 4; ++r) {
      int row = row0 + wr * 32 + mi * 16 + quad * 4 + r;
      #pragma unroll
      for (int ni = 0; ni < 4; ++ni)
        C[(size_t)row * D_DIM + n0 + wc * 64 + ni * 16 + lm] = acc[mi][ni][r] + bvv[ni];
    }
}

// ---------------------------------------------------------------------------
// Exact top-409 per (b,h) via 4-pass 8-bit radix select on f32 bits
// (norms >= 0 so uint ordering == float ordering), then ballot-prefix
// write-out. Set matches lax.top_k exactly.
// ---------------------------------------------------------------------------
__global__ __launch_bounds__(1024) void topk_kernel(
    const float* __restrict__ norms, int* __restrict__ sel)
{
  const int bh = blockIdx.x;
  const int t  = threadIdx.x;
  const int w  = t >> 6;            // wave 0..15
  const int lane = t & 63;

  __shared__ int bins[256];
  __shared__ unsigned int sh_pfx;
  __shared__ int cnt0[16], cnt1[16], ecnt0[16], ecnt1[16];

  const unsigned int k0 = __float_as_uint(norms[bh * L_DIM + t]);
  const unsigned int k1 = __float_as_uint(norms[bh * L_DIM + t + 1024]);

  unsigned int pfx = 0;
  int r = KTOP;
  #pragma unroll
  for (int p = 0; p < 4; ++p) {
    const int sh = 24 - 8 * p;
    if (t < 256) bins[t] = 0;
    __syncthreads();
    const bool q0 = (p == 0) || ((k0 >> (sh + 8)) == pfx);
    const bool q1 = (p == 0) || ((k1 >> (sh + 8)) == pfx);
    if (q0) atomicAdd(&bins[(k0 >> sh) & 255], 1);
    if (q1) atomicAdd(&bins[(k1 >> sh) & 255], 1);
    __syncthreads();
    if (t == 0) {
      int cum = 0, B = 0;
      for (int v = 255; v >= 0; --v) {
        int c = bins[v];
        if (cum + c >= r) { B = v; r -= cum; break; }
        cum += c;
      }
      sh_pfx = (pfx << 8) | (unsigned int)B;
      bins[0] = r;
    }
    __syncthreads();
    pfx = sh_pfx;
    r = bins[0];
    __syncthreads();
  }
  const unsigned int T = pfx;

  const bool gt0 = (k0 > T), gt1 = (k1 > T);
  const bool eq0 = (k0 == T), eq1 = (k1 == T);
  const unsigned long long mlt = (lane == 63) ? 0x7fffffffffffffffull
                                              : ((1ull << lane) - 1ull);
  const unsigned long long bg0 = __ballot(gt0);
  const unsigned long long bg1 = __ballot(gt1);
  const unsigned long long be0 = __ballot(eq0);
  const unsigned long long be1 = __ballot(eq1);
  if (lane == 0) {
    cnt0[w]  = __popcll(bg0);
    cnt1[w]  = __popcll(bg1);
    ecnt0[w] = __popcll(be0);
    ecnt1[w] = __popcll(be1);
  }
  __syncthreads();
  int og0 = 0, og1 = 0, oe0 = 0, oe1 = 0;
  int tg0 = 0, tg1 = 0, te0 = 0;
  #pragma unroll
  for (int i = 0; i < 16; ++i) {
    if (i < w) { og0 += cnt0[i]; og1 += cnt1[i]; oe0 += ecnt0[i]; oe1 += ecnt1[i]; }
    tg0 += cnt0[i]; tg1 += cnt1[i]; te0 += ecnt0[i];
  }
  const int G = tg0 + tg1;
  const int take = KTOP - G;
  const int base = bh * SLOTS;

  if (gt0) sel[base + og0 + __popcll(bg0 & mlt)] = t;
  if (gt1) sel[base + tg0 + og1 + __popcll(bg1 & mlt)] = t + 1024;
  if (eq0) {
    int rk = oe0 + __popcll(be0 & mlt);
    if (rk < take) sel[base + G + rk] = t;
  }
  if (eq1) {
    int rk = te0 + oe1 + __popcll(be1 & mlt);
    if (rk < take) sel[base + G + rk] = t + 1024;
  }
  if (t < SLOTS - KTOP) sel[base + KTOP + t] = -1;
}

// ---------------------------------------------------------------------------
// K-split flash attention — FOUR 16-slot q-tiles per wave (64 slots).
// K/V loads shared across all 4 tiles -> MFMA:load = 32:8; four independent
// per-qt dependency chains give intra-wave ILP (r1 showed chains, not
// occupancy, bind). Grid 512 = 2 blocks/CU x 4 waves = 8 waves/CU.
// K per-head [b][h][L][64]; V key-tiled [(b,h)][kb][d][32]; XCD affinity.
// ---------------------------------------------------------------------------
__global__ __launch_bounds__(256) void attn_kernel(
    const bf16_t* __restrict__ Qhi,
    const bf16_t* __restrict__ Khi,
    const bf16_t* __restrict__ VThi,
    const int* __restrict__ sel,
    float* __restrict__ Ol, bf16_t* __restrict__ Oo)
{
  const int bx = blockIdx.x;
  const int xl = bx & 7;          // XCD id under default round-robin
  const int rest = bx >> 3;       // 0..63
  const int qc = rest & 1;
  const int gh = rest >> 1;       // 0..31
  const int g  = gh * 8 + xl;     // K/V-chunk group 0..255
  const int bh = g & 31;
  const int ks = g >> 5;
  const int b = bh >> 4, h = bh & 15;
  const int wave = threadIdx.x >> 6;
  const int lane = threadIdx.x & 63;
  const int lm = lane & 15, quad = lane >> 4;

  __shared__ __align__(16) bf16_t sPh[2][4][4][16][40];  // [PB][qt][wave][q][key]

  const int qbase = qc * 256 + wave * 64;   // tile qt covers +qt*16
  bf16x8 qa[4][2];
  #pragma unroll
  for (int qt = 0; qt < 4; ++qt) {
    int qi = sel[bh * SLOTS + qbase + qt * 16 + lm];
    size_t qo = ((size_t)(b * L_DIM + (qi >= 0 ? qi : 0))) * D_DIM + h * 64;
    qa[qt][0] = *reinterpret_cast<const bf16x8*>(&Qhi[qo + quad * 8]);
    qa[qt][1] = *reinterpret_cast<const bf16x8*>(&Qhi[qo + 32 + quad * 8]);
  }

  const f32x4 vzero = {0.f, 0.f, 0.f, 0.f};
  float l_l[4][4];
  f32x4 o[4][4];
  #pragma unroll
  for (int qt = 0; qt < 4; ++qt)
    #pragma unroll
    for (int ni = 0; ni < 4; ++ni) { o[qt][ni] = vzero; l_l[qt][ni] = 0.f; }

  const float scale = 0.125f;
  const size_t khead = (size_t)(b * H_DIM + h) * HSZ;
  const int key0 = ks * KCHUNK;

  #pragma unroll 2
  for (int kt = 0; kt < KCHUNK; kt += 32) {
    const int PB = (kt >> 5) & 1;
    size_t kr0 = khead + (size_t)(key0 + kt + lm) * 64;
    size_t kr1 = khead + (size_t)(key0 + kt + 16 + lm) * 64;
    bf16x8 kb0 = *reinterpret_cast<const bf16x8*>(&Khi[kr0 + quad * 8]);
    bf16x8 kb1 = *reinterpret_cast<const bf16x8*>(&Khi[kr0 + 32 + quad * 8]);
    bf16x8 kb2 = *reinterpret_cast<const bf16x8*>(&Khi[kr1 + quad * 8]);
    bf16x8 kb3 = *reinterpret_cast<const bf16x8*>(&Khi[kr1 + 32 + quad * 8]);
    const int kbv = (key0 + kt) >> 5;
    bf16x8 vbh[4];
    #pragma unroll
    for (int ni = 0; ni < 4; ++ni) {
      size_t vo = khead + (size_t)(kbv * 64 + ni * 16 + lm) * 32 + quad * 8;
      vbh[ni] = *reinterpret_cast<const bf16x8*>(&VThi[vo]);
    }
    #pragma unroll
    for (int qt = 0; qt < 4; ++qt) {
      f32x4 s0 = vzero, s1 = vzero;
      s0 = __builtin_amdgcn_mfma_f32_16x16x32_bf16(qa[qt][0], kb0, s0, 0, 0, 0);
      s0 = __builtin_amdgcn_mfma_f32_16x16x32_bf16(qa[qt][1], kb1, s0, 0, 0, 0);
      s1 = __builtin_amdgcn_mfma_f32_16x16x32_bf16(qa[qt][0], kb2, s1, 0, 0, 0);
      s1 = __builtin_amdgcn_mfma_f32_16x16x32_bf16(qa[qt][1], kb3, s1, 0, 0, 0);
      #pragma unroll
      for (int r = 0; r < 4; ++r) {
        float p0 = __expf(s0[r] * scale);
        float p1 = __expf(s1[r] * scale);
        l_l[qt][r] += p0 + p1;
        sPh[PB][qt][wave][quad * 4 + r][lm]      = (bf16_t)p0;
        sPh[PB][qt][wave][quad * 4 + r][16 + lm] = (bf16_t)p1;
      }
      bf16x8 pah = *reinterpret_cast<const bf16x8*>(&sPh[PB][qt][wave][lm][quad * 8]);
      #pragma unroll
      for (int ni = 0; ni < 4; ++ni)
        o[qt][ni] = __builtin_amdgcn_mfma_f32_16x16x32_bf16(pah, vbh[ni], o[qt][ni], 0, 0, 0);
    }
  }

  #pragma unroll
  for (int qt = 0; qt < 4; ++qt)
    #pragma unroll
    for (int r = 0; r < 4; ++r) {
      l_l[qt][r] += __shfl_xor(l_l[qt][r], 1);
      l_l[qt][r] += __shfl_xor(l_l[qt][r], 2);
      l_l[qt][r] += __shfl_xor(l_l[qt][r], 4);
      l_l[qt][r] += __shfl_xor(l_l[qt][r], 8);
    }

  #pragma unroll
  for (int qt = 0; qt < 4; ++qt)
    #pragma unroll
    for (int r = 0; r < 4; ++r) {
      int slot = qbase + qt * 16 + quad * 4 + r;
      int s2 = sel[bh * SLOTS + slot];
      if (s2 >= 0) {
        size_t gs = (size_t)(bh * SLOTS_IO + slot) * KSPLIT + ks;
        if (lm == 0) Ol[gs] = l_l[qt][r];
        #pragma unroll
        for (int ni = 0; ni < 4; ++ni)
          Oo[gs * 64 + ni * 16 + lm] = (bf16_t)o[qt][ni][r];
      }
    }
}

// ---------------------------------------------------------------------------
// Combine ksplit partials -> AO (selected rows; meanfill covered the rest).
// ---------------------------------------------------------------------------
__global__ __launch_bounds__(256) void combine_kernel(
    const float* __restrict__ Ol, const bf16_t* __restrict__ Oo,
    const int* __restrict__ sel, bf16_t* __restrict__ AOhi)
{
  const int bh = blockIdx.x;
  const int b = bh >> 4, h = bh & 15;
  const int chunk = blockIdx.y;
  const int tid = threadIdx.x;
  const int dim = tid & 63;
  const int sl  = tid >> 6;
  #pragma unroll
  for (int p = 0; p < 4; ++p) {
    int slot = chunk * 16 + p * 4 + sl;
    int qi = sel[bh * SLOTS + slot];
    if (qi < 0) continue;
    size_t gs = (size_t)(bh * SLOTS_IO + slot) * KSPLIT;
    float L = 0.f, ov = 0.f;
    #pragma unroll
    for (int s = 0; s < KSPLIT; ++s) {
      L  += Ol[gs + s];
      ov += (float)Oo[(gs + s) * 64 + dim];
    }
    AOhi[((size_t)(b * L_DIM + qi)) * D_DIM + h * 64 + dim] = (bf16_t)(ov / L);
  }
}

// ---------------------------------------------------------------------------
// meanfill: broadcast Vmean (precomputed in qkv z2 via f32 atomics) to EVERY
// AO row; combine overwrites selected rows. Pure write-BW kernel now.
// ---------------------------------------------------------------------------
__global__ __launch_bounds__(256) void meanfill_kernel(
    const float* __restrict__ Vmeanf, bf16_t* __restrict__ AOhi)
{
  const int bh = blockIdx.x;
  const int b = bh >> 4, h = bh & 15;
  const int t = threadIdx.x;
  __shared__ __align__(16) bf16_t smh[64];
  if (t < 64)
    smh[t] = (bf16_t)(Vmeanf[(b * H_DIM + h) * 64 + t] * (1.0f / (float)L_DIM));
  __syncthreads();
  const int lbase = blockIdx.y * 256;
  for (int i = t; i < 256 * 64; i += 256) {
    int l = lbase + (i >> 6), hd = i & 63;
    AOhi[((size_t)(b * L_DIM + l)) * D_DIM + h * 64 + hd] = smh[hd];
  }
}

// ---------------------------------------------------------------------------
extern "C" void kernel_launch(void* const* d_in, const int* in_sizes, int n_in,
                              void* d_out, int out_size, void* d_ws, size_t ws_size,
                              hipStream_t stream) {
  const float* x  = (const float*)d_in[0];
  const float* Wq = (const float*)d_in[1];
  const float* bq = (const float*)d_in[2];
  const float* Wk = (const float*)d_in[3];
  const float* bk = (const float*)d_in[4];
  const float* Wv = (const float*)d_in[5];
  const float* bv = (const float*)d_in[6];
  const float* Wo = (const float*)d_in[7];
  const float* bo = (const float*)d_in[8];
  float* out = (float*)d_out;

  // ws layout (~43 MB):
  //  [0,8)    Qhi  (aliased as AOhi after attn)
  //  [8,16)   VThi (key-tiled per-head layout)
  //  [16,24)  xhi  -+ dead after gemm_qkv; [16,32) reused for Oo (bf16, 14.7MB
  //  [24,32)  xlo  -+  at SLOTS_IO=448 stride)
  //  [32,34)  Wqhi  [34,36) Wqlo  [36,38) Wkb  [38,40) Wvb  [40,42) Wob
  //  [42,..)  norms (256 KB), sel (64 KB), Ol (458 KB), Vmeanf (8 KB @832K)
  // Khi (per-head layout) lives in d_out (8 of 16 MB) — dead until gemm_out.
  const size_t MB = 1u << 20;
  char* ws = (char*)d_ws;
  bf16_t* Qhi  = (bf16_t*)(ws);
  bf16_t* VThi = (bf16_t*)(ws + 8 * MB);
  bf16_t* xhi  = (bf16_t*)(ws + 16 * MB);
  bf16_t* xlo  = (bf16_t*)(ws + 24 * MB);
  bf16_t* Oo   = (bf16_t*)(ws + 16 * MB);         // aliases xhi/xlo
  bf16_t* Wqhi = (bf16_t*)(ws + 32 * MB);
  bf16_t* Wqlo = (bf16_t*)(ws + 34 * MB);
  bf16_t* Wkb  = (bf16_t*)(ws + 36 * MB);
  bf16_t* Wvb  = (bf16_t*)(ws + 38 * MB);
  bf16_t* Wob  = (bf16_t*)(ws + 40 * MB);
  float*  norms = (float*)(ws + 42 * MB);
  int*    sel   = (int*)(ws + 42 * MB + (256u << 10));
  float*  Ol    = (float*)(ws + 42 * MB + (320u << 10));
  float*  Vmeanf = (float*)(ws + 42 * MB + (832u << 10));
  bf16_t* AOhi = Qhi;
  bf16_t* Khi = (bf16_t*)d_out;

  dim3 blk(256);
  prep_kernel<<<dim3(2048), blk, 0, stream>>>(x, Wq, Wk, Wv, Wo,
                                              xhi, xlo, Wqhi, Wqlo, Wkb, Wvb, Wob,
                                              Vmeanf);
  gemm_qkv<<<dim3(768), blk, 0, stream>>>(xhi, xlo, Wqhi, Wqlo, Wkb, Wvb,
                                          bq, bk, bv, Qhi, Khi, VThi, norms, Vmeanf);
  topk_kernel<<<dim3(32), dim3(1024), 0, stream>>>(norms, sel);
  attn_kernel<<<dim3(32 * 2 * KSPLIT), blk, 0, stream>>>(Qhi, Khi, VThi, sel, Ol, Oo);
  meanfill_kernel<<<dim3(32, 8), blk, 0, stream>>>(Vmeanf, AOhi);
  combine_kernel<<<dim3(32, 32), blk, 0, stream>>>(Ol, Oo, sel, AOhi);
  gemm_out<<<dim3(8, 64), blk, 0, stream>>>(AOhi, Wob, bo, out);
}

// Round 10
// 248.192 us; speedup vs baseline: 1.1064x; 1.0303x over previous
//
#include <hip/hip_runtime.h>
#include <hip/hip_bf16.h>
#include <math.h>

typedef __bf16 bf16_t;
typedef __bf16 bf16x8 __attribute__((ext_vector_type(8)));
typedef __bf16 bf16x4 __attribute__((ext_vector_type(4)));
typedef float  f32x4  __attribute__((ext_vector_type(4)));

#define L_DIM 2048
#define D_DIM 1024
#define H_DIM 16
#define M_DIM 4096
#define KTOP 409
#define SLOTS 512      // sel padding (128-slot q-chunks; sel = -1 beyond KTOP)
#define SLOTS_IO 448   // Oo/Ol stride (real slots < 448) — keeps 16MB window
#define KSPLIT 8
#define KCHUNK 256     // L_DIM / KSPLIT
#define HSZ (L_DIM * 64)   // elements per (b,h) head block = 131072

// split f32 into bf16 hi + bf16 lo (a ~= hi + lo)
__device__ __forceinline__ void split2(float a, bf16_t& h, bf16_t& l) {
  h = (bf16_t)a;
  l = (bf16_t)(a - (float)h);
}

// async global -> LDS, 16B per lane; lds ptr must be wave-uniform (m104/m108)
__device__ __forceinline__ void gld16(const bf16_t* g, bf16_t* l) {
  __builtin_amdgcn_global_load_lds(
      (const __attribute__((address_space(1))) void*)g,
      (__attribute__((address_space(3))) void*)l, 16, 0, 0);
}

// LDS source-side XOR swizzle (rule #21; perf-neutral measured, kept)
#define STAGE_TILE128(src, dst)                                               \
  {                                                                           \
    const int seg0 = wave * 2;                                                \
    const int r0 = seg0 * 16 + (lane >> 2);                                   \
    const int c0 = (((lane & 3) ^ ((lane >> 2) & 3))) * 8;                    \
    gld16((src) + (size_t)r0 * D_DIM + c0, (dst) + seg0 * 512);               \
    gld16((src) + (size_t)(r0 + 16) * D_DIM + c0, (dst) + (seg0 + 1) * 512);  \
  }

#define STAGE_TILE64(src, dst)                                                \
  {                                                                           \
    const int r0 = wave * 16 + (lane >> 2);                                   \
    const int c0 = (((lane & 3) ^ ((lane >> 2) & 3))) * 8;                    \
    gld16((src) + (size_t)r0 * D_DIM + c0, (dst) + wave * 512);               \
  }

#define FRAG(buf, ROW) \
  (*reinterpret_cast<const bf16x8*>(&(buf)[(ROW) * 32 + (quad ^ (lm & 3)) * 8]))

// ---------------------------------------------------------------------------
// prep: pre-split x and Wq into bf16 hi/lo; pre-round Wk/Wv/Wo to bf16.
// Also zeroes the Vmean accumulator (2048 f32 = 512 f32x4 items).
// ---------------------------------------------------------------------------
__global__ __launch_bounds__(256) void prep_kernel(
    const float* __restrict__ x,  const float* __restrict__ Wq,
    const float* __restrict__ Wk, const float* __restrict__ Wv,
    const float* __restrict__ Wo,
    bf16_t* __restrict__ xhi, bf16_t* __restrict__ xlo,
    bf16_t* __restrict__ Wqhi, bf16_t* __restrict__ Wqlo,
    bf16_t* __restrict__ Wkb,  bf16_t* __restrict__ Wvb,
    bf16_t* __restrict__ Wob,  float* __restrict__ Vmeanf)
{
  const int XV = (M_DIM * D_DIM) / 4;
  const int WV = (D_DIM * D_DIM) / 4;
  const int TOT = XV + 4 * WV + 512;
  for (int i = blockIdx.x * 256 + threadIdx.x; i < TOT; i += gridDim.x * 256) {
    if (i < XV) {
      f32x4 v = ((const f32x4*)x)[i];
      bf16x4 h, l;
      #pragma unroll
      for (int j = 0; j < 4; ++j) { bf16_t hh, ll; split2(v[j], hh, ll); h[j] = hh; l[j] = ll; }
      ((bf16x4*)xhi)[i] = h;
      ((bf16x4*)xlo)[i] = l;
    } else if (i < XV + WV) {
      int j0 = i - XV;
      f32x4 v = ((const f32x4*)Wq)[j0];
      bf16x4 h, l;
      #pragma unroll
      for (int j = 0; j < 4; ++j) { bf16_t hh, ll; split2(v[j], hh, ll); h[j] = hh; l[j] = ll; }
      ((bf16x4*)Wqhi)[j0] = h;
      ((bf16x4*)Wqlo)[j0] = l;
    } else if (i < XV + 2 * WV) {
      int j0 = i - XV - WV;
      f32x4 v = ((const f32x4*)Wk)[j0];
      bf16x4 h;
      #pragma unroll
      for (int j = 0; j < 4; ++j) h[j] = (bf16_t)v[j];
      ((bf16x4*)Wkb)[j0] = h;
    } else if (i < XV + 3 * WV) {
      int j0 = i - XV - 2 * WV;
      f32x4 v = ((const f32x4*)Wv)[j0];
      bf16x4 h;
      #pragma unroll
      for (int j = 0; j < 4; ++j) h[j] = (bf16_t)v[j];
      ((bf16x4*)Wvb)[j0] = h;
    } else if (i < XV + 4 * WV) {
      int j0 = i - XV - 3 * WV;
      f32x4 v = ((const f32x4*)Wo)[j0];
      bf16x4 h;
      #pragma unroll
      for (int j = 0; j < 4; ++j) h[j] = (bf16_t)v[j];
      ((bf16x4*)Wob)[j0] = h;
    } else {
      int j0 = i - XV - 4 * WV;           // 0..511
      f32x4 zz = {0.f, 0.f, 0.f, 0.f};
      ((f32x4*)Vmeanf)[j0] = zz;
    }
  }
}

// ---------------------------------------------------------------------------
// Fused QKV projections — r5 structure (measured best, 3 blocks/CU).
// z0 split into A/B phases at 48 KB LDS, prefetch dbuf.
// K written per-head [b][h][L][64]; V key-tiled [(b,h)][kb][d][32].
// z2 epilogue accumulates column-sums of V into Vmeanf (f32 atomics).
// ---------------------------------------------------------------------------
__global__ __launch_bounds__(256, 3) void gemm_qkv(
    const bf16_t* __restrict__ xhi, const bf16_t* __restrict__ xlo,
    const bf16_t* __restrict__ Wqhi, const bf16_t* __restrict__ Wqlo,
    const bf16_t* __restrict__ Wkb, const bf16_t* __restrict__ Wvb,
    const float* __restrict__ bq, const float* __restrict__ bk, const float* __restrict__ bv,
    bf16_t* __restrict__ Qhi, bf16_t* __restrict__ Khi, bf16_t* __restrict__ VThi,
    float* __restrict__ norms, float* __restrict__ Vmeanf)
{
  const int bx = blockIdx.x;
  const int z  = bx % 3;          // interleaved so each CU gets a z-mix
  const int id = bx / 3;          // 0..255
  const int n0   = (id & 7) * 128;
  const int row0 = (id >> 3) * 128;

  __shared__ __align__(16) bf16_t sm[2][3][4096];   // 48 KB: dbuf x 3 tiles

  const int tid  = threadIdx.x;
  const int lane = tid & 63;
  const int wave = tid >> 6;
  const int wr = wave >> 1, wc = wave & 1;
  const int lm = lane & 15, quad = lane >> 4;

  const f32x4 vzero = {0.f, 0.f, 0.f, 0.f};
  f32x4 acc[4][4];
  #pragma unroll
  for (int mi = 0; mi < 4; ++mi)
    #pragma unroll
    for (int ni = 0; ni < 4; ++ni) acc[mi][ni] = vzero;

  if (z == 0) {
#define STAGE_A(k0, b) do {                                                  \
      STAGE_TILE128(xhi  + (size_t)row0 * D_DIM + (k0), sm[b][0]);           \
      STAGE_TILE128(Wqhi + (size_t)n0   * D_DIM + (k0), sm[b][1]);           \
      STAGE_TILE128(Wqlo + (size_t)n0   * D_DIM + (k0), sm[b][2]);           \
    } while (0)
#define STAGE_B(k0, b) do {                                                  \
      STAGE_TILE128(xlo  + (size_t)row0 * D_DIM + (k0), sm[b][0]);           \
      STAGE_TILE128(Wqhi + (size_t)n0   * D_DIM + (k0), sm[b][1]);           \
    } while (0)

    STAGE_A(0, 0);
    __syncthreads();
    int cur = 0;
    // phase A: acc += xh*Wqh + xh*Wql
    for (int k0 = 0; k0 < D_DIM; k0 += 32) {
      if (k0 + 32 < D_DIM) STAGE_A(k0 + 32, cur ^ 1);
      else                 STAGE_B(0, cur ^ 1);       // bridge into phase B
      bf16x8 af[4], bh0[4], bl0[4];
      #pragma unroll
      for (int mi = 0; mi < 4; ++mi)
        af[mi] = FRAG(sm[cur][0], wr * 64 + mi * 16 + lm);
      #pragma unroll
      for (int ni = 0; ni < 4; ++ni) {
        bh0[ni] = FRAG(sm[cur][1], wc * 64 + ni * 16 + lm);
        bl0[ni] = FRAG(sm[cur][2], wc * 64 + ni * 16 + lm);
      }
      #pragma unroll
      for (int mi = 0; mi < 4; ++mi)
        #pragma unroll
        for (int ni = 0; ni < 4; ++ni) {
          acc[mi][ni] = __builtin_amdgcn_mfma_f32_16x16x32_bf16(af[mi], bh0[ni], acc[mi][ni], 0, 0, 0);
          acc[mi][ni] = __builtin_amdgcn_mfma_f32_16x16x32_bf16(af[mi], bl0[ni], acc[mi][ni], 0, 0, 0);
        }
      __syncthreads();
      cur ^= 1;
    }
    // phase B: acc += xl*Wqh
    for (int k0 = 0; k0 < D_DIM; k0 += 32) {
      if (k0 + 32 < D_DIM) STAGE_B(k0 + 32, cur ^ 1);
      bf16x8 af[4], bh0[4];
      #pragma unroll
      for (int mi = 0; mi < 4; ++mi)
        af[mi] = FRAG(sm[cur][0], wr * 64 + mi * 16 + lm);
      #pragma unroll
      for (int ni = 0; ni < 4; ++ni)
        bh0[ni] = FRAG(sm[cur][1], wc * 64 + ni * 16 + lm);
      #pragma unroll
      for (int mi = 0; mi < 4; ++mi)
        #pragma unroll
        for (int ni = 0; ni < 4; ++ni)
          acc[mi][ni] = __builtin_amdgcn_mfma_f32_16x16x32_bf16(af[mi], bh0[ni], acc[mi][ni], 0, 0, 0);
      __syncthreads();
      cur ^= 1;
    }

    float bvv[4];
    #pragma unroll
    for (int ni = 0; ni < 4; ++ni) bvv[ni] = bq[n0 + wc * 64 + ni * 16 + lm];
    #pragma unroll
    for (int mi = 0; mi < 4; ++mi)
      #pragma unroll
      for (int ni = 0; ni < 4; ++ni)
        #pragma unroll
        for (int r = 0; r < 4; ++r) acc[mi][ni][r] += bvv[ni];

    const int h = (n0 + wc * 64) >> 6;
    #pragma unroll
    for (int mi = 0; mi < 4; ++mi)
      #pragma unroll
      for (int r = 0; r < 4; ++r) {
        float s = 0.f;
        #pragma unroll
        for (int ni = 0; ni < 4; ++ni) { float v = acc[mi][ni][r]; s += v * v; }
        s += __shfl_xor(s, 1); s += __shfl_xor(s, 2);
        s += __shfl_xor(s, 4); s += __shfl_xor(s, 8);
        if (lm == 0) {
          int row = row0 + wr * 64 + mi * 16 + quad * 4 + r;
          int bb = row >> 11, ll = row & (L_DIM - 1);
          norms[(bb * H_DIM + h) * L_DIM + ll] = s;
        }
      }

    #pragma unroll
    for (int mi = 0; mi < 4; ++mi)
      #pragma unroll
      for (int r = 0; r < 4; ++r) {
        int row = row0 + wr * 64 + mi * 16 + quad * 4 + r;
        #pragma unroll
        for (int ni = 0; ni < 4; ++ni)
          Qhi[(size_t)row * D_DIM + n0 + wc * 64 + ni * 16 + lm] = (bf16_t)acc[mi][ni][r];
      }
  } else {
    const bf16_t* W = (z == 1) ? Wkb : Wvb;
#define STAGE_L(k0, b) do {                                                  \
      STAGE_TILE128(xhi + (size_t)row0 * D_DIM + (k0), sm[b][0]);            \
      STAGE_TILE128(W   + (size_t)n0   * D_DIM + (k0), sm[b][1]);            \
    } while (0)

    STAGE_L(0, 0);
    __syncthreads();
    int cur = 0;
    for (int k0 = 0; k0 < D_DIM; k0 += 32) {
      if (k0 + 32 < D_DIM) STAGE_L(k0 + 32, cur ^ 1);
      bf16x8 af[4], bfr[4];
      #pragma unroll
      for (int mi = 0; mi < 4; ++mi)
        af[mi] = FRAG(sm[cur][0], wr * 64 + mi * 16 + lm);
      #pragma unroll
      for (int ni = 0; ni < 4; ++ni)
        bfr[ni] = FRAG(sm[cur][1], wc * 64 + ni * 16 + lm);
      #pragma unroll
      for (int mi = 0; mi < 4; ++mi)
        #pragma unroll
        for (int ni = 0; ni < 4; ++ni)
          acc[mi][ni] = __builtin_amdgcn_mfma_f32_16x16x32_bf16(af[mi], bfr[ni], acc[mi][ni], 0, 0, 0);
      __syncthreads();
      cur ^= 1;
    }

    const float* bias = (z == 1) ? bk : bv;
    float bvv[4];
    #pragma unroll
    for (int ni = 0; ni < 4; ++ni) bvv[ni] = bias[n0 + wc * 64 + ni * 16 + lm];
    #pragma unroll
    for (int mi = 0; mi < 4; ++mi)
      #pragma unroll
      for (int ni = 0; ni < 4; ++ni)
        #pragma unroll
        for (int r = 0; r < 4; ++r) acc[mi][ni][r] += bvv[ni];

    const int hh = (n0 + wc * 64) >> 6;   // head 0..15
    if (z == 1) {
      // Khead[b][h][l][64]
      #pragma unroll
      for (int mi = 0; mi < 4; ++mi)
        #pragma unroll
        for (int r = 0; r < 4; ++r) {
          int row = row0 + wr * 64 + mi * 16 + quad * 4 + r;
          int bb = row >> 11, ll = row & (L_DIM - 1);
          size_t base = (size_t)(bb * H_DIM + hh) * HSZ + (size_t)ll * 64;
          #pragma unroll
          for (int ni = 0; ni < 4; ++ni)
            Khi[base + ni * 16 + lm] = (bf16_t)acc[mi][ni][r];
        }
    } else {
      // V key-tiled: [(b,h)][kb=l/32][d][32]
      #pragma unroll
      for (int mi = 0; mi < 4; ++mi) {
        int rbase = row0 + wr * 64 + mi * 16 + quad * 4;
        int bb = rbase >> 11, l0 = rbase & (L_DIM - 1);
        int kbv = l0 >> 5, kin = l0 & 31;
        size_t hb = (size_t)(bb * H_DIM + hh) * HSZ;
        #pragma unroll
        for (int ni = 0; ni < 4; ++ni) {
          int d = ni * 16 + lm;
          bf16x4 wv;
          #pragma unroll
          for (int r = 0; r < 4; ++r) wv[r] = (bf16_t)acc[mi][ni][r];
          *reinterpret_cast<bf16x4*>(&VThi[hb + (size_t)(kbv * 64 + d) * 32 + kin]) = wv;
        }
      }
      // Vmean partial: sum this block's 128 rows per (head, dim), f32.
      const int bb = row0 >> 11;
      float ps[4];
      #pragma unroll
      for (int ni = 0; ni < 4; ++ni) {
        float s = 0.f;
        #pragma unroll
        for (int mi = 0; mi < 4; ++mi)
          #pragma unroll
          for (int r = 0; r < 4; ++r) s += acc[mi][ni][r];
        ps[ni] = s;
      }
      #pragma unroll
      for (int ni = 0; ni < 4; ++ni) {
        ps[ni] += __shfl_xor(ps[ni], 16);
        ps[ni] += __shfl_xor(ps[ni], 32);
      }
      if (quad == 0) {
        #pragma unroll
        for (int ni = 0; ni < 4; ++ni)
          atomicAdd(&Vmeanf[(bb * H_DIM + hh) * 64 + ni * 16 + lm], ps[ni]);
      }
    }
  }
}

// ---------------------------------------------------------------------------
// Output projection: 64x128 tiles, grid (8,64) = 2 blocks/CU, prefetch dbuf.
// ---------------------------------------------------------------------------
__global__ __launch_bounds__(256) void gemm_out(
    const bf16_t* __restrict__ Ahi, const bf16_t* __restrict__ Wob,
    const float* __restrict__ bias, float* __restrict__ C)
{
  const int n0   = blockIdx.x * 128;
  const int row0 = blockIdx.y * 64;

  __shared__ __align__(16) bf16_t sm[2][6144];   // 24 KB: dbuf x (A64 + B128)

  const int tid  = threadIdx.x;
  const int lane = tid & 63;
  const int wave = tid >> 6;
  const int wr = wave >> 1, wc = wave & 1;
  const int lm = lane & 15, quad = lane >> 4;

  const f32x4 vzero = {0.f, 0.f, 0.f, 0.f};
  f32x4 acc[2][4];
  #pragma unroll
  for (int mi = 0; mi < 2; ++mi)
    #pragma unroll
    for (int ni = 0; ni < 4; ++ni) acc[mi][ni] = vzero;

#define STAGE_O(k0, b) do {                                                  \
    STAGE_TILE64(Ahi + (size_t)row0 * D_DIM + (k0), sm[b]);                  \
    STAGE_TILE128(Wob + (size_t)n0 * D_DIM + (k0), sm[b] + 2048);            \
  } while (0)

  STAGE_O(0, 0);
  __syncthreads();
  int cur = 0;
  for (int k0 = 0; k0 < D_DIM; k0 += 32) {
    if (k0 + 32 < D_DIM) STAGE_O(k0 + 32, cur ^ 1);
    bf16x8 af[2], bfr[4];
    #pragma unroll
    for (int mi = 0; mi < 2; ++mi)
      af[mi] = FRAG(sm[cur], wr * 32 + mi * 16 + lm);
    #pragma unroll
    for (int ni = 0; ni < 4; ++ni)
      bfr[ni] = FRAG(sm[cur] + 2048, wc * 64 + ni * 16 + lm);
    #pragma unroll
    for (int mi = 0; mi < 2; ++mi)
      #pragma unroll
      for (int ni = 0; ni < 4; ++ni)
        acc[mi][ni] = __builtin_amdgcn_mfma_f32_16x16x32_bf16(af[mi], bfr[ni], acc[mi][ni], 0, 0, 0);
    __syncthreads();
    cur ^= 1;
  }

  float bvv[4];
  #pragma unroll
  for (int ni = 0; ni < 4; ++ni) bvv[ni] = bias[n0 + wc * 64 + ni * 16 + lm];
  #pragma unroll
  for (int mi = 0; mi < 2; ++mi)
    #pragma unroll
    for (int r = 0; r < 4; ++r) {
      int row = row0 + wr * 32 + mi * 16 + quad * 4 + r;
      #pragma unroll
      for (int ni = 0; ni < 4; ++ni)
        C[(size_t)row * D_DIM + n0 + wc * 64 + ni * 16 + lm] = acc[mi][ni][r] + bvv[ni];
    }
}

// ---------------------------------------------------------------------------
// Exact top-409 per (b,h) via 4-pass 8-bit radix select on f32 bits
// (norms >= 0 so uint ordering == float ordering), then ballot-prefix
// write-out. Set matches lax.top_k exactly.
// ---------------------------------------------------------------------------
__global__ __launch_bounds__(1024) void topk_kernel(
    const float* __restrict__ norms, int* __restrict__ sel)
{
  const int bh = blockIdx.x;
  const int t  = threadIdx.x;
  const int w  = t >> 6;            // wave 0..15
  const int lane = t & 63;

  __shared__ int bins[256];
  __shared__ unsigned int sh_pfx;
  __shared__ int cnt0[16], cnt1[16], ecnt0[16], ecnt1[16];

  const unsigned int k0 = __float_as_uint(norms[bh * L_DIM + t]);
  const unsigned int k1 = __float_as_uint(norms[bh * L_DIM + t + 1024]);

  unsigned int pfx = 0;
  int r = KTOP;
  #pragma unroll
  for (int p = 0; p < 4; ++p) {
    const int sh = 24 - 8 * p;
    if (t < 256) bins[t] = 0;
    __syncthreads();
    const bool q0 = (p == 0) || ((k0 >> (sh + 8)) == pfx);
    const bool q1 = (p == 0) || ((k1 >> (sh + 8)) == pfx);
    if (q0) atomicAdd(&bins[(k0 >> sh) & 255], 1);
    if (q1) atomicAdd(&bins[(k1 >> sh) & 255], 1);
    __syncthreads();
    if (t == 0) {
      int cum = 0, B = 0;
      for (int v = 255; v >= 0; --v) {
        int c = bins[v];
        if (cum + c >= r) { B = v; r -= cum; break; }
        cum += c;
      }
      sh_pfx = (pfx << 8) | (unsigned int)B;
      bins[0] = r;
    }
    __syncthreads();
    pfx = sh_pfx;
    r = bins[0];
    __syncthreads();
  }
  const unsigned int T = pfx;

  const bool gt0 = (k0 > T), gt1 = (k1 > T);
  const bool eq0 = (k0 == T), eq1 = (k1 == T);
  const unsigned long long mlt = (lane == 63) ? 0x7fffffffffffffffull
                                              : ((1ull << lane) - 1ull);
  const unsigned long long bg0 = __ballot(gt0);
  const unsigned long long bg1 = __ballot(gt1);
  const unsigned long long be0 = __ballot(eq0);
  const unsigned long long be1 = __ballot(eq1);
  if (lane == 0) {
    cnt0[w]  = __popcll(bg0);
    cnt1[w]  = __popcll(bg1);
    ecnt0[w] = __popcll(be0);
    ecnt1[w] = __popcll(be1);
  }
  __syncthreads();
  int og0 = 0, og1 = 0, oe0 = 0, oe1 = 0;
  int tg0 = 0, tg1 = 0, te0 = 0;
  #pragma unroll
  for (int i = 0; i < 16; ++i) {
    if (i < w) { og0 += cnt0[i]; og1 += cnt1[i]; oe0 += ecnt0[i]; oe1 += ecnt1[i]; }
    tg0 += cnt0[i]; tg1 += cnt1[i]; te0 += ecnt0[i];
  }
  const int G = tg0 + tg1;
  const int take = KTOP - G;
  const int base = bh * SLOTS;

  if (gt0) sel[base + og0 + __popcll(bg0 & mlt)] = t;
  if (gt1) sel[base + tg0 + og1 + __popcll(bg1 & mlt)] = t + 1024;
  if (eq0) {
    int rk = oe0 + __popcll(be0 & mlt);
    if (rk < take) sel[base + G + rk] = t;
  }
  if (eq1) {
    int rk = te0 + oe1 + __popcll(be1 & mlt);
    if (rk < take) sel[base + G + rk] = t + 1024;
  }
  if (t < SLOTS - KTOP) sel[base + KTOP + t] = -1;
}

// ---------------------------------------------------------------------------
// K-split flash attention — r8 measured-best config: TWO 16-slot q-tiles per
// wave (32 slots), MFMA:load = 16:8, grid 1024 = 4 blocks/CU (16 waves/CU).
// K per-head [b][h][L][64]; V key-tiled [(b,h)][kb][d][32]; XCD affinity.
// ---------------------------------------------------------------------------
__global__ __launch_bounds__(256) void attn_kernel(
    const bf16_t* __restrict__ Qhi,
    const bf16_t* __restrict__ Khi,
    const bf16_t* __restrict__ VThi,
    const int* __restrict__ sel,
    float* __restrict__ Ol, bf16_t* __restrict__ Oo)
{
  const int bx = blockIdx.x;
  const int xl = bx & 7;          // XCD id under default round-robin
  const int rest = bx >> 3;       // 0..127
  const int qc = rest & 3;
  const int gh = rest >> 2;       // 0..31
  const int g  = gh * 8 + xl;     // K/V-chunk group 0..255
  const int bh = g & 31;
  const int ks = g >> 5;
  const int b = bh >> 4, h = bh & 15;
  const int wave = threadIdx.x >> 6;
  const int lane = threadIdx.x & 63;
  const int lm = lane & 15, quad = lane >> 4;

  __shared__ __align__(16) bf16_t sPh[2][2][4][16][40];  // [PB][qt][wave][q][key]

  const int qbase = qc * 128 + wave * 32;   // tile qt covers +qt*16
  bf16x8 qa[2][2];
  #pragma unroll
  for (int qt = 0; qt < 2; ++qt) {
    int qi = sel[bh * SLOTS + qbase + qt * 16 + lm];
    size_t qo = ((size_t)(b * L_DIM + (qi >= 0 ? qi : 0))) * D_DIM + h * 64;
    qa[qt][0] = *reinterpret_cast<const bf16x8*>(&Qhi[qo + quad * 8]);
    qa[qt][1] = *reinterpret_cast<const bf16x8*>(&Qhi[qo + 32 + quad * 8]);
  }

  const f32x4 vzero = {0.f, 0.f, 0.f, 0.f};
  float l_l[2][4];
  f32x4 o[2][4];
  #pragma unroll
  for (int qt = 0; qt < 2; ++qt)
    #pragma unroll
    for (int ni = 0; ni < 4; ++ni) { o[qt][ni] = vzero; l_l[qt][ni] = 0.f; }

  const float scale = 0.125f;
  const size_t khead = (size_t)(b * H_DIM + h) * HSZ;
  const int key0 = ks * KCHUNK;

  #pragma unroll 2
  for (int kt = 0; kt < KCHUNK; kt += 32) {
    const int PB = (kt >> 5) & 1;
    size_t kr0 = khead + (size_t)(key0 + kt + lm) * 64;
    size_t kr1 = khead + (size_t)(key0 + kt + 16 + lm) * 64;
    bf16x8 kb0 = *reinterpret_cast<const bf16x8*>(&Khi[kr0 + quad * 8]);
    bf16x8 kb1 = *reinterpret_cast<const bf16x8*>(&Khi[kr0 + 32 + quad * 8]);
    bf16x8 kb2 = *reinterpret_cast<const bf16x8*>(&Khi[kr1 + quad * 8]);
    bf16x8 kb3 = *reinterpret_cast<const bf16x8*>(&Khi[kr1 + 32 + quad * 8]);
    const int kbv = (key0 + kt) >> 5;
    bf16x8 vbh[4];
    #pragma unroll
    for (int ni = 0; ni < 4; ++ni) {
      size_t vo = khead + (size_t)(kbv * 64 + ni * 16 + lm) * 32 + quad * 8;
      vbh[ni] = *reinterpret_cast<const bf16x8*>(&VThi[vo]);
    }
    #pragma unroll
    for (int qt = 0; qt < 2; ++qt) {
      f32x4 s0 = vzero, s1 = vzero;
      s0 = __builtin_amdgcn_mfma_f32_16x16x32_bf16(qa[qt][0], kb0, s0, 0, 0, 0);
      s0 = __builtin_amdgcn_mfma_f32_16x16x32_bf16(qa[qt][1], kb1, s0, 0, 0, 0);
      s1 = __builtin_amdgcn_mfma_f32_16x16x32_bf16(qa[qt][0], kb2, s1, 0, 0, 0);
      s1 = __builtin_amdgcn_mfma_f32_16x16x32_bf16(qa[qt][1], kb3, s1, 0, 0, 0);
      #pragma unroll
      for (int r = 0; r < 4; ++r) {
        float p0 = __expf(s0[r] * scale);
        float p1 = __expf(s1[r] * scale);
        l_l[qt][r] += p0 + p1;
        sPh[PB][qt][wave][quad * 4 + r][lm]      = (bf16_t)p0;
        sPh[PB][qt][wave][quad * 4 + r][16 + lm] = (bf16_t)p1;
      }
      bf16x8 pah = *reinterpret_cast<const bf16x8*>(&sPh[PB][qt][wave][lm][quad * 8]);
      #pragma unroll
      for (int ni = 0; ni < 4; ++ni)
        o[qt][ni] = __builtin_amdgcn_mfma_f32_16x16x32_bf16(pah, vbh[ni], o[qt][ni], 0, 0, 0);
    }
  }

  #pragma unroll
  for (int qt = 0; qt < 2; ++qt)
    #pragma unroll
    for (int r = 0; r < 4; ++r) {
      l_l[qt][r] += __shfl_xor(l_l[qt][r], 1);
      l_l[qt][r] += __shfl_xor(l_l[qt][r], 2);
      l_l[qt][r] += __shfl_xor(l_l[qt][r], 4);
      l_l[qt][r] += __shfl_xor(l_l[qt][r], 8);
    }

  #pragma unroll
  for (int qt = 0; qt < 2; ++qt)
    #pragma unroll
    for (int r = 0; r < 4; ++r) {
      int slot = qbase + qt * 16 + quad * 4 + r;
      int s2 = sel[bh * SLOTS + slot];
      if (s2 >= 0) {
        size_t gs = (size_t)(bh * SLOTS_IO + slot) * KSPLIT + ks;
        if (lm == 0) Ol[gs] = l_l[qt][r];
        #pragma unroll
        for (int ni = 0; ni < 4; ++ni)
          Oo[gs * 64 + ni * 16 + lm] = (bf16_t)o[qt][ni][r];
      }
    }
}

// ---------------------------------------------------------------------------
// Combine ksplit partials -> AO (selected rows; meanfill covered the rest).
// ---------------------------------------------------------------------------
__global__ __launch_bounds__(256) void combine_kernel(
    const float* __restrict__ Ol, const bf16_t* __restrict__ Oo,
    const int* __restrict__ sel, bf16_t* __restrict__ AOhi)
{
  const int bh = blockIdx.x;
  const int b = bh >> 4, h = bh & 15;
  const int chunk = blockIdx.y;
  const int tid = threadIdx.x;
  const int dim = tid & 63;
  const int sl  = tid >> 6;
  #pragma unroll
  for (int p = 0; p < 4; ++p) {
    int slot = chunk * 16 + p * 4 + sl;
    int qi = sel[bh * SLOTS + slot];
    if (qi < 0) continue;
    size_t gs = (size_t)(bh * SLOTS_IO + slot) * KSPLIT;
    float L = 0.f, ov = 0.f;
    #pragma unroll
    for (int s = 0; s < KSPLIT; ++s) {
      L  += Ol[gs + s];
      ov += (float)Oo[(gs + s) * 64 + dim];
    }
    AOhi[((size_t)(b * L_DIM + qi)) * D_DIM + h * 64 + dim] = (bf16_t)(ov / L);
  }
}

// ---------------------------------------------------------------------------
// meanfill: broadcast Vmean (precomputed in qkv z2 via f32 atomics) to EVERY
// AO row; combine overwrites selected rows. Pure write-BW kernel.
// ---------------------------------------------------------------------------
__global__ __launch_bounds__(256) void meanfill_kernel(
    const float* __restrict__ Vmeanf, bf16_t* __restrict__ AOhi)
{
  const int bh = blockIdx.x;
  const int b = bh >> 4, h = bh & 15;
  const int t = threadIdx.x;
  __shared__ __align__(16) bf16_t smh[64];
  if (t < 64)
    smh[t] = (bf16_t)(Vmeanf[(b * H_DIM + h) * 64 + t] * (1.0f / (float)L_DIM));
  __syncthreads();
  const int lbase = blockIdx.y * 256;
  for (int i = t; i < 256 * 64; i += 256) {
    int l = lbase + (i >> 6), hd = i & 63;
    AOhi[((size_t)(b * L_DIM + l)) * D_DIM + h * 64 + hd] = smh[hd];
  }
}

// ---------------------------------------------------------------------------
extern "C" void kernel_launch(void* const* d_in, const int* in_sizes, int n_in,
                              void* d_out, int out_size, void* d_ws, size_t ws_size,
                              hipStream_t stream) {
  const float* x  = (const float*)d_in[0];
  const float* Wq = (const float*)d_in[1];
  const float* bq = (const float*)d_in[2];
  const float* Wk = (const float*)d_in[3];
  const float* bk = (const float*)d_in[4];
  const float* Wv = (const float*)d_in[5];
  const float* bv = (const float*)d_in[6];
  const float* Wo = (const float*)d_in[7];
  const float* bo = (const float*)d_in[8];
  float* out = (float*)d_out;

  // ws layout (~43 MB):
  //  [0,8)    Qhi  (aliased as AOhi after attn)
  //  [8,16)   VThi (key-tiled per-head layout)
  //  [16,24)  xhi  -+ dead after gemm_qkv; [16,32) reused for Oo (bf16, 14.7MB
  //  [24,32)  xlo  -+  at SLOTS_IO=448 stride)
  //  [32,34)  Wqhi  [34,36) Wqlo  [36,38) Wkb  [38,40) Wvb  [40,42) Wob
  //  [42,..)  norms (256 KB), sel (64 KB), Ol (458 KB), Vmeanf (8 KB @832K)
  // Khi (per-head layout) lives in d_out (8 of 16 MB) — dead until gemm_out.
  const size_t MB = 1u << 20;
  char* ws = (char*)d_ws;
  bf16_t* Qhi  = (bf16_t*)(ws);
  bf16_t* VThi = (bf16_t*)(ws + 8 * MB);
  bf16_t* xhi  = (bf16_t*)(ws + 16 * MB);
  bf16_t* xlo  = (bf16_t*)(ws + 24 * MB);
  bf16_t* Oo   = (bf16_t*)(ws + 16 * MB);         // aliases xhi/xlo
  bf16_t* Wqhi = (bf16_t*)(ws + 32 * MB);
  bf16_t* Wqlo = (bf16_t*)(ws + 34 * MB);
  bf16_t* Wkb  = (bf16_t*)(ws + 36 * MB);
  bf16_t* Wvb  = (bf16_t*)(ws + 38 * MB);
  bf16_t* Wob  = (bf16_t*)(ws + 40 * MB);
  float*  norms = (float*)(ws + 42 * MB);
  int*    sel   = (int*)(ws + 42 * MB + (256u << 10));
  float*  Ol    = (float*)(ws + 42 * MB + (320u << 10));
  float*  Vmeanf = (float*)(ws + 42 * MB + (832u << 10));
  bf16_t* AOhi = Qhi;
  bf16_t* Khi = (bf16_t*)d_out;

  dim3 blk(256);
  prep_kernel<<<dim3(2048), blk, 0, stream>>>(x, Wq, Wk, Wv, Wo,
                                              xhi, xlo, Wqhi, Wqlo, Wkb, Wvb, Wob,
                                              Vmeanf);
  gemm_qkv<<<dim3(768), blk, 0, stream>>>(xhi, xlo, Wqhi, Wqlo, Wkb, Wvb,
                                          bq, bk, bv, Qhi, Khi, VThi, norms, Vmeanf);
  topk_kernel<<<dim3(32), dim3(1024), 0, stream>>>(norms, sel);
  attn_kernel<<<dim3(32 * 4 * KSPLIT), blk, 0, stream>>>(Qhi, Khi, VThi, sel, Ol, Oo);
  meanfill_kernel<<<dim3(32, 8), blk, 0, stream>>>(Vmeanf, AOhi);
  combine_kernel<<<dim3(32, 32), blk, 0, stream>>>(Ol, Oo, sel, AOhi);
  gemm_out<<<dim3(8, 64), blk, 0, stream>>>(AOhi, Wob, bo, out);
}

// Round 11
// 214.001 us; speedup vs baseline: 1.2832x; 1.1598x over previous
//
#include <hip/hip_runtime.h>
#include <hip/hip_bf16.h>
#include <math.h>

typedef __bf16 bf16_t;
typedef __bf16 bf16x8 __attribute__((ext_vector_type(8)));
typedef __bf16 bf16x4 __attribute__((ext_vector_type(4)));
typedef float  f32x4  __attribute__((ext_vector_type(4)));

#define L_DIM 2048
#define D_DIM 1024
#define H_DIM 16
#define M_DIM 4096
#define KTOP 409
#define SLOTS 512      // sel padding (128-slot q-chunks; sel = -1 beyond KTOP)
#define SLOTS_IO 448   // Oo/Ol stride (real slots < 448) — keeps 16MB window
#define KSPLIT 8
#define KCHUNK 256     // L_DIM / KSPLIT
#define HSZ (L_DIM * 64)   // elements per (b,h) head block = 131072

// split f32 into bf16 hi + bf16 lo (a ~= hi + lo)
__device__ __forceinline__ void split2(float a, bf16_t& h, bf16_t& l) {
  h = (bf16_t)a;
  l = (bf16_t)(a - (float)h);
}

// async global -> LDS, 16B per lane; lds ptr must be wave-uniform (m104/m108)
__device__ __forceinline__ void gld16(const bf16_t* g, bf16_t* l) {
  __builtin_amdgcn_global_load_lds(
      (const __attribute__((address_space(1))) void*)g,
      (__attribute__((address_space(3))) void*)l, 16, 0, 0);
}

// LDS source-side XOR swizzle (rule #21; perf-neutral measured, kept)
#define STAGE_TILE128(src, dst)                                               \
  {                                                                           \
    const int seg0 = wave * 2;                                                \
    const int r0 = seg0 * 16 + (lane >> 2);                                   \
    const int c0 = (((lane & 3) ^ ((lane >> 2) & 3))) * 8;                    \
    gld16((src) + (size_t)r0 * D_DIM + c0, (dst) + seg0 * 512);               \
    gld16((src) + (size_t)(r0 + 16) * D_DIM + c0, (dst) + (seg0 + 1) * 512);  \
  }

#define STAGE_TILE64(src, dst)                                                \
  {                                                                           \
    const int r0 = wave * 16 + (lane >> 2);                                   \
    const int c0 = (((lane & 3) ^ ((lane >> 2) & 3))) * 8;                    \
    gld16((src) + (size_t)r0 * D_DIM + c0, (dst) + wave * 512);               \
  }

#define FRAG(buf, ROW) \
  (*reinterpret_cast<const bf16x8*>(&(buf)[(ROW) * 32 + (quad ^ (lm & 3)) * 8]))

// ---------------------------------------------------------------------------
// prep: pre-split x and Wq into bf16 hi/lo; pre-round Wk/Wv/Wo to bf16.
// Also zeroes the Vmean accumulator (2048 f32 = 512 f32x4 items).
// ---------------------------------------------------------------------------
__global__ __launch_bounds__(256) void prep_kernel(
    const float* __restrict__ x,  const float* __restrict__ Wq,
    const float* __restrict__ Wk, const float* __restrict__ Wv,
    const float* __restrict__ Wo,
    bf16_t* __restrict__ xhi, bf16_t* __restrict__ xlo,
    bf16_t* __restrict__ Wqhi, bf16_t* __restrict__ Wqlo,
    bf16_t* __restrict__ Wkb,  bf16_t* __restrict__ Wvb,
    bf16_t* __restrict__ Wob,  float* __restrict__ Vmeanf)
{
  const int XV = (M_DIM * D_DIM) / 4;
  const int WV = (D_DIM * D_DIM) / 4;
  const int TOT = XV + 4 * WV + 512;
  for (int i = blockIdx.x * 256 + threadIdx.x; i < TOT; i += gridDim.x * 256) {
    if (i < XV) {
      f32x4 v = ((const f32x4*)x)[i];
      bf16x4 h, l;
      #pragma unroll
      for (int j = 0; j < 4; ++j) { bf16_t hh, ll; split2(v[j], hh, ll); h[j] = hh; l[j] = ll; }
      ((bf16x4*)xhi)[i] = h;
      ((bf16x4*)xlo)[i] = l;
    } else if (i < XV + WV) {
      int j0 = i - XV;
      f32x4 v = ((const f32x4*)Wq)[j0];
      bf16x4 h, l;
      #pragma unroll
      for (int j = 0; j < 4; ++j) { bf16_t hh, ll; split2(v[j], hh, ll); h[j] = hh; l[j] = ll; }
      ((bf16x4*)Wqhi)[j0] = h;
      ((bf16x4*)Wqlo)[j0] = l;
    } else if (i < XV + 2 * WV) {
      int j0 = i - XV - WV;
      f32x4 v = ((const f32x4*)Wk)[j0];
      bf16x4 h;
      #pragma unroll
      for (int j = 0; j < 4; ++j) h[j] = (bf16_t)v[j];
      ((bf16x4*)Wkb)[j0] = h;
    } else if (i < XV + 3 * WV) {
      int j0 = i - XV - 2 * WV;
      f32x4 v = ((const f32x4*)Wv)[j0];
      bf16x4 h;
      #pragma unroll
      for (int j = 0; j < 4; ++j) h[j] = (bf16_t)v[j];
      ((bf16x4*)Wvb)[j0] = h;
    } else if (i < XV + 4 * WV) {
      int j0 = i - XV - 3 * WV;
      f32x4 v = ((const f32x4*)Wo)[j0];
      bf16x4 h;
      #pragma unroll
      for (int j = 0; j < 4; ++j) h[j] = (bf16_t)v[j];
      ((bf16x4*)Wob)[j0] = h;
    } else {
      int j0 = i - XV - 4 * WV;           // 0..511
      f32x4 zz = {0.f, 0.f, 0.f, 0.f};
      ((f32x4*)Vmeanf)[j0] = zz;
    }
  }
}

// ---------------------------------------------------------------------------
// Fused QKV projections — r5 structure (measured best, 3 blocks/CU).
// z0 split into A/B phases at 48 KB LDS, prefetch dbuf.
// K written per-head [b][h][L][64]; V key-tiled [(b,h)][kb][d][32].
// z2 epilogue accumulates column-sums of V into Vmeanf (f32 atomics).
// ---------------------------------------------------------------------------
__global__ __launch_bounds__(256, 3) void gemm_qkv(
    const bf16_t* __restrict__ xhi, const bf16_t* __restrict__ xlo,
    const bf16_t* __restrict__ Wqhi, const bf16_t* __restrict__ Wqlo,
    const bf16_t* __restrict__ Wkb, const bf16_t* __restrict__ Wvb,
    const float* __restrict__ bq, const float* __restrict__ bk, const float* __restrict__ bv,
    bf16_t* __restrict__ Qhi, bf16_t* __restrict__ Khi, bf16_t* __restrict__ VThi,
    float* __restrict__ norms, float* __restrict__ Vmeanf)
{
  const int bx = blockIdx.x;
  const int z  = bx % 3;          // interleaved so each CU gets a z-mix
  const int id = bx / 3;          // 0..255
  const int n0   = (id & 7) * 128;
  const int row0 = (id >> 3) * 128;

  __shared__ __align__(16) bf16_t sm[2][3][4096];   // 48 KB: dbuf x 3 tiles

  const int tid  = threadIdx.x;
  const int lane = tid & 63;
  const int wave = tid >> 6;
  const int wr = wave >> 1, wc = wave & 1;
  const int lm = lane & 15, quad = lane >> 4;

  const f32x4 vzero = {0.f, 0.f, 0.f, 0.f};
  f32x4 acc[4][4];
  #pragma unroll
  for (int mi = 0; mi < 4; ++mi)
    #pragma unroll
    for (int ni = 0; ni < 4; ++ni) acc[mi][ni] = vzero;

  if (z == 0) {
#define STAGE_A(k0, b) do {                                                  \
      STAGE_TILE128(xhi  + (size_t)row0 * D_DIM + (k0), sm[b][0]);           \
      STAGE_TILE128(Wqhi + (size_t)n0   * D_DIM + (k0), sm[b][1]);           \
      STAGE_TILE128(Wqlo + (size_t)n0   * D_DIM + (k0), sm[b][2]);           \
    } while (0)
#define STAGE_B(k0, b) do {                                                  \
      STAGE_TILE128(xlo  + (size_t)row0 * D_DIM + (k0), sm[b][0]);           \
      STAGE_TILE128(Wqhi + (size_t)n0   * D_DIM + (k0), sm[b][1]);           \
    } while (0)

    STAGE_A(0, 0);
    __syncthreads();
    int cur = 0;
    // phase A: acc += xh*Wqh + xh*Wql
    for (int k0 = 0; k0 < D_DIM; k0 += 32) {
      if (k0 + 32 < D_DIM) STAGE_A(k0 + 32, cur ^ 1);
      else                 STAGE_B(0, cur ^ 1);       // bridge into phase B
      bf16x8 af[4], bh0[4], bl0[4];
      #pragma unroll
      for (int mi = 0; mi < 4; ++mi)
        af[mi] = FRAG(sm[cur][0], wr * 64 + mi * 16 + lm);
      #pragma unroll
      for (int ni = 0; ni < 4; ++ni) {
        bh0[ni] = FRAG(sm[cur][1], wc * 64 + ni * 16 + lm);
        bl0[ni] = FRAG(sm[cur][2], wc * 64 + ni * 16 + lm);
      }
      #pragma unroll
      for (int mi = 0; mi < 4; ++mi)
        #pragma unroll
        for (int ni = 0; ni < 4; ++ni) {
          acc[mi][ni] = __builtin_amdgcn_mfma_f32_16x16x32_bf16(af[mi], bh0[ni], acc[mi][ni], 0, 0, 0);
          acc[mi][ni] = __builtin_amdgcn_mfma_f32_16x16x32_bf16(af[mi], bl0[ni], acc[mi][ni], 0, 0, 0);
        }
      __syncthreads();
      cur ^= 1;
    }
    // phase B: acc += xl*Wqh
    for (int k0 = 0; k0 < D_DIM; k0 += 32) {
      if (k0 + 32 < D_DIM) STAGE_B(k0 + 32, cur ^ 1);
      bf16x8 af[4], bh0[4];
      #pragma unroll
      for (int mi = 0; mi < 4; ++mi)
        af[mi] = FRAG(sm[cur][0], wr * 64 + mi * 16 + lm);
      #pragma unroll
      for (int ni = 0; ni < 4; ++ni)
        bh0[ni] = FRAG(sm[cur][1], wc * 64 + ni * 16 + lm);
      #pragma unroll
      for (int mi = 0; mi < 4; ++mi)
        #pragma unroll
        for (int ni = 0; ni < 4; ++ni)
          acc[mi][ni] = __builtin_amdgcn_mfma_f32_16x16x32_bf16(af[mi], bh0[ni], acc[mi][ni], 0, 0, 0);
      __syncthreads();
      cur ^= 1;
    }

    float bvv[4];
    #pragma unroll
    for (int ni = 0; ni < 4; ++ni) bvv[ni] = bq[n0 + wc * 64 + ni * 16 + lm];
    #pragma unroll
    for (int mi = 0; mi < 4; ++mi)
      #pragma unroll
      for (int ni = 0; ni < 4; ++ni)
        #pragma unroll
        for (int r = 0; r < 4; ++r) acc[mi][ni][r] += bvv[ni];

    const int h = (n0 + wc * 64) >> 6;
    #pragma unroll
    for (int mi = 0; mi < 4; ++mi)
      #pragma unroll
      for (int r = 0; r < 4; ++r) {
        float s = 0.f;
        #pragma unroll
        for (int ni = 0; ni < 4; ++ni) { float v = acc[mi][ni][r]; s += v * v; }
        s += __shfl_xor(s, 1); s += __shfl_xor(s, 2);
        s += __shfl_xor(s, 4); s += __shfl_xor(s, 8);
        if (lm == 0) {
          int row = row0 + wr * 64 + mi * 16 + quad * 4 + r;
          int bb = row >> 11, ll = row & (L_DIM - 1);
          norms[(bb * H_DIM + h) * L_DIM + ll] = s;
        }
      }

    #pragma unroll
    for (int mi = 0; mi < 4; ++mi)
      #pragma unroll
      for (int r = 0; r < 4; ++r) {
        int row = row0 + wr * 64 + mi * 16 + quad * 4 + r;
        #pragma unroll
        for (int ni = 0; ni < 4; ++ni)
          Qhi[(size_t)row * D_DIM + n0 + wc * 64 + ni * 16 + lm] = (bf16_t)acc[mi][ni][r];
      }
  } else {
    const bf16_t* W = (z == 1) ? Wkb : Wvb;
#define STAGE_L(k0, b) do {                                                  \
      STAGE_TILE128(xhi + (size_t)row0 * D_DIM + (k0), sm[b][0]);            \
      STAGE_TILE128(W   + (size_t)n0   * D_DIM + (k0), sm[b][1]);            \
    } while (0)

    STAGE_L(0, 0);
    __syncthreads();
    int cur = 0;
    for (int k0 = 0; k0 < D_DIM; k0 += 32) {
      if (k0 + 32 < D_DIM) STAGE_L(k0 + 32, cur ^ 1);
      bf16x8 af[4], bfr[4];
      #pragma unroll
      for (int mi = 0; mi < 4; ++mi)
        af[mi] = FRAG(sm[cur][0], wr * 64 + mi * 16 + lm);
      #pragma unroll
      for (int ni = 0; ni < 4; ++ni)
        bfr[ni] = FRAG(sm[cur][1], wc * 64 + ni * 16 + lm);
      #pragma unroll
      for (int mi = 0; mi < 4; ++mi)
        #pragma unroll
        for (int ni = 0; ni < 4; ++ni)
          acc[mi][ni] = __builtin_amdgcn_mfma_f32_16x16x32_bf16(af[mi], bfr[ni], acc[mi][ni], 0, 0, 0);
      __syncthreads();
      cur ^= 1;
    }

    const float* bias = (z == 1) ? bk : bv;
    float bvv[4];
    #pragma unroll
    for (int ni = 0; ni < 4; ++ni) bvv[ni] = bias[n0 + wc * 64 + ni * 16 + lm];
    #pragma unroll
    for (int mi = 0; mi < 4; ++mi)
      #pragma unroll
      for (int ni = 0; ni < 4; ++ni)
        #pragma unroll
        for (int r = 0; r < 4; ++r) acc[mi][ni][r] += bvv[ni];

    const int hh = (n0 + wc * 64) >> 6;   // head 0..15
    if (z == 1) {
      // Khead[b][h][l][64]
      #pragma unroll
      for (int mi = 0; mi < 4; ++mi)
        #pragma unroll
        for (int r = 0; r < 4; ++r) {
          int row = row0 + wr * 64 + mi * 16 + quad * 4 + r;
          int bb = row >> 11, ll = row & (L_DIM - 1);
          size_t base = (size_t)(bb * H_DIM + hh) * HSZ + (size_t)ll * 64;
          #pragma unroll
          for (int ni = 0; ni < 4; ++ni)
            Khi[base + ni * 16 + lm] = (bf16_t)acc[mi][ni][r];
        }
    } else {
      // V key-tiled: [(b,h)][kb=l/32][d][32]
      #pragma unroll
      for (int mi = 0; mi < 4; ++mi) {
        int rbase = row0 + wr * 64 + mi * 16 + quad * 4;
        int bb = rbase >> 11, l0 = rbase & (L_DIM - 1);
        int kbv = l0 >> 5, kin = l0 & 31;
        size_t hb = (size_t)(bb * H_DIM + hh) * HSZ;
        #pragma unroll
        for (int ni = 0; ni < 4; ++ni) {
          int d = ni * 16 + lm;
          bf16x4 wv;
          #pragma unroll
          for (int r = 0; r < 4; ++r) wv[r] = (bf16_t)acc[mi][ni][r];
          *reinterpret_cast<bf16x4*>(&VThi[hb + (size_t)(kbv * 64 + d) * 32 + kin]) = wv;
        }
      }
      // Vmean partial: sum this block's 128 rows per (head, dim), f32.
      const int bb = row0 >> 11;
      float ps[4];
      #pragma unroll
      for (int ni = 0; ni < 4; ++ni) {
        float s = 0.f;
        #pragma unroll
        for (int mi = 0; mi < 4; ++mi)
          #pragma unroll
          for (int r = 0; r < 4; ++r) s += acc[mi][ni][r];
        ps[ni] = s;
      }
      #pragma unroll
      for (int ni = 0; ni < 4; ++ni) {
        ps[ni] += __shfl_xor(ps[ni], 16);
        ps[ni] += __shfl_xor(ps[ni], 32);
      }
      if (quad == 0) {
        #pragma unroll
        for (int ni = 0; ni < 4; ++ni)
          atomicAdd(&Vmeanf[(bb * H_DIM + hh) * 64 + ni * 16 + lm], ps[ni]);
      }
    }
  }
}

// ---------------------------------------------------------------------------
// Output projection: 64x128 tiles, grid (8,64) = 2 blocks/CU, prefetch dbuf.
// ---------------------------------------------------------------------------
__global__ __launch_bounds__(256) void gemm_out(
    const bf16_t* __restrict__ Ahi, const bf16_t* __restrict__ Wob,
    const float* __restrict__ bias, float* __restrict__ C)
{
  const int n0   = blockIdx.x * 128;
  const int row0 = blockIdx.y * 64;

  __shared__ __align__(16) bf16_t sm[2][6144];   // 24 KB: dbuf x (A64 + B128)

  const int tid  = threadIdx.x;
  const int lane = tid & 63;
  const int wave = tid >> 6;
  const int wr = wave >> 1, wc = wave & 1;
  const int lm = lane & 15, quad = lane >> 4;

  const f32x4 vzero = {0.f, 0.f, 0.f, 0.f};
  f32x4 acc[2][4];
  #pragma unroll
  for (int mi = 0; mi < 2; ++mi)
    #pragma unroll
    for (int ni = 0; ni < 4; ++ni) acc[mi][ni] = vzero;

#define STAGE_O(k0, b) do {                                                  \
    STAGE_TILE64(Ahi + (size_t)row0 * D_DIM + (k0), sm[b]);                  \
    STAGE_TILE128(Wob + (size_t)n0 * D_DIM + (k0), sm[b] + 2048);            \
  } while (0)

  STAGE_O(0, 0);
  __syncthreads();
  int cur = 0;
  for (int k0 = 0; k0 < D_DIM; k0 += 32) {
    if (k0 + 32 < D_DIM) STAGE_O(k0 + 32, cur ^ 1);
    bf16x8 af[2], bfr[4];
    #pragma unroll
    for (int mi = 0; mi < 2; ++mi)
      af[mi] = FRAG(sm[cur], wr * 32 + mi * 16 + lm);
    #pragma unroll
    for (int ni = 0; ni < 4; ++ni)
      bfr[ni] = FRAG(sm[cur] + 2048, wc * 64 + ni * 16 + lm);
    #pragma unroll
    for (int mi = 0; mi < 2; ++mi)
      #pragma unroll
      for (int ni = 0; ni < 4; ++ni)
        acc[mi][ni] = __builtin_amdgcn_mfma_f32_16x16x32_bf16(af[mi], bfr[ni], acc[mi][ni], 0, 0, 0);
    __syncthreads();
    cur ^= 1;
  }

  float bvv[4];
  #pragma unroll
  for (int ni = 0; ni < 4; ++ni) bvv[ni] = bias[n0 + wc * 64 + ni * 16 + lm];
  #pragma unroll
  for (int mi = 0; mi < 2; ++mi)
    #pragma unroll
    for (int r = 0; r < 4; ++r) {
      int row = row0 + wr * 32 + mi * 16 + quad * 4 + r;
      #pragma unroll
      for (int ni = 0; ni < 4; ++ni)
        C[(size_t)row * D_DIM + n0 + wc * 64 + ni * 16 + lm] = acc[mi][ni][r] + bvv[ni];
    }
}

// ---------------------------------------------------------------------------
// Exact top-409 per (b,h) via 4-pass 8-bit radix select on f32 bits.
// Round-11: the per-pass bin selection is now a WAVE-PARALLEL suffix scan
// (wave 0: 4 bins/lane, 6-step shfl_down doubling, in-register 4-bin walk)
// replacing the t==0 serial 256-LDS-read loop (~120cy each, latency-bound).
// Also writes rowmap[bh][l] = slot (or -1) for the fused fill kernel.
// ---------------------------------------------------------------------------
__global__ __launch_bounds__(1024) void topk_kernel(
    const float* __restrict__ norms, int* __restrict__ sel,
    int* __restrict__ rowmap)
{
  const int bh = blockIdx.x;
  const int t  = threadIdx.x;
  const int w  = t >> 6;            // wave 0..15
  const int lane = t & 63;

  __shared__ int bins[256];
  __shared__ unsigned int sh_pfx;
  __shared__ int sh_r;
  __shared__ int cnt0[16], cnt1[16], ecnt0[16], ecnt1[16];

  const unsigned int k0 = __float_as_uint(norms[bh * L_DIM + t]);
  const unsigned int k1 = __float_as_uint(norms[bh * L_DIM + t + 1024]);

  // init rowmap (selected rows overwritten at the end)
  rowmap[bh * L_DIM + t] = -1;
  rowmap[bh * L_DIM + t + 1024] = -1;

  unsigned int pfx = 0;
  int r = KTOP;
  #pragma unroll
  for (int p = 0; p < 4; ++p) {
    const int sh = 24 - 8 * p;
    if (t < 256) bins[t] = 0;
    __syncthreads();
    const bool q0 = (p == 0) || ((k0 >> (sh + 8)) == pfx);
    const bool q1 = (p == 0) || ((k1 >> (sh + 8)) == pfx);
    if (q0) atomicAdd(&bins[(k0 >> sh) & 255], 1);
    if (q1) atomicAdd(&bins[(k1 >> sh) & 255], 1);
    __syncthreads();
    if (w == 0) {
      // lane owns bins[4*lane .. 4*lane+3]
      const int b0 = bins[lane * 4 + 0];
      const int b1 = bins[lane * 4 + 1];
      const int b2 = bins[lane * 4 + 2];
      const int b3 = bins[lane * 4 + 3];
      int sfx = b0 + b1 + b2 + b3;
      // inclusive suffix-sum across lanes (sfx[l] = sum over lanes >= l)
      #pragma unroll
      for (int off = 1; off < 64; off <<= 1) {
        int other = __shfl_down(sfx, off);
        if (lane + off < 64) sfx += other;
      }
      int nsfx = __shfl_down(sfx, 1);
      if (lane == 63) nsfx = 0;
      if (sfx >= r && nsfx < r) {      // unique winner lane
        int cum = nsfx, B, rn;
        if (cum + b3 >= r)      { B = lane * 4 + 3; rn = r - cum; }
        else { cum += b3;
          if (cum + b2 >= r)    { B = lane * 4 + 2; rn = r - cum; }
          else { cum += b2;
            if (cum + b1 >= r)  { B = lane * 4 + 1; rn = r - cum; }
            else { cum += b1;     B = lane * 4 + 0; rn = r - cum; }
          }
        }
        sh_pfx = (pfx << 8) | (unsigned int)B;
        sh_r = rn;
      }
    }
    __syncthreads();
    pfx = sh_pfx;
    r = sh_r;
    __syncthreads();
  }
  const unsigned int T = pfx;

  const bool gt0 = (k0 > T), gt1 = (k1 > T);
  const bool eq0 = (k0 == T), eq1 = (k1 == T);
  const unsigned long long mlt = (lane == 63) ? 0x7fffffffffffffffull
                                              : ((1ull << lane) - 1ull);
  const unsigned long long bg0 = __ballot(gt0);
  const unsigned long long bg1 = __ballot(gt1);
  const unsigned long long be0 = __ballot(eq0);
  const unsigned long long be1 = __ballot(eq1);
  if (lane == 0) {
    cnt0[w]  = __popcll(bg0);
    cnt1[w]  = __popcll(bg1);
    ecnt0[w] = __popcll(be0);
    ecnt1[w] = __popcll(be1);
  }
  __syncthreads();
  int og0 = 0, og1 = 0, oe0 = 0, oe1 = 0;
  int tg0 = 0, tg1 = 0, te0 = 0;
  #pragma unroll
  for (int i = 0; i < 16; ++i) {
    if (i < w) { og0 += cnt0[i]; og1 += cnt1[i]; oe0 += ecnt0[i]; oe1 += ecnt1[i]; }
    tg0 += cnt0[i]; tg1 += cnt1[i]; te0 += ecnt0[i];
  }
  const int G = tg0 + tg1;          // total keys > T (G < KTOP)
  const int take = KTOP - G;        // ties to take, earliest index first
  const int base = bh * SLOTS;

  if (gt0) {
    int slot = og0 + __popcll(bg0 & mlt);
    sel[base + slot] = t;
    rowmap[bh * L_DIM + t] = slot;
  }
  if (gt1) {
    int slot = tg0 + og1 + __popcll(bg1 & mlt);
    sel[base + slot] = t + 1024;
    rowmap[bh * L_DIM + t + 1024] = slot;
  }
  if (eq0) {
    int rk = oe0 + __popcll(be0 & mlt);
    if (rk < take) {
      sel[base + G + rk] = t;
      rowmap[bh * L_DIM + t] = G + rk;
    }
  }
  if (eq1) {
    int rk = te0 + oe1 + __popcll(be1 & mlt);
    if (rk < take) {
      sel[base + G + rk] = t + 1024;
      rowmap[bh * L_DIM + t + 1024] = G + rk;
    }
  }
  if (t < SLOTS - KTOP) sel[base + KTOP + t] = -1;
}

// ---------------------------------------------------------------------------
// K-split flash attention — r8 measured-best config: TWO 16-slot q-tiles per
// wave (32 slots), MFMA:load = 16:8, grid 1024 = 4 blocks/CU (16 waves/CU).
// K per-head [b][h][L][64]; V key-tiled [(b,h)][kb][d][32]; XCD affinity.
// ---------------------------------------------------------------------------
__global__ __launch_bounds__(256) void attn_kernel(
    const bf16_t* __restrict__ Qhi,
    const bf16_t* __restrict__ Khi,
    const bf16_t* __restrict__ VThi,
    const int* __restrict__ sel,
    float* __restrict__ Ol, bf16_t* __restrict__ Oo)
{
  const int bx = blockIdx.x;
  const int xl = bx & 7;          // XCD id under default round-robin
  const int rest = bx >> 3;       // 0..127
  const int qc = rest & 3;
  const int gh = rest >> 2;       // 0..31
  const int g  = gh * 8 + xl;     // K/V-chunk group 0..255
  const int bh = g & 31;
  const int ks = g >> 5;
  const int b = bh >> 4, h = bh & 15;
  const int wave = threadIdx.x >> 6;
  const int lane = threadIdx.x & 63;
  const int lm = lane & 15, quad = lane >> 4;

  __shared__ __align__(16) bf16_t sPh[2][2][4][16][40];  // [PB][qt][wave][q][key]

  const int qbase = qc * 128 + wave * 32;   // tile qt covers +qt*16
  bf16x8 qa[2][2];
  #pragma unroll
  for (int qt = 0; qt < 2; ++qt) {
    int qi = sel[bh * SLOTS + qbase + qt * 16 + lm];
    size_t qo = ((size_t)(b * L_DIM + (qi >= 0 ? qi : 0))) * D_DIM + h * 64;
    qa[qt][0] = *reinterpret_cast<const bf16x8*>(&Qhi[qo + quad * 8]);
    qa[qt][1] = *reinterpret_cast<const bf16x8*>(&Qhi[qo + 32 + quad * 8]);
  }

  const f32x4 vzero = {0.f, 0.f, 0.f, 0.f};
  float l_l[2][4];
  f32x4 o[2][4];
  #pragma unroll
  for (int qt = 0; qt < 2; ++qt)
    #pragma unroll
    for (int ni = 0; ni < 4; ++ni) { o[qt][ni] = vzero; l_l[qt][ni] = 0.f; }

  const float scale = 0.125f;
  const size_t khead = (size_t)(b * H_DIM + h) * HSZ;
  const int key0 = ks * KCHUNK;

  #pragma unroll 2
  for (int kt = 0; kt < KCHUNK; kt += 32) {
    const int PB = (kt >> 5) & 1;
    size_t kr0 = khead + (size_t)(key0 + kt + lm) * 64;
    size_t kr1 = khead + (size_t)(key0 + kt + 16 + lm) * 64;
    bf16x8 kb0 = *reinterpret_cast<const bf16x8*>(&Khi[kr0 + quad * 8]);
    bf16x8 kb1 = *reinterpret_cast<const bf16x8*>(&Khi[kr0 + 32 + quad * 8]);
    bf16x8 kb2 = *reinterpret_cast<const bf16x8*>(&Khi[kr1 + quad * 8]);
    bf16x8 kb3 = *reinterpret_cast<const bf16x8*>(&Khi[kr1 + 32 + quad * 8]);
    const int kbv = (key0 + kt) >> 5;
    bf16x8 vbh[4];
    #pragma unroll
    for (int ni = 0; ni < 4; ++ni) {
      size_t vo = khead + (size_t)(kbv * 64 + ni * 16 + lm) * 32 + quad * 8;
      vbh[ni] = *reinterpret_cast<const bf16x8*>(&VThi[vo]);
    }
    #pragma unroll
    for (int qt = 0; qt < 2; ++qt) {
      f32x4 s0 = vzero, s1 = vzero;
      s0 = __builtin_amdgcn_mfma_f32_16x16x32_bf16(qa[qt][0], kb0, s0, 0, 0, 0);
      s0 = __builtin_amdgcn_mfma_f32_16x16x32_bf16(qa[qt][1], kb1, s0, 0, 0, 0);
      s1 = __builtin_amdgcn_mfma_f32_16x16x32_bf16(qa[qt][0], kb2, s1, 0, 0, 0);
      s1 = __builtin_amdgcn_mfma_f32_16x16x32_bf16(qa[qt][1], kb3, s1, 0, 0, 0);
      #pragma unroll
      for (int r = 0; r < 4; ++r) {
        float p0 = __expf(s0[r] * scale);
        float p1 = __expf(s1[r] * scale);
        l_l[qt][r] += p0 + p1;
        sPh[PB][qt][wave][quad * 4 + r][lm]      = (bf16_t)p0;
        sPh[PB][qt][wave][quad * 4 + r][16 + lm] = (bf16_t)p1;
      }
      bf16x8 pah = *reinterpret_cast<const bf16x8*>(&sPh[PB][qt][wave][lm][quad * 8]);
      #pragma unroll
      for (int ni = 0; ni < 4; ++ni)
        o[qt][ni] = __builtin_amdgcn_mfma_f32_16x16x32_bf16(pah, vbh[ni], o[qt][ni], 0, 0, 0);
    }
  }

  #pragma unroll
  for (int qt = 0; qt < 2; ++qt)
    #pragma unroll
    for (int r = 0; r < 4; ++r) {
      l_l[qt][r] += __shfl_xor(l_l[qt][r], 1);
      l_l[qt][r] += __shfl_xor(l_l[qt][r], 2);
      l_l[qt][r] += __shfl_xor(l_l[qt][r], 4);
      l_l[qt][r] += __shfl_xor(l_l[qt][r], 8);
    }

  #pragma unroll
  for (int qt = 0; qt < 2; ++qt)
    #pragma unroll
    for (int r = 0; r < 4; ++r) {
      int slot = qbase + qt * 16 + quad * 4 + r;
      int s2 = sel[bh * SLOTS + slot];
      if (s2 >= 0) {
        size_t gs = (size_t)(bh * SLOTS_IO + slot) * KSPLIT + ks;
        if (lm == 0) Ol[gs] = l_l[qt][r];
        #pragma unroll
        for (int ni = 0; ni < 4; ++ni)
          Oo[gs * 64 + ni * 16 + lm] = (bf16_t)o[qt][ni][r];
      }
    }
}

// ---------------------------------------------------------------------------
// Fused fill: every AO row written exactly once — mean(V) for non-selected,
// ksplit-combine for selected. Grid (32,32) = 4 blocks/CU; per-wave rowmap
// prefetch (16 parallel loads) + shfl broadcast avoids serial scalar stalls
// (the r4 fill mistake: 1 block/CU + dependent per-row loads).
// ---------------------------------------------------------------------------
__global__ __launch_bounds__(256) void fill_kernel(
    const float* __restrict__ Ol, const bf16_t* __restrict__ Oo,
    const int* __restrict__ rowmap, const float* __restrict__ Vmeanf,
    bf16_t* __restrict__ AOhi)
{
  const int bh = blockIdx.x;
  const int b = bh >> 4, h = bh & 15;
  const int t = threadIdx.x;
  const int lane = t & 63;
  const int w = t >> 6;

  __shared__ __align__(16) bf16_t smh[64];
  if (t < 64)
    smh[t] = (bf16_t)(Vmeanf[(b * H_DIM + h) * 64 + t] * (1.0f / (float)L_DIM));
  __syncthreads();

  const int rbase = blockIdx.y * 64 + w * 16;   // 16 rows per wave
  int flag = -1;
  if (lane < 16) flag = rowmap[bh * L_DIM + rbase + lane];

  for (int j = 0; j < 16; ++j) {
    const int s = __shfl(flag, j);              // wave-uniform slot or -1
    const int row = rbase + j;
    bf16_t outv;
    if (s < 0) {
      outv = smh[lane];
    } else {
      size_t gs = (size_t)(bh * SLOTS_IO + s) * KSPLIT;
      float L = 0.f, ov = 0.f;
      #pragma unroll
      for (int sp = 0; sp < KSPLIT; ++sp) {
        L  += Ol[gs + sp];
        ov += (float)Oo[(gs + sp) * 64 + lane];
      }
      outv = (bf16_t)(ov / L);
    }
    AOhi[((size_t)(b * L_DIM + row)) * D_DIM + h * 64 + lane] = outv;
  }
}

// ---------------------------------------------------------------------------
extern "C" void kernel_launch(void* const* d_in, const int* in_sizes, int n_in,
                              void* d_out, int out_size, void* d_ws, size_t ws_size,
                              hipStream_t stream) {
  const float* x  = (const float*)d_in[0];
  const float* Wq = (const float*)d_in[1];
  const float* bq = (const float*)d_in[2];
  const float* Wk = (const float*)d_in[3];
  const float* bk = (const float*)d_in[4];
  const float* Wv = (const float*)d_in[5];
  const float* bv = (const float*)d_in[6];
  const float* Wo = (const float*)d_in[7];
  const float* bo = (const float*)d_in[8];
  float* out = (float*)d_out;

  // ws layout (~43 MB):
  //  [0,8)    Qhi  (aliased as AOhi after attn)
  //  [8,16)   VThi (key-tiled per-head layout)
  //  [16,24)  xhi  -+ dead after gemm_qkv; [16,~30.7) reused for Oo (bf16,
  //  [24,32)  xlo  -+  SLOTS_IO=448 stride); [31,32) rowmap (topk, xlo dead)
  //  [32,34)  Wqhi  [34,36) Wqlo  [36,38) Wkb  [38,40) Wvb  [40,42) Wob
  //  [42,..)  norms (256 KB), sel (64 KB), Ol (458 KB), Vmeanf (8 KB @832K)
  // Khi (per-head layout) lives in d_out (8 of 16 MB) — dead until gemm_out.
  const size_t MB = 1u << 20;
  char* ws = (char*)d_ws;
  bf16_t* Qhi  = (bf16_t*)(ws);
  bf16_t* VThi = (bf16_t*)(ws + 8 * MB);
  bf16_t* xhi  = (bf16_t*)(ws + 16 * MB);
  bf16_t* xlo  = (bf16_t*)(ws + 24 * MB);
  bf16_t* Oo   = (bf16_t*)(ws + 16 * MB);         // aliases xhi/xlo
  int*    rowmap = (int*)(ws + 31 * MB);          // 256 KB, past Oo's tail
  bf16_t* Wqhi = (bf16_t*)(ws + 32 * MB);
  bf16_t* Wqlo = (bf16_t*)(ws + 34 * MB);
  bf16_t* Wkb  = (bf16_t*)(ws + 36 * MB);
  bf16_t* Wvb  = (bf16_t*)(ws + 38 * MB);
  bf16_t* Wob  = (bf16_t*)(ws + 40 * MB);
  float*  norms = (float*)(ws + 42 * MB);
  int*    sel   = (int*)(ws + 42 * MB + (256u << 10));
  float*  Ol    = (float*)(ws + 42 * MB + (320u << 10));
  float*  Vmeanf = (float*)(ws + 42 * MB + (832u << 10));
  bf16_t* AOhi = Qhi;
  bf16_t* Khi = (bf16_t*)d_out;

  dim3 blk(256);
  prep_kernel<<<dim3(2048), blk, 0, stream>>>(x, Wq, Wk, Wv, Wo,
                                              xhi, xlo, Wqhi, Wqlo, Wkb, Wvb, Wob,
                                              Vmeanf);
  gemm_qkv<<<dim3(768), blk, 0, stream>>>(xhi, xlo, Wqhi, Wqlo, Wkb, Wvb,
                                          bq, bk, bv, Qhi, Khi, VThi, norms, Vmeanf);
  topk_kernel<<<dim3(32), dim3(1024), 0, stream>>>(norms, sel, rowmap);
  attn_kernel<<<dim3(32 * 4 * KSPLIT), blk, 0, stream>>>(Qhi, Khi, VThi, sel, Ol, Oo);
  fill_kernel<<<dim3(32, 32), blk, 0, stream>>>(Ol, Oo, rowmap, Vmeanf, AOhi);
  gemm_out<<<dim3(8, 64), blk, 0, stream>>>(AOhi, Wob, bo, out);
}

// Round 12
// 198.804 us; speedup vs baseline: 1.3813x; 1.0764x over previous
//
#include <hip/hip_runtime.h>
#include <hip/hip_bf16.h>
#include <math.h>

typedef __bf16 bf16_t;
typedef __bf16 bf16x8 __attribute__((ext_vector_type(8)));
typedef __bf16 bf16x4 __attribute__((ext_vector_type(4)));
typedef float  f32x4  __attribute__((ext_vector_type(4)));

#define L_DIM 2048
#define D_DIM 1024
#define H_DIM 16
#define M_DIM 4096
#define KTOP 409
#define SLOTS 512      // sel padding (128-slot q-chunks; sel = -1 beyond KTOP)
#define SLOTS_IO 448   // Oo/Ol stride (real slots < 448) — keeps 16MB window
#define KSPLIT 8
#define KCHUNK 256     // L_DIM / KSPLIT
#define HSZ (L_DIM * 64)   // elements per (b,h) head block = 131072

// split f32 into bf16 hi + bf16 lo (a ~= hi + lo)
__device__ __forceinline__ void split2(float a, bf16_t& h, bf16_t& l) {
  h = (bf16_t)a;
  l = (bf16_t)(a - (float)h);
}

// async global -> LDS, 16B per lane; lds ptr must be wave-uniform (m104/m108)
__device__ __forceinline__ void gld16(const bf16_t* g, bf16_t* l) {
  __builtin_amdgcn_global_load_lds(
      (const __attribute__((address_space(1))) void*)g,
      (__attribute__((address_space(3))) void*)l, 16, 0, 0);
}

// LDS source-side XOR swizzle (rule #21; perf-neutral measured, kept)
#define STAGE_TILE128(src, dst)                                               \
  {                                                                           \
    const int seg0 = wave * 2;                                                \
    const int r0 = seg0 * 16 + (lane >> 2);                                   \
    const int c0 = (((lane & 3) ^ ((lane >> 2) & 3))) * 8;                    \
    gld16((src) + (size_t)r0 * D_DIM + c0, (dst) + seg0 * 512);               \
    gld16((src) + (size_t)(r0 + 16) * D_DIM + c0, (dst) + (seg0 + 1) * 512);  \
  }

#define STAGE_TILE64(src, dst)                                                \
  {                                                                           \
    const int r0 = wave * 16 + (lane >> 2);                                   \
    const int c0 = (((lane & 3) ^ ((lane >> 2) & 3))) * 8;                    \
    gld16((src) + (size_t)r0 * D_DIM + c0, (dst) + wave * 512);               \
  }

#define FRAG(buf, ROW) \
  (*reinterpret_cast<const bf16x8*>(&(buf)[(ROW) * 32 + (quad ^ (lm & 3)) * 8]))

// ---------------------------------------------------------------------------
// prep: pre-split x and Wq into bf16 hi/lo; pre-round Wk/Wv/Wo to bf16.
// Also zeroes the Vmean accumulator (2048 f32 = 512 f32x4 items).
// ---------------------------------------------------------------------------
__global__ __launch_bounds__(256) void prep_kernel(
    const float* __restrict__ x,  const float* __restrict__ Wq,
    const float* __restrict__ Wk, const float* __restrict__ Wv,
    const float* __restrict__ Wo,
    bf16_t* __restrict__ xhi, bf16_t* __restrict__ xlo,
    bf16_t* __restrict__ Wqhi, bf16_t* __restrict__ Wqlo,
    bf16_t* __restrict__ Wkb,  bf16_t* __restrict__ Wvb,
    bf16_t* __restrict__ Wob,  float* __restrict__ Vmeanf)
{
  const int XV = (M_DIM * D_DIM) / 4;
  const int WV = (D_DIM * D_DIM) / 4;
  const int TOT = XV + 4 * WV + 512;
  for (int i = blockIdx.x * 256 + threadIdx.x; i < TOT; i += gridDim.x * 256) {
    if (i < XV) {
      f32x4 v = ((const f32x4*)x)[i];
      bf16x4 h, l;
      #pragma unroll
      for (int j = 0; j < 4; ++j) { bf16_t hh, ll; split2(v[j], hh, ll); h[j] = hh; l[j] = ll; }
      ((bf16x4*)xhi)[i] = h;
      ((bf16x4*)xlo)[i] = l;
    } else if (i < XV + WV) {
      int j0 = i - XV;
      f32x4 v = ((const f32x4*)Wq)[j0];
      bf16x4 h, l;
      #pragma unroll
      for (int j = 0; j < 4; ++j) { bf16_t hh, ll; split2(v[j], hh, ll); h[j] = hh; l[j] = ll; }
      ((bf16x4*)Wqhi)[j0] = h;
      ((bf16x4*)Wqlo)[j0] = l;
    } else if (i < XV + 2 * WV) {
      int j0 = i - XV - WV;
      f32x4 v = ((const f32x4*)Wk)[j0];
      bf16x4 h;
      #pragma unroll
      for (int j = 0; j < 4; ++j) h[j] = (bf16_t)v[j];
      ((bf16x4*)Wkb)[j0] = h;
    } else if (i < XV + 3 * WV) {
      int j0 = i - XV - 2 * WV;
      f32x4 v = ((const f32x4*)Wv)[j0];
      bf16x4 h;
      #pragma unroll
      for (int j = 0; j < 4; ++j) h[j] = (bf16_t)v[j];
      ((bf16x4*)Wvb)[j0] = h;
    } else if (i < XV + 4 * WV) {
      int j0 = i - XV - 3 * WV;
      f32x4 v = ((const f32x4*)Wo)[j0];
      bf16x4 h;
      #pragma unroll
      for (int j = 0; j < 4; ++j) h[j] = (bf16_t)v[j];
      ((bf16x4*)Wob)[j0] = h;
    } else {
      int j0 = i - XV - 4 * WV;           // 0..511
      f32x4 zz = {0.f, 0.f, 0.f, 0.f};
      ((f32x4*)Vmeanf)[j0] = zz;
    }
  }
}

// ---------------------------------------------------------------------------
// Fused QKV projections — r5 structure (measured best, 3 blocks/CU).
// z0 split into A/B phases at 48 KB LDS, prefetch dbuf.
// K written per-head [b][h][L][64]; V key-tiled [(b,h)][kb][d][32].
// z2 epilogue accumulates column-sums of V into Vmeanf (f32 atomics).
// ---------------------------------------------------------------------------
__global__ __launch_bounds__(256, 3) void gemm_qkv(
    const bf16_t* __restrict__ xhi, const bf16_t* __restrict__ xlo,
    const bf16_t* __restrict__ Wqhi, const bf16_t* __restrict__ Wqlo,
    const bf16_t* __restrict__ Wkb, const bf16_t* __restrict__ Wvb,
    const float* __restrict__ bq, const float* __restrict__ bk, const float* __restrict__ bv,
    bf16_t* __restrict__ Qhi, bf16_t* __restrict__ Khi, bf16_t* __restrict__ VThi,
    float* __restrict__ norms, float* __restrict__ Vmeanf)
{
  const int bx = blockIdx.x;
  const int z  = bx % 3;          // interleaved so each CU gets a z-mix
  const int id = bx / 3;          // 0..255
  const int n0   = (id & 7) * 128;
  const int row0 = (id >> 3) * 128;

  __shared__ __align__(16) bf16_t sm[2][3][4096];   // 48 KB: dbuf x 3 tiles

  const int tid  = threadIdx.x;
  const int lane = tid & 63;
  const int wave = tid >> 6;
  const int wr = wave >> 1, wc = wave & 1;
  const int lm = lane & 15, quad = lane >> 4;

  const f32x4 vzero = {0.f, 0.f, 0.f, 0.f};
  f32x4 acc[4][4];
  #pragma unroll
  for (int mi = 0; mi < 4; ++mi)
    #pragma unroll
    for (int ni = 0; ni < 4; ++ni) acc[mi][ni] = vzero;

  if (z == 0) {
#define STAGE_A(k0, b) do {                                                  \
      STAGE_TILE128(xhi  + (size_t)row0 * D_DIM + (k0), sm[b][0]);           \
      STAGE_TILE128(Wqhi + (size_t)n0   * D_DIM + (k0), sm[b][1]);           \
      STAGE_TILE128(Wqlo + (size_t)n0   * D_DIM + (k0), sm[b][2]);           \
    } while (0)
#define STAGE_B(k0, b) do {                                                  \
      STAGE_TILE128(xlo  + (size_t)row0 * D_DIM + (k0), sm[b][0]);           \
      STAGE_TILE128(Wqhi + (size_t)n0   * D_DIM + (k0), sm[b][1]);           \
    } while (0)

    STAGE_A(0, 0);
    __syncthreads();
    int cur = 0;
    // phase A: acc += xh*Wqh + xh*Wql
    for (int k0 = 0; k0 < D_DIM; k0 += 32) {
      if (k0 + 32 < D_DIM) STAGE_A(k0 + 32, cur ^ 1);
      else                 STAGE_B(0, cur ^ 1);       // bridge into phase B
      bf16x8 af[4], bh0[4], bl0[4];
      #pragma unroll
      for (int mi = 0; mi < 4; ++mi)
        af[mi] = FRAG(sm[cur][0], wr * 64 + mi * 16 + lm);
      #pragma unroll
      for (int ni = 0; ni < 4; ++ni) {
        bh0[ni] = FRAG(sm[cur][1], wc * 64 + ni * 16 + lm);
        bl0[ni] = FRAG(sm[cur][2], wc * 64 + ni * 16 + lm);
      }
      #pragma unroll
      for (int mi = 0; mi < 4; ++mi)
        #pragma unroll
        for (int ni = 0; ni < 4; ++ni) {
          acc[mi][ni] = __builtin_amdgcn_mfma_f32_16x16x32_bf16(af[mi], bh0[ni], acc[mi][ni], 0, 0, 0);
          acc[mi][ni] = __builtin_amdgcn_mfma_f32_16x16x32_bf16(af[mi], bl0[ni], acc[mi][ni], 0, 0, 0);
        }
      __syncthreads();
      cur ^= 1;
    }
    // phase B: acc += xl*Wqh
    for (int k0 = 0; k0 < D_DIM; k0 += 32) {
      if (k0 + 32 < D_DIM) STAGE_B(k0 + 32, cur ^ 1);
      bf16x8 af[4], bh0[4];
      #pragma unroll
      for (int mi = 0; mi < 4; ++mi)
        af[mi] = FRAG(sm[cur][0], wr * 64 + mi * 16 + lm);
      #pragma unroll
      for (int ni = 0; ni < 4; ++ni)
        bh0[ni] = FRAG(sm[cur][1], wc * 64 + ni * 16 + lm);
      #pragma unroll
      for (int mi = 0; mi < 4; ++mi)
        #pragma unroll
        for (int ni = 0; ni < 4; ++ni)
          acc[mi][ni] = __builtin_amdgcn_mfma_f32_16x16x32_bf16(af[mi], bh0[ni], acc[mi][ni], 0, 0, 0);
      __syncthreads();
      cur ^= 1;
    }

    float bvv[4];
    #pragma unroll
    for (int ni = 0; ni < 4; ++ni) bvv[ni] = bq[n0 + wc * 64 + ni * 16 + lm];
    #pragma unroll
    for (int mi = 0; mi < 4; ++mi)
      #pragma unroll
      for (int ni = 0; ni < 4; ++ni)
        #pragma unroll
        for (int r = 0; r < 4; ++r) acc[mi][ni][r] += bvv[ni];

    const int h = (n0 + wc * 64) >> 6;
    #pragma unroll
    for (int mi = 0; mi < 4; ++mi)
      #pragma unroll
      for (int r = 0; r < 4; ++r) {
        float s = 0.f;
        #pragma unroll
        for (int ni = 0; ni < 4; ++ni) { float v = acc[mi][ni][r]; s += v * v; }
        s += __shfl_xor(s, 1); s += __shfl_xor(s, 2);
        s += __shfl_xor(s, 4); s += __shfl_xor(s, 8);
        if (lm == 0) {
          int row = row0 + wr * 64 + mi * 16 + quad * 4 + r;
          int bb = row >> 11, ll = row & (L_DIM - 1);
          norms[(bb * H_DIM + h) * L_DIM + ll] = s;
        }
      }

    #pragma unroll
    for (int mi = 0; mi < 4; ++mi)
      #pragma unroll
      for (int r = 0; r < 4; ++r) {
        int row = row0 + wr * 64 + mi * 16 + quad * 4 + r;
        #pragma unroll
        for (int ni = 0; ni < 4; ++ni)
          Qhi[(size_t)row * D_DIM + n0 + wc * 64 + ni * 16 + lm] = (bf16_t)acc[mi][ni][r];
      }
  } else {
    const bf16_t* W = (z == 1) ? Wkb : Wvb;
#define STAGE_L(k0, b) do {                                                  \
      STAGE_TILE128(xhi + (size_t)row0 * D_DIM + (k0), sm[b][0]);            \
      STAGE_TILE128(W   + (size_t)n0   * D_DIM + (k0), sm[b][1]);            \
    } while (0)

    STAGE_L(0, 0);
    __syncthreads();
    int cur = 0;
    for (int k0 = 0; k0 < D_DIM; k0 += 32) {
      if (k0 + 32 < D_DIM) STAGE_L(k0 + 32, cur ^ 1);
      bf16x8 af[4], bfr[4];
      #pragma unroll
      for (int mi = 0; mi < 4; ++mi)
        af[mi] = FRAG(sm[cur][0], wr * 64 + mi * 16 + lm);
      #pragma unroll
      for (int ni = 0; ni < 4; ++ni)
        bfr[ni] = FRAG(sm[cur][1], wc * 64 + ni * 16 + lm);
      #pragma unroll
      for (int mi = 0; mi < 4; ++mi)
        #pragma unroll
        for (int ni = 0; ni < 4; ++ni)
          acc[mi][ni] = __builtin_amdgcn_mfma_f32_16x16x32_bf16(af[mi], bfr[ni], acc[mi][ni], 0, 0, 0);
      __syncthreads();
      cur ^= 1;
    }

    const float* bias = (z == 1) ? bk : bv;
    float bvv[4];
    #pragma unroll
    for (int ni = 0; ni < 4; ++ni) bvv[ni] = bias[n0 + wc * 64 + ni * 16 + lm];
    #pragma unroll
    for (int mi = 0; mi < 4; ++mi)
      #pragma unroll
      for (int ni = 0; ni < 4; ++ni)
        #pragma unroll
        for (int r = 0; r < 4; ++r) acc[mi][ni][r] += bvv[ni];

    const int hh = (n0 + wc * 64) >> 6;   // head 0..15
    if (z == 1) {
      // Khead[b][h][l][64]
      #pragma unroll
      for (int mi = 0; mi < 4; ++mi)
        #pragma unroll
        for (int r = 0; r < 4; ++r) {
          int row = row0 + wr * 64 + mi * 16 + quad * 4 + r;
          int bb = row >> 11, ll = row & (L_DIM - 1);
          size_t base = (size_t)(bb * H_DIM + hh) * HSZ + (size_t)ll * 64;
          #pragma unroll
          for (int ni = 0; ni < 4; ++ni)
            Khi[base + ni * 16 + lm] = (bf16_t)acc[mi][ni][r];
        }
    } else {
      // V key-tiled: [(b,h)][kb=l/32][d][32]
      #pragma unroll
      for (int mi = 0; mi < 4; ++mi) {
        int rbase = row0 + wr * 64 + mi * 16 + quad * 4;
        int bb = rbase >> 11, l0 = rbase & (L_DIM - 1);
        int kbv = l0 >> 5, kin = l0 & 31;
        size_t hb = (size_t)(bb * H_DIM + hh) * HSZ;
        #pragma unroll
        for (int ni = 0; ni < 4; ++ni) {
          int d = ni * 16 + lm;
          bf16x4 wv;
          #pragma unroll
          for (int r = 0; r < 4; ++r) wv[r] = (bf16_t)acc[mi][ni][r];
          *reinterpret_cast<bf16x4*>(&VThi[hb + (size_t)(kbv * 64 + d) * 32 + kin]) = wv;
        }
      }
      // Vmean partial: sum this block's 128 rows per (head, dim), f32.
      const int bb = row0 >> 11;
      float ps[4];
      #pragma unroll
      for (int ni = 0; ni < 4; ++ni) {
        float s = 0.f;
        #pragma unroll
        for (int mi = 0; mi < 4; ++mi)
          #pragma unroll
          for (int r = 0; r < 4; ++r) s += acc[mi][ni][r];
        ps[ni] = s;
      }
      #pragma unroll
      for (int ni = 0; ni < 4; ++ni) {
        ps[ni] += __shfl_xor(ps[ni], 16);
        ps[ni] += __shfl_xor(ps[ni], 32);
      }
      if (quad == 0) {
        #pragma unroll
        for (int ni = 0; ni < 4; ++ni)
          atomicAdd(&Vmeanf[(bb * H_DIM + hh) * 64 + ni * 16 + lm], ps[ni]);
      }
    }
  }
}

// ---------------------------------------------------------------------------
// Output projection: 64x128 tiles, grid (8,64) = 2 blocks/CU, prefetch dbuf.
// ---------------------------------------------------------------------------
__global__ __launch_bounds__(256) void gemm_out(
    const bf16_t* __restrict__ Ahi, const bf16_t* __restrict__ Wob,
    const float* __restrict__ bias, float* __restrict__ C)
{
  const int n0   = blockIdx.x * 128;
  const int row0 = blockIdx.y * 64;

  __shared__ __align__(16) bf16_t sm[2][6144];   // 24 KB: dbuf x (A64 + B128)

  const int tid  = threadIdx.x;
  const int lane = tid & 63;
  const int wave = tid >> 6;
  const int wr = wave >> 1, wc = wave & 1;
  const int lm = lane & 15, quad = lane >> 4;

  const f32x4 vzero = {0.f, 0.f, 0.f, 0.f};
  f32x4 acc[2][4];
  #pragma unroll
  for (int mi = 0; mi < 2; ++mi)
    #pragma unroll
    for (int ni = 0; ni < 4; ++ni) acc[mi][ni] = vzero;

#define STAGE_O(k0, b) do {                                                  \
    STAGE_TILE64(Ahi + (size_t)row0 * D_DIM + (k0), sm[b]);                  \
    STAGE_TILE128(Wob + (size_t)n0 * D_DIM + (k0), sm[b] + 2048);            \
  } while (0)

  STAGE_O(0, 0);
  __syncthreads();
  int cur = 0;
  for (int k0 = 0; k0 < D_DIM; k0 += 32) {
    if (k0 + 32 < D_DIM) STAGE_O(k0 + 32, cur ^ 1);
    bf16x8 af[2], bfr[4];
    #pragma unroll
    for (int mi = 0; mi < 2; ++mi)
      af[mi] = FRAG(sm[cur], wr * 32 + mi * 16 + lm);
    #pragma unroll
    for (int ni = 0; ni < 4; ++ni)
      bfr[ni] = FRAG(sm[cur] + 2048, wc * 64 + ni * 16 + lm);
    #pragma unroll
    for (int mi = 0; mi < 2; ++mi)
      #pragma unroll
      for (int ni = 0; ni < 4; ++ni)
        acc[mi][ni] = __builtin_amdgcn_mfma_f32_16x16x32_bf16(af[mi], bfr[ni], acc[mi][ni], 0, 0, 0);
    __syncthreads();
    cur ^= 1;
  }

  float bvv[4];
  #pragma unroll
  for (int ni = 0; ni < 4; ++ni) bvv[ni] = bias[n0 + wc * 64 + ni * 16 + lm];
  #pragma unroll
  for (int mi = 0; mi < 2; ++mi)
    #pragma unroll
    for (int r = 0; r < 4; ++r) {
      int row = row0 + wr * 32 + mi * 16 + quad * 4 + r;
      #pragma unroll
      for (int ni = 0; ni < 4; ++ni)
        C[(size_t)row * D_DIM + n0 + wc * 64 + ni * 16 + lm] = acc[mi][ni][r] + bvv[ni];
    }
}

// ---------------------------------------------------------------------------
// Exact top-409 per (b,h) via 4-pass 8-bit radix select on f32 bits.
// Wave-parallel suffix scan for bin selection (r11). Writes rowmap for fill.
// ---------------------------------------------------------------------------
__global__ __launch_bounds__(1024) void topk_kernel(
    const float* __restrict__ norms, int* __restrict__ sel,
    int* __restrict__ rowmap)
{
  const int bh = blockIdx.x;
  const int t  = threadIdx.x;
  const int w  = t >> 6;            // wave 0..15
  const int lane = t & 63;

  __shared__ int bins[256];
  __shared__ unsigned int sh_pfx;
  __shared__ int sh_r;
  __shared__ int cnt0[16], cnt1[16], ecnt0[16], ecnt1[16];

  const unsigned int k0 = __float_as_uint(norms[bh * L_DIM + t]);
  const unsigned int k1 = __float_as_uint(norms[bh * L_DIM + t + 1024]);

  // init rowmap (selected rows overwritten at the end)
  rowmap[bh * L_DIM + t] = -1;
  rowmap[bh * L_DIM + t + 1024] = -1;

  unsigned int pfx = 0;
  int r = KTOP;
  #pragma unroll
  for (int p = 0; p < 4; ++p) {
    const int sh = 24 - 8 * p;
    if (t < 256) bins[t] = 0;
    __syncthreads();
    const bool q0 = (p == 0) || ((k0 >> (sh + 8)) == pfx);
    const bool q1 = (p == 0) || ((k1 >> (sh + 8)) == pfx);
    if (q0) atomicAdd(&bins[(k0 >> sh) & 255], 1);
    if (q1) atomicAdd(&bins[(k1 >> sh) & 255], 1);
    __syncthreads();
    if (w == 0) {
      const int b0 = bins[lane * 4 + 0];
      const int b1 = bins[lane * 4 + 1];
      const int b2 = bins[lane * 4 + 2];
      const int b3 = bins[lane * 4 + 3];
      int sfx = b0 + b1 + b2 + b3;
      #pragma unroll
      for (int off = 1; off < 64; off <<= 1) {
        int other = __shfl_down(sfx, off);
        if (lane + off < 64) sfx += other;
      }
      int nsfx = __shfl_down(sfx, 1);
      if (lane == 63) nsfx = 0;
      if (sfx >= r && nsfx < r) {      // unique winner lane
        int cum = nsfx, B, rn;
        if (cum + b3 >= r)      { B = lane * 4 + 3; rn = r - cum; }
        else { cum += b3;
          if (cum + b2 >= r)    { B = lane * 4 + 2; rn = r - cum; }
          else { cum += b2;
            if (cum + b1 >= r)  { B = lane * 4 + 1; rn = r - cum; }
            else { cum += b1;     B = lane * 4 + 0; rn = r - cum; }
          }
        }
        sh_pfx = (pfx << 8) | (unsigned int)B;
        sh_r = rn;
      }
    }
    __syncthreads();
    pfx = sh_pfx;
    r = sh_r;
    __syncthreads();
  }
  const unsigned int T = pfx;

  const bool gt0 = (k0 > T), gt1 = (k1 > T);
  const bool eq0 = (k0 == T), eq1 = (k1 == T);
  const unsigned long long mlt = (lane == 63) ? 0x7fffffffffffffffull
                                              : ((1ull << lane) - 1ull);
  const unsigned long long bg0 = __ballot(gt0);
  const unsigned long long bg1 = __ballot(gt1);
  const unsigned long long be0 = __ballot(eq0);
  const unsigned long long be1 = __ballot(eq1);
  if (lane == 0) {
    cnt0[w]  = __popcll(bg0);
    cnt1[w]  = __popcll(bg1);
    ecnt0[w] = __popcll(be0);
    ecnt1[w] = __popcll(be1);
  }
  __syncthreads();
  int og0 = 0, og1 = 0, oe0 = 0, oe1 = 0;
  int tg0 = 0, tg1 = 0, te0 = 0;
  #pragma unroll
  for (int i = 0; i < 16; ++i) {
    if (i < w) { og0 += cnt0[i]; og1 += cnt1[i]; oe0 += ecnt0[i]; oe1 += ecnt1[i]; }
    tg0 += cnt0[i]; tg1 += cnt1[i]; te0 += ecnt0[i];
  }
  const int G = tg0 + tg1;          // total keys > T (G < KTOP)
  const int take = KTOP - G;        // ties to take, earliest index first
  const int base = bh * SLOTS;

  if (gt0) {
    int slot = og0 + __popcll(bg0 & mlt);
    sel[base + slot] = t;
    rowmap[bh * L_DIM + t] = slot;
  }
  if (gt1) {
    int slot = tg0 + og1 + __popcll(bg1 & mlt);
    sel[base + slot] = t + 1024;
    rowmap[bh * L_DIM + t + 1024] = slot;
  }
  if (eq0) {
    int rk = oe0 + __popcll(be0 & mlt);
    if (rk < take) {
      sel[base + G + rk] = t;
      rowmap[bh * L_DIM + t] = G + rk;
    }
  }
  if (eq1) {
    int rk = te0 + oe1 + __popcll(be1 & mlt);
    if (rk < take) {
      sel[base + G + rk] = t + 1024;
      rowmap[bh * L_DIM + t + 1024] = G + rk;
    }
  }
  if (t < SLOTS - KTOP) sel[base + KTOP + t] = -1;
}

// ---------------------------------------------------------------------------
// K-split flash attention — round-12: LDS-staged K/V with prefetch dbuf.
// Per 32-key step the block stages K (32x64, slot^(row&7) swizzle) and
// V (key-tile 64x32, slot^(row&3) swizzle) once via global_load_lds
// (2 gld16/wave, replacing 8 wave-redundant global loads), prefetching
// step kt+32 before computing kt; one barrier/step drains the DMA.
// qt=2 q-tiles/wave (r8 best); grid 1024 = 4 blocks/CU; XCD affinity.
// ---------------------------------------------------------------------------
__global__ __launch_bounds__(256) void attn_kernel(
    const bf16_t* __restrict__ Qhi,
    const bf16_t* __restrict__ Khi,
    const bf16_t* __restrict__ VThi,
    const int* __restrict__ sel,
    float* __restrict__ Ol, bf16_t* __restrict__ Oo)
{
  const int bx = blockIdx.x;
  const int xl = bx & 7;          // XCD id under default round-robin
  const int rest = bx >> 3;       // 0..127
  const int qc = rest & 3;
  const int gh = rest >> 2;       // 0..31
  const int g  = gh * 8 + xl;     // K/V-chunk group 0..255
  const int bh = g & 31;
  const int ks = g >> 5;
  const int b = bh >> 4, h = bh & 15;
  const int wave = threadIdx.x >> 6;
  const int lane = threadIdx.x & 63;
  const int lm = lane & 15, quad = lane >> 4;

  __shared__ __align__(16) bf16_t sK[2][2048];   // 32 keys x 64d, swizzled
  __shared__ __align__(16) bf16_t sV[2][2048];   // 64 d x 32 keys, swizzled
  __shared__ __align__(16) bf16_t sPh[2][2][4][16][40];  // [PB][qt][wave][q][k]

  const int qbase = qc * 128 + wave * 32;   // tile qt covers +qt*16
  bf16x8 qa[2][2];
  #pragma unroll
  for (int qt = 0; qt < 2; ++qt) {
    int qi = sel[bh * SLOTS + qbase + qt * 16 + lm];
    size_t qo = ((size_t)(b * L_DIM + (qi >= 0 ? qi : 0))) * D_DIM + h * 64;
    qa[qt][0] = *reinterpret_cast<const bf16x8*>(&Qhi[qo + quad * 8]);
    qa[qt][1] = *reinterpret_cast<const bf16x8*>(&Qhi[qo + 32 + quad * 8]);
  }

  const f32x4 vzero = {0.f, 0.f, 0.f, 0.f};
  float l_l[2][4];
  f32x4 o[2][4];
  #pragma unroll
  for (int qt = 0; qt < 2; ++qt)
    #pragma unroll
    for (int ni = 0; ni < 4; ++ni) { o[qt][ni] = vzero; l_l[qt][ni] = 0.f; }

  const float scale = 0.125f;
  const size_t khead = (size_t)(b * H_DIM + h) * HSZ;
  const int key0 = ks * KCHUNK;

  // K: row = wave*8 + (lane>>3) in 0..31 (64B halves: slot=lane&7 of 8);
  //    source col pre-swizzled by row&7 so swizzled-read matches (rule #21).
  // V: row = wave*16 + (lane>>2) in 0..63 (16B slots: lane&3 of 4);
  //    source col pre-swizzled by row&3.
#define ATTN_STAGE(KT, bsel) do {                                             \
    const int krow = wave * 8 + (lane >> 3);                                  \
    const int kslot = (lane & 7) ^ ((lane >> 3) & 7);                         \
    gld16(&Khi[khead + (size_t)(key0 + (KT) + krow) * 64 + kslot * 8],        \
          sK[bsel] + wave * 512);                                             \
    const int vrow = wave * 16 + (lane >> 2);                                 \
    const int vslot = (lane & 3) ^ ((lane >> 2) & 3);                         \
    const size_t vbase = khead + (size_t)((key0 + (KT)) >> 5) * 2048;         \
    gld16(&VThi[vbase + vrow * 32 + vslot * 8], sV[bsel] + wave * 512);       \
  } while (0)

  ATTN_STAGE(0, 0);
  __syncthreads();
  int cur = 0;
  #pragma unroll 2
  for (int kt = 0; kt < KCHUNK; kt += 32) {
    if (kt + 32 < KCHUNK) ATTN_STAGE(kt + 32, cur ^ 1);
    const int PB = (kt >> 5) & 1;
    // K fragment reads (swizzled): K[row][s] at sK[row*64 + (s^(row&7))*8]
    const int kx = lm & 7;
    bf16x8 kb0 = *reinterpret_cast<const bf16x8*>(&sK[cur][lm * 64 + ((quad) ^ kx) * 8]);
    bf16x8 kb1 = *reinterpret_cast<const bf16x8*>(&sK[cur][lm * 64 + ((quad + 4) ^ kx) * 8]);
    bf16x8 kb2 = *reinterpret_cast<const bf16x8*>(&sK[cur][(16 + lm) * 64 + ((quad) ^ kx) * 8]);
    bf16x8 kb3 = *reinterpret_cast<const bf16x8*>(&sK[cur][(16 + lm) * 64 + ((quad + 4) ^ kx) * 8]);
    bf16x8 vbh[4];
    #pragma unroll
    for (int ni = 0; ni < 4; ++ni) {
      const int vr = ni * 16 + lm;
      vbh[ni] = *reinterpret_cast<const bf16x8*>(&sV[cur][vr * 32 + ((quad) ^ (vr & 3)) * 8]);
    }
    #pragma unroll
    for (int qt = 0; qt < 2; ++qt) {
      f32x4 s0 = vzero, s1 = vzero;
      s0 = __builtin_amdgcn_mfma_f32_16x16x32_bf16(qa[qt][0], kb0, s0, 0, 0, 0);
      s0 = __builtin_amdgcn_mfma_f32_16x16x32_bf16(qa[qt][1], kb1, s0, 0, 0, 0);
      s1 = __builtin_amdgcn_mfma_f32_16x16x32_bf16(qa[qt][0], kb2, s1, 0, 0, 0);
      s1 = __builtin_amdgcn_mfma_f32_16x16x32_bf16(qa[qt][1], kb3, s1, 0, 0, 0);
      #pragma unroll
      for (int r = 0; r < 4; ++r) {
        float p0 = __expf(s0[r] * scale);
        float p1 = __expf(s1[r] * scale);
        l_l[qt][r] += p0 + p1;
        sPh[PB][qt][wave][quad * 4 + r][lm]      = (bf16_t)p0;
        sPh[PB][qt][wave][quad * 4 + r][16 + lm] = (bf16_t)p1;
      }
      bf16x8 pah = *reinterpret_cast<const bf16x8*>(&sPh[PB][qt][wave][lm][quad * 8]);
      #pragma unroll
      for (int ni = 0; ni < 4; ++ni)
        o[qt][ni] = __builtin_amdgcn_mfma_f32_16x16x32_bf16(pah, vbh[ni], o[qt][ni], 0, 0, 0);
    }
    __syncthreads();
    cur ^= 1;
  }

  #pragma unroll
  for (int qt = 0; qt < 2; ++qt)
    #pragma unroll
    for (int r = 0; r < 4; ++r) {
      l_l[qt][r] += __shfl_xor(l_l[qt][r], 1);
      l_l[qt][r] += __shfl_xor(l_l[qt][r], 2);
      l_l[qt][r] += __shfl_xor(l_l[qt][r], 4);
      l_l[qt][r] += __shfl_xor(l_l[qt][r], 8);
    }

  #pragma unroll
  for (int qt = 0; qt < 2; ++qt)
    #pragma unroll
    for (int r = 0; r < 4; ++r) {
      int slot = qbase + qt * 16 + quad * 4 + r;
      int s2 = sel[bh * SLOTS + slot];
      if (s2 >= 0) {
        size_t gs = (size_t)(bh * SLOTS_IO + slot) * KSPLIT + ks;
        if (lm == 0) Ol[gs] = l_l[qt][r];
        #pragma unroll
        for (int ni = 0; ni < 4; ++ni)
          Oo[gs * 64 + ni * 16 + lm] = (bf16_t)o[qt][ni][r];
      }
    }
}

// ---------------------------------------------------------------------------
// Fused fill: every AO row written exactly once — mean(V) for non-selected,
// ksplit-combine for selected. Grid (32,32) = 4 blocks/CU; per-wave rowmap
// prefetch + shfl broadcast.
// ---------------------------------------------------------------------------
__global__ __launch_bounds__(256) void fill_kernel(
    const float* __restrict__ Ol, const bf16_t* __restrict__ Oo,
    const int* __restrict__ rowmap, const float* __restrict__ Vmeanf,
    bf16_t* __restrict__ AOhi)
{
  const int bh = blockIdx.x;
  const int b = bh >> 4, h = bh & 15;
  const int t = threadIdx.x;
  const int lane = t & 63;
  const int w = t >> 6;

  __shared__ __align__(16) bf16_t smh[64];
  if (t < 64)
    smh[t] = (bf16_t)(Vmeanf[(b * H_DIM + h) * 64 + t] * (1.0f / (float)L_DIM));
  __syncthreads();

  const int rbase = blockIdx.y * 64 + w * 16;   // 16 rows per wave
  int flag = -1;
  if (lane < 16) flag = rowmap[bh * L_DIM + rbase + lane];

  for (int j = 0; j < 16; ++j) {
    const int s = __shfl(flag, j);              // wave-uniform slot or -1
    const int row = rbase + j;
    bf16_t outv;
    if (s < 0) {
      outv = smh[lane];
    } else {
      size_t gs = (size_t)(bh * SLOTS_IO + s) * KSPLIT;
      float L = 0.f, ov = 0.f;
      #pragma unroll
      for (int sp = 0; sp < KSPLIT; ++sp) {
        L  += Ol[gs + sp];
        ov += (float)Oo[(gs + sp) * 64 + lane];
      }
      outv = (bf16_t)(ov / L);
    }
    AOhi[((size_t)(b * L_DIM + row)) * D_DIM + h * 64 + lane] = outv;
  }
}

// ---------------------------------------------------------------------------
extern "C" void kernel_launch(void* const* d_in, const int* in_sizes, int n_in,
                              void* d_out, int out_size, void* d_ws, size_t ws_size,
                              hipStream_t stream) {
  const float* x  = (const float*)d_in[0];
  const float* Wq = (const float*)d_in[1];
  const float* bq = (const float*)d_in[2];
  const float* Wk = (const float*)d_in[3];
  const float* bk = (const float*)d_in[4];
  const float* Wv = (const float*)d_in[5];
  const float* bv = (const float*)d_in[6];
  const float* Wo = (const float*)d_in[7];
  const float* bo = (const float*)d_in[8];
  float* out = (float*)d_out;

  // ws layout (~43 MB):
  //  [0,8)    Qhi  (aliased as AOhi after attn)
  //  [8,16)   VThi (key-tiled per-head layout)
  //  [16,24)  xhi  -+ dead after gemm_qkv; [16,~30.7) reused for Oo (bf16,
  //  [24,32)  xlo  -+  SLOTS_IO=448 stride); [31,32) rowmap (topk, xlo dead)
  //  [32,34)  Wqhi  [34,36) Wqlo  [36,38) Wkb  [38,40) Wvb  [40,42) Wob
  //  [42,..)  norms (256 KB), sel (64 KB), Ol (458 KB), Vmeanf (8 KB @832K)
  // Khi (per-head layout) lives in d_out (8 of 16 MB) — dead until gemm_out.
  const size_t MB = 1u << 20;
  char* ws = (char*)d_ws;
  bf16_t* Qhi  = (bf16_t*)(ws);
  bf16_t* VThi = (bf16_t*)(ws + 8 * MB);
  bf16_t* xhi  = (bf16_t*)(ws + 16 * MB);
  bf16_t* xlo  = (bf16_t*)(ws + 24 * MB);
  bf16_t* Oo   = (bf16_t*)(ws + 16 * MB);         // aliases xhi/xlo
  int*    rowmap = (int*)(ws + 31 * MB);          // 256 KB, past Oo's tail
  bf16_t* Wqhi = (bf16_t*)(ws + 32 * MB);
  bf16_t* Wqlo = (bf16_t*)(ws + 34 * MB);
  bf16_t* Wkb  = (bf16_t*)(ws + 36 * MB);
  bf16_t* Wvb  = (bf16_t*)(ws + 38 * MB);
  bf16_t* Wob  = (bf16_t*)(ws + 40 * MB);
  float*  norms = (float*)(ws + 42 * MB);
  int*    sel   = (int*)(ws + 42 * MB + (256u << 10));
  float*  Ol    = (float*)(ws + 42 * MB + (320u << 10));
  float*  Vmeanf = (float*)(ws + 42 * MB + (832u << 10));
  bf16_t* AOhi = Qhi;
  bf16_t* Khi = (bf16_t*)d_out;

  dim3 blk(256);
  prep_kernel<<<dim3(2048), blk, 0, stream>>>(x, Wq, Wk, Wv, Wo,
                                              xhi, xlo, Wqhi, Wqlo, Wkb, Wvb, Wob,
                                              Vmeanf);
  gemm_qkv<<<dim3(768), blk, 0, stream>>>(xhi, xlo, Wqhi, Wqlo, Wkb, Wvb,
                                          bq, bk, bv, Qhi, Khi, VThi, norms, Vmeanf);
  topk_kernel<<<dim3(32), dim3(1024), 0, stream>>>(norms, sel, rowmap);
  attn_kernel<<<dim3(32 * 4 * KSPLIT), blk, 0, stream>>>(Qhi, Khi, VThi, sel, Ol, Oo);
  fill_kernel<<<dim3(32, 32), blk, 0, stream>>>(Ol, Oo, rowmap, Vmeanf, AOhi);
  gemm_out<<<dim3(8, 64), blk, 0, stream>>>(AOhi, Wob, bo, out);
}